// Round 1
// baseline (14997.650 us; speedup 1.0000x reference)
//
#include <hip/hip_runtime.h>
#include <hip/hip_bf16.h>
#include <math.h>

#define B_   4
#define L_   512
#define H_   768
#define NH_  12
#define HD_  64
#define M_   3072
#define NL_  6
#define RD_  128
#define NR_  255          // 2*RD-1
#define ROWS (B_*L_)      // 2048
#define COEF_ 0.125f      // 1/sqrt(64)

// ---------------- utility ----------------

static __device__ __forceinline__ float wave_reduce_sum(float v) {
#pragma unroll
    for (int off = 32; off > 0; off >>= 1) v += __shfl_xor(v, off, 64);
    return v;
}

static __device__ __forceinline__ float gelu_f(float x) {
    // jax.nn.gelu default: approximate=True (tanh form)
    float x3 = x * x * x;
    return 0.5f * x * (1.f + tanhf(0.7978845608028654f * (x + 0.044715f * x3)));
}

// ---------------- embedding + LN ----------------

__global__ __launch_bounds__(256) void embed_ln_kernel(
    const int* __restrict__ tok, const int* __restrict__ seg,
    const float* __restrict__ temb, const float* __restrict__ semb,
    const float* __restrict__ sc, const float* __restrict__ bi,
    float* __restrict__ out)
{
    int row = blockIdx.x;
    int t = threadIdx.x;
    int tid = tok[row], sid = seg[row];
    const float* tp = temb + (size_t)tid * H_;
    const float* sp = semb + (size_t)sid * H_;
    float v[3];
#pragma unroll
    for (int j = 0; j < 3; j++) { int idx = t + j * 256; v[j] = tp[idx] + sp[idx]; }

    __shared__ float red[4];
    __shared__ float bc;
    int lane = t & 63, wid = t >> 6;

    float s = v[0] + v[1] + v[2];
    s = wave_reduce_sum(s);
    if (lane == 0) red[wid] = s;
    __syncthreads();
    if (t == 0) bc = (red[0] + red[1] + red[2] + red[3]) * (1.f / H_);
    __syncthreads();
    float mean = bc;

    float c[3]; float ss = 0.f;
#pragma unroll
    for (int j = 0; j < 3; j++) { c[j] = v[j] - mean; ss += c[j] * c[j]; }
    ss = wave_reduce_sum(ss);
    __syncthreads();
    if (lane == 0) red[wid] = ss;
    __syncthreads();
    if (t == 0) bc = rsqrtf((red[0] + red[1] + red[2] + red[3]) * (1.f / H_) + 1e-12f);
    __syncthreads();
    float r = bc;
#pragma unroll
    for (int j = 0; j < 3; j++) {
        int idx = t + j * 256;
        out[(size_t)row * H_ + idx] = c[j] * r * sc[idx] + bi[idx];
    }
}

// ---------------- residual add + LN ----------------

__global__ __launch_bounds__(256) void add_ln_kernel(
    const float* __restrict__ x, const float* __restrict__ y,
    const float* __restrict__ sc, const float* __restrict__ bi,
    float* __restrict__ out)
{
    int row = blockIdx.x;
    int t = threadIdx.x;
    const float* xp = x + (size_t)row * H_;
    const float* yp = y + (size_t)row * H_;
    float v[3];
#pragma unroll
    for (int j = 0; j < 3; j++) { int idx = t + j * 256; v[j] = xp[idx] + yp[idx]; }

    __shared__ float red[4];
    __shared__ float bc;
    int lane = t & 63, wid = t >> 6;

    float s = v[0] + v[1] + v[2];
    s = wave_reduce_sum(s);
    if (lane == 0) red[wid] = s;
    __syncthreads();
    if (t == 0) bc = (red[0] + red[1] + red[2] + red[3]) * (1.f / H_);
    __syncthreads();
    float mean = bc;

    float c[3]; float ss = 0.f;
#pragma unroll
    for (int j = 0; j < 3; j++) { c[j] = v[j] - mean; ss += c[j] * c[j]; }
    ss = wave_reduce_sum(ss);
    __syncthreads();
    if (lane == 0) red[wid] = ss;
    __syncthreads();
    if (t == 0) bc = rsqrtf((red[0] + red[1] + red[2] + red[3]) * (1.f / H_) + 1e-12f);
    __syncthreads();
    float r = bc;
#pragma unroll
    for (int j = 0; j < 3; j++) {
        int idx = t + j * 256;
        out[(size_t)row * H_ + idx] = c[j] * r * sc[idx] + bi[idx];
    }
}

// ---------------- fp32 tiled GEMM: C[M,N] = A[M,K] @ B[K,N] + bias, optional GELU ----------------
// grid: (N/128, ceil(M/128)), block 256. N,K must be multiples of 128/16 (true here).

#define GBM 128
#define GBN 128
#define GBK 16

__global__ __launch_bounds__(256) void gemm_kernel(
    const float* __restrict__ A, const float* __restrict__ B,
    const float* __restrict__ bias, float* __restrict__ C,
    int M, int N, int K, int act)
{
    __shared__ float As[GBK][GBM];
    __shared__ float Bs[GBK][GBN];
    int t = threadIdx.x;
    int bm = blockIdx.y * GBM;
    int bn = blockIdx.x * GBN;
    int tm = (t >> 4) * 8;
    int tn = (t & 15) * 8;
    float acc[8][8];
#pragma unroll
    for (int i = 0; i < 8; i++)
#pragma unroll
        for (int j = 0; j < 8; j++) acc[i][j] = 0.f;

    int arow = t >> 2;            // 0..63
    int acol = (t & 3) * 4;       // 0,4,8,12
    int brow = t >> 5;            // 0..7
    int bcol = (t & 31) * 4;      // 0..124

    for (int k0 = 0; k0 < K; k0 += GBK) {
#pragma unroll
        for (int rr = 0; rr < 2; rr++) {
            int r = arow + rr * 64;
            int gm = bm + r;
            float4 av = make_float4(0.f, 0.f, 0.f, 0.f);
            if (gm < M) av = *(const float4*)(A + (size_t)gm * K + k0 + acol);
            As[acol + 0][r] = av.x;
            As[acol + 1][r] = av.y;
            As[acol + 2][r] = av.z;
            As[acol + 3][r] = av.w;
        }
#pragma unroll
        for (int rr = 0; rr < 2; rr++) {
            int r = brow + rr * 8;
            float4 bv = *(const float4*)(B + (size_t)(k0 + r) * N + bn + bcol);
            *(float4*)&Bs[r][bcol] = bv;
        }
        __syncthreads();
#pragma unroll
        for (int kk = 0; kk < GBK; kk++) {
            float a[8], bb[8];
            *(float4*)&a[0] = *(const float4*)&As[kk][tm];
            *(float4*)&a[4] = *(const float4*)&As[kk][tm + 4];
            *(float4*)&bb[0] = *(const float4*)&Bs[kk][tn];
            *(float4*)&bb[4] = *(const float4*)&Bs[kk][tn + 4];
#pragma unroll
            for (int i = 0; i < 8; i++)
#pragma unroll
                for (int j = 0; j < 8; j++)
                    acc[i][j] = fmaf(a[i], bb[j], acc[i][j]);
        }
        __syncthreads();
    }

#pragma unroll
    for (int i = 0; i < 8; i++) {
        int gm = bm + tm + i;
        if (gm >= M) continue;
        float* cp = C + (size_t)gm * N + bn + tn;
#pragma unroll
        for (int j4 = 0; j4 < 2; j4++) {
            float4 o;
            float v0 = acc[i][j4 * 4 + 0] + bias[bn + tn + j4 * 4 + 0];
            float v1 = acc[i][j4 * 4 + 1] + bias[bn + tn + j4 * 4 + 1];
            float v2 = acc[i][j4 * 4 + 2] + bias[bn + tn + j4 * 4 + 2];
            float v3 = acc[i][j4 * 4 + 3] + bias[bn + tn + j4 * 4 + 3];
            if (act == 1) { v0 = gelu_f(v0); v1 = gelu_f(v1); v2 = gelu_f(v2); v3 = gelu_f(v3); }
            o.x = v0; o.y = v1; o.z = v2; o.w = v3;
            *(float4*)(cp + j4 * 4) = o;
        }
    }
}

// ---------------- fused rel-pos attention ----------------
// grid (16 qtiles, NH, B), block 256.
// thread t: qloc = t>>3 (0..31), kg = t&7; thread owns 64 keys k = kg*64 + i.
// s[q,k] = COEF*( q·(k_k + k_rel[j]) ), j = clamp(k-q+127, 0, 254)
// out[q] = sum_k P[k] * ( v_k + v_rel[j] )

__global__ __launch_bounds__(256) void attn_kernel(
    const float* __restrict__ Q, const float* __restrict__ K, const float* __restrict__ V,
    const float* __restrict__ KR, const float* __restrict__ VR,
    const int* __restrict__ mask, float* __restrict__ CTX)
{
    int qt = blockIdx.x;
    int h  = blockIdx.y;
    int b  = blockIdx.z;
    int t  = threadIdx.x;
    int qloc = t >> 3;
    int kg   = t & 7;
    int qg   = qt * 32 + qloc;

    __shared__ float Qs[32][68];
    {
        int r = t >> 3;
        int c = (t & 7) * 8;
        const float* src = Q + ((size_t)(b * L_ + qt * 32 + r)) * H_ + h * HD_ + c;
        float4 v0 = *(const float4*)src;
        float4 v1 = *(const float4*)(src + 4);
        *(float4*)&Qs[r][c] = v0;
        *(float4*)&Qs[r][c + 4] = v1;
    }
    __syncthreads();

    float s[64];
    {
        float qreg[64];
#pragma unroll
        for (int d = 0; d < 64; d++) qreg[d] = Qs[qloc][d];
        const float* Kb  = K  + ((size_t)b * L_) * H_ + h * HD_;
        const float* KRb = KR + h * HD_;
        for (int i = 0; i < 64; i++) {
            int kk = kg * 64 + i;
            int j = kk - qg + 127; j = j < 0 ? 0 : (j > 254 ? 254 : j);
            const float4* kp = (const float4*)(Kb  + (size_t)kk * H_);
            const float4* rp = (const float4*)(KRb + (size_t)j  * H_);
            float a = 0.f;
#pragma unroll
            for (int d4 = 0; d4 < 16; d4++) {
                float4 kv = kp[d4]; float4 rv = rp[d4];
                a = fmaf(qreg[4 * d4 + 0], kv.x + rv.x, a);
                a = fmaf(qreg[4 * d4 + 1], kv.y + rv.y, a);
                a = fmaf(qreg[4 * d4 + 2], kv.z + rv.z, a);
                a = fmaf(qreg[4 * d4 + 3], kv.w + rv.w, a);
            }
            a *= COEF_;
            if (mask[b * L_ + kk] == 0) a = -INFINITY;
            s[i] = a;
        }
    }

    // softmax over 512 keys (64 local + 8-lane group reduce)
    float mx = -INFINITY;
#pragma unroll
    for (int i = 0; i < 64; i++) mx = fmaxf(mx, s[i]);
#pragma unroll
    for (int off = 1; off < 8; off <<= 1) mx = fmaxf(mx, __shfl_xor(mx, off, 64));
    float sum = 0.f;
#pragma unroll
    for (int i = 0; i < 64; i++) { float e = __expf(s[i] - mx); s[i] = e; sum += e; }
#pragma unroll
    for (int off = 1; off < 8; off <<= 1) sum += __shfl_xor(sum, off, 64);
    float inv = 1.f / sum;

    float acc[64];
#pragma unroll
    for (int d = 0; d < 64; d++) acc[d] = 0.f;
    const float* Vb  = V  + ((size_t)b * L_) * H_ + h * HD_;
    const float* VRb = VR + h * HD_;
    for (int i = 0; i < 64; i++) {
        int kk = kg * 64 + i;
        int j = kk - qg + 127; j = j < 0 ? 0 : (j > 254 ? 254 : j);
        float p = s[i] * inv;
        const float4* vp = (const float4*)(Vb  + (size_t)kk * H_);
        const float4* rp = (const float4*)(VRb + (size_t)j  * H_);
#pragma unroll
        for (int d4 = 0; d4 < 16; d4++) {
            float4 vv = vp[d4]; float4 rv = rp[d4];
            acc[4 * d4 + 0] = fmaf(p, vv.x + rv.x, acc[4 * d4 + 0]);
            acc[4 * d4 + 1] = fmaf(p, vv.y + rv.y, acc[4 * d4 + 1]);
            acc[4 * d4 + 2] = fmaf(p, vv.z + rv.z, acc[4 * d4 + 2]);
            acc[4 * d4 + 3] = fmaf(p, vv.w + rv.w, acc[4 * d4 + 3]);
        }
    }
#pragma unroll
    for (int off = 1; off < 8; off <<= 1) {
#pragma unroll
        for (int d = 0; d < 64; d++) acc[d] += __shfl_xor(acc[d], off, 64);
    }
    if (kg == 0) {
        float* op = CTX + ((size_t)(b * L_ + qg)) * H_ + h * HD_;
#pragma unroll
        for (int d4 = 0; d4 < 16; d4++) {
            float4 o;
            o.x = acc[4 * d4 + 0]; o.y = acc[4 * d4 + 1];
            o.z = acc[4 * d4 + 2]; o.w = acc[4 * d4 + 3];
            ((float4*)op)[d4] = o;
        }
    }
}

// ---------------- host ----------------

extern "C" void kernel_launch(void* const* d_in, const int* in_sizes, int n_in,
                              void* d_out, int out_size, void* d_ws, size_t ws_size,
                              hipStream_t stream)
{
    const int*   tok    = (const int*)d_in[0];
    const int*   seg    = (const int*)d_in[1];
    const int*   maskp  = (const int*)d_in[2];
    const float* temb   = (const float*)d_in[3];
    const float* semb   = (const float*)d_in[4];
    const float* esc    = (const float*)d_in[5];
    const float* ebi    = (const float*)d_in[6];
    const float* Wq     = (const float*)d_in[7];
    const float* bq     = (const float*)d_in[8];
    const float* Wk     = (const float*)d_in[9];
    const float* bk     = (const float*)d_in[10];
    const float* Wv     = (const float*)d_in[11];
    const float* bv     = (const float*)d_in[12];
    const float* relpos = (const float*)d_in[13];
    const float* Wo     = (const float*)d_in[14];
    const float* bo     = (const float*)d_in[15];
    const float* ln1s   = (const float*)d_in[16];
    const float* ln1b   = (const float*)d_in[17];
    const float* W1     = (const float*)d_in[18];
    const float* b1     = (const float*)d_in[19];
    const float* W2     = (const float*)d_in[20];
    const float* b2     = (const float*)d_in[21];
    const float* ln2s   = (const float*)d_in[22];
    const float* ln2b   = (const float*)d_in[23];

    float* ws = (float*)d_ws;
    const size_t NX = (size_t)ROWS * H_;
    float* x   = ws;
    float* x2  = x   + NX;
    float* y   = x2  + NX;
    float* qb  = y   + NX;
    float* kb  = qb  + NX;
    float* vb  = kb  + NX;
    float* ctx = vb  + NX;
    float* krb = ctx + NX;
    float* vrb = krb + (size_t)NR_ * H_;
    float* h1  = vrb + (size_t)NR_ * H_;   // ROWS*M_ floats

    dim3 blk(256);

    embed_ln_kernel<<<ROWS, blk, 0, stream>>>(tok, seg, temb, semb, esc, ebi, x);

    for (int l = 0; l < NL_; l++) {
        const float* wq = Wq + (size_t)l * H_ * H_;
        const float* wk = Wk + (size_t)l * H_ * H_;
        const float* wv = Wv + (size_t)l * H_ * H_;
        const float* wo = Wo + (size_t)l * H_ * H_;
        const float* w1 = W1 + (size_t)l * H_ * M_;
        const float* w2 = W2 + (size_t)l * M_ * H_;
        const float* rp = relpos + (size_t)l * NR_ * H_;
        const float* bql = bq + (size_t)l * H_;
        const float* bkl = bk + (size_t)l * H_;
        const float* bvl = bv + (size_t)l * H_;
        const float* bol = bo + (size_t)l * H_;
        const float* b1l = b1 + (size_t)l * M_;
        const float* b2l = b2 + (size_t)l * H_;

        dim3 g768(H_ / GBN, ROWS / GBM);        // (6,16)
        dim3 g3072(M_ / GBN, ROWS / GBM);       // (24,16)
        dim3 gRel(H_ / GBN, (NR_ + GBM - 1) / GBM); // (6,2)

        gemm_kernel<<<g768, blk, 0, stream>>>(x, wq, bql, qb, ROWS, H_, H_, 0);
        gemm_kernel<<<g768, blk, 0, stream>>>(x, wk, bkl, kb, ROWS, H_, H_, 0);
        gemm_kernel<<<g768, blk, 0, stream>>>(x, wv, bvl, vb, ROWS, H_, H_, 0);
        gemm_kernel<<<gRel, blk, 0, stream>>>(rp, wk, bkl, krb, NR_, H_, H_, 0);
        gemm_kernel<<<gRel, blk, 0, stream>>>(rp, wv, bvl, vrb, NR_, H_, H_, 0);

        attn_kernel<<<dim3(L_ / 32, NH_, B_), blk, 0, stream>>>(qb, kb, vb, krb, vrb, maskp, ctx);

        gemm_kernel<<<g768, blk, 0, stream>>>(ctx, wo, bol, y, ROWS, H_, H_, 0);
        add_ln_kernel<<<ROWS, blk, 0, stream>>>(x, y, ln1s + (size_t)l * H_, ln1b + (size_t)l * H_, x2);

        gemm_kernel<<<g3072, blk, 0, stream>>>(x2, w1, b1l, h1, ROWS, M_, H_, 1);
        gemm_kernel<<<g768, blk, 0, stream>>>(h1, w2, b2l, y, ROWS, H_, M_, 0);

        float* outp = (l == NL_ - 1) ? (float*)d_out : x;
        add_ln_kernel<<<ROWS, blk, 0, stream>>>(x2, y, ln2s + (size_t)l * H_, ln2b + (size_t)l * H_, outp);
    }
}

// Round 2
// 4589.656 us; speedup vs baseline: 3.2677x; 3.2677x over previous
//
#include <hip/hip_runtime.h>
#include <hip/hip_bf16.h>
#include <math.h>

#define B_   4
#define L_   512
#define H_   768
#define NH_  12
#define HD_  64
#define M_   3072
#define NL_  6
#define RD_  128
#define NR_  255          // 2*RD-1
#define ROWS (B_*L_)      // 2048
#define COEF_ 0.125f      // 1/sqrt(64)

typedef __attribute__((ext_vector_type(8))) short bf16x8;
typedef __attribute__((ext_vector_type(4))) float f32x4;

// ---------------- utility ----------------

static __device__ __forceinline__ float wave_reduce_sum(float v) {
#pragma unroll
    for (int off = 32; off > 0; off >>= 1) v += __shfl_xor(v, off, 64);
    return v;
}

static __device__ __forceinline__ float gelu_f(float x) {
    float x3 = x * x * x;
    return 0.5f * x * (1.f + tanhf(0.7978845608028654f * (x + 0.044715f * x3)));
}

// ---------------- embedding + LN (fp32 out + bf16 twin) ----------------

__global__ __launch_bounds__(256) void embed_ln_kernel(
    const int* __restrict__ tok, const int* __restrict__ seg,
    const float* __restrict__ temb, const float* __restrict__ semb,
    const float* __restrict__ sc, const float* __restrict__ bi,
    float* __restrict__ out, __hip_bfloat16* __restrict__ outb)
{
    int row = blockIdx.x;
    int t = threadIdx.x;
    int tid = tok[row], sid = seg[row];
    const float* tp = temb + (size_t)tid * H_;
    const float* sp = semb + (size_t)sid * H_;
    float v[3];
#pragma unroll
    for (int j = 0; j < 3; j++) { int idx = t + j * 256; v[j] = tp[idx] + sp[idx]; }

    __shared__ float red[4];
    __shared__ float bc;
    int lane = t & 63, wid = t >> 6;

    float s = v[0] + v[1] + v[2];
    s = wave_reduce_sum(s);
    if (lane == 0) red[wid] = s;
    __syncthreads();
    if (t == 0) bc = (red[0] + red[1] + red[2] + red[3]) * (1.f / H_);
    __syncthreads();
    float mean = bc;

    float c[3]; float ss = 0.f;
#pragma unroll
    for (int j = 0; j < 3; j++) { c[j] = v[j] - mean; ss += c[j] * c[j]; }
    ss = wave_reduce_sum(ss);
    __syncthreads();
    if (lane == 0) red[wid] = ss;
    __syncthreads();
    if (t == 0) bc = rsqrtf((red[0] + red[1] + red[2] + red[3]) * (1.f / H_) + 1e-12f);
    __syncthreads();
    float r = bc;
#pragma unroll
    for (int j = 0; j < 3; j++) {
        int idx = t + j * 256;
        float o = c[j] * r * sc[idx] + bi[idx];
        out[(size_t)row * H_ + idx] = o;
        outb[(size_t)row * H_ + idx] = __float2bfloat16(o);
    }
}

// ---------------- residual add + LN (fp32 out + optional bf16 twin) ----------------

__global__ __launch_bounds__(256) void add_ln_kernel(
    const float* __restrict__ x, const float* __restrict__ y,
    const float* __restrict__ sc, const float* __restrict__ bi,
    float* __restrict__ out, __hip_bfloat16* __restrict__ outb)
{
    int row = blockIdx.x;
    int t = threadIdx.x;
    const float* xp = x + (size_t)row * H_;
    const float* yp = y + (size_t)row * H_;
    float v[3];
#pragma unroll
    for (int j = 0; j < 3; j++) { int idx = t + j * 256; v[j] = xp[idx] + yp[idx]; }

    __shared__ float red[4];
    __shared__ float bc;
    int lane = t & 63, wid = t >> 6;

    float s = v[0] + v[1] + v[2];
    s = wave_reduce_sum(s);
    if (lane == 0) red[wid] = s;
    __syncthreads();
    if (t == 0) bc = (red[0] + red[1] + red[2] + red[3]) * (1.f / H_);
    __syncthreads();
    float mean = bc;

    float c[3]; float ss = 0.f;
#pragma unroll
    for (int j = 0; j < 3; j++) { c[j] = v[j] - mean; ss += c[j] * c[j]; }
    ss = wave_reduce_sum(ss);
    __syncthreads();
    if (lane == 0) red[wid] = ss;
    __syncthreads();
    if (t == 0) bc = rsqrtf((red[0] + red[1] + red[2] + red[3]) * (1.f / H_) + 1e-12f);
    __syncthreads();
    float r = bc;
#pragma unroll
    for (int j = 0; j < 3; j++) {
        int idx = t + j * 256;
        float o = c[j] * r * sc[idx] + bi[idx];
        out[(size_t)row * H_ + idx] = o;
        if (outb) outb[(size_t)row * H_ + idx] = __float2bfloat16(o);
    }
}

// ---------------- transpose + fp32->bf16 weight pack: in[K][N] f32 -> out[N][K] bf16 ----------------

__global__ __launch_bounds__(256) void transpose_cvt_kernel(
    const float* __restrict__ in, __hip_bfloat16* __restrict__ out, int K, int N)
{
    __shared__ float tile[32][33];
    int bx = blockIdx.x * 32;   // n
    int by = blockIdx.y * 32;   // k
    int tx = threadIdx.x & 31, ty = threadIdx.x >> 5;
#pragma unroll
    for (int i = 0; i < 4; i++)
        tile[ty + 8 * i][tx] = in[(size_t)(by + ty + 8 * i) * N + bx + tx];
    __syncthreads();
#pragma unroll
    for (int i = 0; i < 4; i++)
        out[(size_t)(bx + ty + 8 * i) * K + by + tx] = __float2bfloat16(tile[tx][ty + 8 * i]);
}

__global__ void cvt_kernel(const float* __restrict__ in, __hip_bfloat16* __restrict__ out, int n) {
    int i = blockIdx.x * blockDim.x + threadIdx.x;
    int stride = gridDim.x * blockDim.x;
    for (; i < n; i += stride) out[i] = __float2bfloat16(in[i]);
}

__global__ void pack_qkv_bias_kernel(const float* __restrict__ bq, const float* __restrict__ bk,
                                     const float* __restrict__ bv, float* __restrict__ out) {
    int i = blockIdx.x * 256 + threadIdx.x;
    if (i >= 2304) return;
    out[i] = i < 768 ? bq[i] : (i < 1536 ? bk[i - 768] : bv[i - 1536]);
}

// ---------------- bf16 MFMA GEMM: C[M,N] = A[M,K] @ Bt[N,K]^T + bias (+gelu) ----------------
// A, Bt bf16 row-major (both K-contiguous). 128x128 tile, BK=64, 4 waves (2x2), 4x4 frags.
// XOR-swizzled LDS (row 128B: byte ^= (row&7)<<4). Output fp32 (Cf) or bf16 (Cb).

#define TK 64

static __device__ __forceinline__ void gemm_load_tile(
    const __hip_bfloat16* A, const __hip_bfloat16* Bt, int M, int K,
    int bm, int bn, int srow, int scolb, int k0, uint4* av, uint4* bv)
{
#pragma unroll
    for (int c = 0; c < 4; c++) {
        int r = srow + c * 32;
        int gr = bm + r; if (gr >= M) gr = M - 1;
        av[c] = *(const uint4*)((const char*)(A + (size_t)gr * K + k0) + scolb);
        bv[c] = *(const uint4*)((const char*)(Bt + (size_t)(bn + r) * K + k0) + scolb);
    }
}

__global__ __launch_bounds__(256) void gemm_bf16_kernel(
    const __hip_bfloat16* __restrict__ A, const __hip_bfloat16* __restrict__ Bt,
    const float* __restrict__ bias, float* __restrict__ Cf, __hip_bfloat16* __restrict__ Cb,
    int M, int N, int K, int act)
{
    __shared__ __hip_bfloat16 As[128 * TK];
    __shared__ __hip_bfloat16 Bs[128 * TK];
    const int t = threadIdx.x;
    const int lane = t & 63;
    const int wid = t >> 6;
    const int wm = (wid >> 1) * 64, wn = (wid & 1) * 64;
    const int bm = blockIdx.y * 128, bn = blockIdx.x * 128;

    f32x4 acc[4][4];
#pragma unroll
    for (int i = 0; i < 4; i++)
#pragma unroll
        for (int j = 0; j < 4; j++) acc[i][j] = (f32x4){0.f, 0.f, 0.f, 0.f};

    const int srow = t >> 3;
    const int scolb = (t & 7) * 16;
    const int nt = K / TK;
    uint4 av[4], bv[4];

    gemm_load_tile(A, Bt, M, K, bm, bn, srow, scolb, 0, av, bv);

    for (int kt = 0; kt < nt; kt++) {
        __syncthreads();
#pragma unroll
        for (int c = 0; c < 4; c++) {
            int r = srow + c * 32;
            int off = r * 128 + (scolb ^ ((r & 7) << 4));
            *(uint4*)((char*)As + off) = av[c];
            *(uint4*)((char*)Bs + off) = bv[c];
        }
        __syncthreads();
        if (kt + 1 < nt)
            gemm_load_tile(A, Bt, M, K, bm, bn, srow, scolb, (kt + 1) * TK, av, bv);
#pragma unroll
        for (int kh = 0; kh < 2; kh++) {
            const int kb = kh * 64 + (lane >> 4) * 16;
            bf16x8 af[4], bfr[4];
#pragma unroll
            for (int i = 0; i < 4; i++) {
                int ra = wm + i * 16 + (lane & 15);
                af[i] = *(const bf16x8*)((const char*)As + ra * 128 + (kb ^ ((ra & 7) << 4)));
                int rb = wn + i * 16 + (lane & 15);
                bfr[i] = *(const bf16x8*)((const char*)Bs + rb * 128 + (kb ^ ((rb & 7) << 4)));
            }
#pragma unroll
            for (int i = 0; i < 4; i++)
#pragma unroll
                for (int j = 0; j < 4; j++)
                    acc[i][j] = __builtin_amdgcn_mfma_f32_16x16x32_bf16(af[i], bfr[j], acc[i][j], 0, 0, 0);
        }
    }

    const int lr = (lane >> 4) * 4;
    const int lc = lane & 15;
#pragma unroll
    for (int i = 0; i < 4; i++) {
#pragma unroll
        for (int j = 0; j < 4; j++) {
            int col = bn + wn + j * 16 + lc;
            float bsv = bias[col];
#pragma unroll
            for (int rr = 0; rr < 4; rr++) {
                int row = bm + wm + i * 16 + lr + rr;
                if (row >= M) continue;
                float v = acc[i][j][rr] + bsv;
                if (act) v = gelu_f(v);
                if (Cb) Cb[(size_t)row * N + col] = __float2bfloat16(v);
                else    Cf[(size_t)row * N + col] = v;
            }
        }
    }
}

// ---------------- fused rel-pos attention, two-pass in LDS ----------------
// grid (L/16, NH, B), 256 threads. thread: q = t>>4 (16 rows), g = t&15.
// qkv rows [2048][2304]: Q|K|V. kvrel rows [255][1536]: KR|VR.
// s[q,k] = COEF*( q.k + Rq[q, clamp(k-qseq+127,0,254)] );  out = (P@V + prel@VR)/l

#define SIDX(q,k) ((q)*512 + ((k) ^ ((((k) >> 5) & 7) << 2)))
#define RIDX(q,j) ((q)*256 + ((j) ^ ((((j) >> 5) & 7) << 2)))

__global__ __launch_bounds__(256) void attn_kernel(
    const float* __restrict__ qkv, const float* __restrict__ kvrel,
    const int* __restrict__ mask, __hip_bfloat16* __restrict__ ctxb)
{
    __shared__ float Rq[16 * 256];   // rel scores, then reused as prel
    __shared__ float S[16 * 512];    // scores / probs (XOR bank-swizzled)
    __shared__ float Ks[32][66];     // staged K tile

    const int qt = blockIdx.x, h = blockIdx.y, b = blockIdx.z;
    const int t = threadIdx.x;
    const int q = t >> 4;
    const int g = t & 15;
    const int qseq = qt * 16 + q;
    const size_t qrow = (size_t)(b * L_ + qseq);

    // Q row into registers (broadcast loads, L1-served)
    float4 qv[16];
#pragma unroll
    for (int d4 = 0; d4 < 16; d4++)
        qv[d4] = *(const float4*)(qkv + qrow * 2304 + h * HD_ + d4 * 4);

    // Phase B: Rq[q][j] = Q[q] . KR[j]
    for (int i = 0; i < 16; i++) {
        int j = g + 16 * i;
        if (j >= NR_) continue;
        const float* kr = kvrel + (size_t)j * 1536 + h * HD_;
        float a = 0.f;
#pragma unroll
        for (int d4 = 0; d4 < 16; d4++) {
            float4 kv = *(const float4*)(kr + d4 * 4);
            a = fmaf(qv[d4].x, kv.x, a);
            a = fmaf(qv[d4].y, kv.y, a);
            a = fmaf(qv[d4].z, kv.z, a);
            a = fmaf(qv[d4].w, kv.w, a);
        }
        Rq[RIDX(q, j)] = a;
    }

    // Phase C: scores (K staged in LDS per 32-key tile)
    for (int kt = 0; kt < 16; kt++) {
        __syncthreads();
        {
            int r = t >> 3, c = (t & 7) * 8;
            const float* src = qkv + (size_t)(b * L_ + kt * 32 + r) * 2304 + 768 + h * HD_ + c;
            *(float4*)&Ks[r][c]     = *(const float4*)src;
            *(float4*)&Ks[r][c + 4] = *(const float4*)(src + 4);
        }
        __syncthreads();
#pragma unroll
        for (int kk = 0; kk < 2; kk++) {
            int kloc = g * 2 + kk;
            int k = kt * 32 + kloc;
            float a = 0.f;
#pragma unroll
            for (int d4 = 0; d4 < 16; d4++) {
                float4 kv = *(const float4*)&Ks[kloc][d4 * 4];
                a = fmaf(qv[d4].x, kv.x, a);
                a = fmaf(qv[d4].y, kv.y, a);
                a = fmaf(qv[d4].z, kv.z, a);
                a = fmaf(qv[d4].w, kv.w, a);
            }
            int j = k - qseq + 127; j = j < 0 ? 0 : (j > 254 ? 254 : j);
            float sc = (a + Rq[RIDX(q, j)]) * COEF_;
            if (mask[b * L_ + k] == 0) sc = -1e30f;
            S[SIDX(q, k)] = sc;
        }
    }
    __syncthreads();

    // Phase D: softmax over 512 (thread owns k in [g*32, g*32+32))
    float mx = -INFINITY;
#pragma unroll
    for (int ii = 0; ii < 8; ii++) {
        float4 v = *(const float4*)&S[SIDX(q, g * 32 + ii * 4)];
        mx = fmaxf(mx, fmaxf(fmaxf(v.x, v.y), fmaxf(v.z, v.w)));
    }
#pragma unroll
    for (int off = 1; off < 16; off <<= 1) mx = fmaxf(mx, __shfl_xor(mx, off, 64));
    float sum = 0.f;
#pragma unroll
    for (int ii = 0; ii < 8; ii++) {
        int k0 = g * 32 + ii * 4;
        float4 v = *(const float4*)&S[SIDX(q, k0)];
        v.x = __expf(v.x - mx); v.y = __expf(v.y - mx);
        v.z = __expf(v.z - mx); v.w = __expf(v.w - mx);
        sum += v.x + v.y + v.z + v.w;
        *(float4*)&S[SIDX(q, k0)] = v;
    }
#pragma unroll
    for (int off = 1; off < 16; off <<= 1) sum += __shfl_xor(sum, off, 64);
    float inv = 1.f / sum;
    __syncthreads();

    // Phase E: prel[q][j] (clamp preimage sums), into Rq
    for (int i = 0; i < 16; i++) {
        int j = g * 16 + i;
        if (j >= NR_) continue;
        float val = 0.f;
        if (j == 0) {
            int kmax = qseq - 127;
            for (int k = 0; k <= kmax; k++) val += S[SIDX(q, k)];
        } else if (j == NR_ - 1) {
            int kmin = qseq + 127;
            for (int k = kmin; k < L_; k++) val += S[SIDX(q, k)];
        } else {
            int k = qseq + j - 127;
            if (k >= 0 && k < L_) val = S[SIDX(q, k)];
        }
        Rq[RIDX(q, j)] = val;
    }
    __syncthreads();

    // Phase F: out[q][d] = ( P@V + prel@VR ) * inv ; thread owns d = g*4..g*4+4
    const int d = g * 4;
    float4 acc = {0.f, 0.f, 0.f, 0.f};
    const float* Vb = qkv + (size_t)(b * L_) * 2304 + 1536 + h * HD_ + d;
    for (int k = 0; k < L_; k += 4) {
        float4 p4 = *(const float4*)&S[SIDX(q, k)];
        float4 v0 = *(const float4*)(Vb + (size_t)(k + 0) * 2304);
        float4 v1 = *(const float4*)(Vb + (size_t)(k + 1) * 2304);
        float4 v2 = *(const float4*)(Vb + (size_t)(k + 2) * 2304);
        float4 v3 = *(const float4*)(Vb + (size_t)(k + 3) * 2304);
        acc.x = fmaf(p4.x, v0.x, acc.x); acc.y = fmaf(p4.x, v0.y, acc.y);
        acc.z = fmaf(p4.x, v0.z, acc.z); acc.w = fmaf(p4.x, v0.w, acc.w);
        acc.x = fmaf(p4.y, v1.x, acc.x); acc.y = fmaf(p4.y, v1.y, acc.y);
        acc.z = fmaf(p4.y, v1.z, acc.z); acc.w = fmaf(p4.y, v1.w, acc.w);
        acc.x = fmaf(p4.z, v2.x, acc.x); acc.y = fmaf(p4.z, v2.y, acc.y);
        acc.z = fmaf(p4.z, v2.z, acc.z); acc.w = fmaf(p4.z, v2.w, acc.w);
        acc.x = fmaf(p4.w, v3.x, acc.x); acc.y = fmaf(p4.w, v3.y, acc.y);
        acc.z = fmaf(p4.w, v3.z, acc.z); acc.w = fmaf(p4.w, v3.w, acc.w);
    }
    const float* VRb = kvrel + 768 + h * HD_ + d;
    for (int j = 0; j < NR_; j++) {
        float pr = Rq[RIDX(q, j)];
        float4 vr = *(const float4*)(VRb + (size_t)j * 1536);
        acc.x = fmaf(pr, vr.x, acc.x); acc.y = fmaf(pr, vr.y, acc.y);
        acc.z = fmaf(pr, vr.z, acc.z); acc.w = fmaf(pr, vr.w, acc.w);
    }
    acc.x *= inv; acc.y *= inv; acc.z *= inv; acc.w *= inv;

    __hip_bfloat16* op = ctxb + qrow * H_ + h * HD_ + d;
    union { __hip_bfloat16 h[4]; ushort4 u; } o;
    o.h[0] = __float2bfloat16(acc.x); o.h[1] = __float2bfloat16(acc.y);
    o.h[2] = __float2bfloat16(acc.z); o.h[3] = __float2bfloat16(acc.w);
    *(ushort4*)op = o.u;
}

// ---------------- host ----------------

extern "C" void kernel_launch(void* const* d_in, const int* in_sizes, int n_in,
                              void* d_out, int out_size, void* d_ws, size_t ws_size,
                              hipStream_t stream)
{
    const int*   tok    = (const int*)d_in[0];
    const int*   seg    = (const int*)d_in[1];
    const int*   maskp  = (const int*)d_in[2];
    const float* temb   = (const float*)d_in[3];
    const float* semb   = (const float*)d_in[4];
    const float* esc    = (const float*)d_in[5];
    const float* ebi    = (const float*)d_in[6];
    const float* Wq     = (const float*)d_in[7];
    const float* bq     = (const float*)d_in[8];
    const float* Wk     = (const float*)d_in[9];
    const float* bk     = (const float*)d_in[10];
    const float* Wv     = (const float*)d_in[11];
    const float* bv     = (const float*)d_in[12];
    const float* relpos = (const float*)d_in[13];
    const float* Wo     = (const float*)d_in[14];
    const float* bo     = (const float*)d_in[15];
    const float* ln1s   = (const float*)d_in[16];
    const float* ln1b   = (const float*)d_in[17];
    const float* W1     = (const float*)d_in[18];
    const float* b1     = (const float*)d_in[19];
    const float* W2     = (const float*)d_in[20];
    const float* b2     = (const float*)d_in[21];
    const float* ln2s   = (const float*)d_in[22];
    const float* ln2b   = (const float*)d_in[23];

    const size_t NX = (size_t)ROWS * H_;
    float* x    = (float*)d_ws;
    float* x2   = x + NX;
    float* y    = x2 + NX;
    float* qkv  = y + NX;                                   // 2048*2304 f32
    float* kvrel= qkv + (size_t)ROWS * 2304;                // 255*1536 f32
    float* qkvb = kvrel + (size_t)NR_ * 1536;               // 2304 f32
    __hip_bfloat16* xb   = (__hip_bfloat16*)(qkvb + 2304);
    __hip_bfloat16* x2b  = xb + NX;
    __hip_bfloat16* ctxb = x2b + NX;
    __hip_bfloat16* relb = ctxb + NX;                       // 6*255*768 bf16
    __hip_bfloat16* Wt   = relb + (size_t)NL_ * NR_ * H_;   // 3072*768 bf16 (per-layer reuse)
    __hip_bfloat16* h1b  = (__hip_bfloat16*)qkv;            // alias: 2048*3072 bf16 <= qkv region

    dim3 blk(256);

    embed_ln_kernel<<<ROWS, blk, 0, stream>>>(tok, seg, temb, semb, esc, ebi, x, xb);
    {
        int n = NL_ * NR_ * H_;
        cvt_kernel<<<1024, blk, 0, stream>>>(relpos, relb, n);
    }

    for (int l = 0; l < NL_; l++) {
        const float* wq = Wq + (size_t)l * H_ * H_;
        const float* wk = Wk + (size_t)l * H_ * H_;
        const float* wv = Wv + (size_t)l * H_ * H_;
        const float* wo = Wo + (size_t)l * H_ * H_;
        const float* w1 = W1 + (size_t)l * H_ * M_;
        const float* w2 = W2 + (size_t)l * M_ * H_;

        // pack QKV weights (transposed bf16) + fused bias
        transpose_cvt_kernel<<<dim3(24, 24), blk, 0, stream>>>(wq, Wt, H_, H_);
        transpose_cvt_kernel<<<dim3(24, 24), blk, 0, stream>>>(wk, Wt + (size_t)H_ * H_, H_, H_);
        transpose_cvt_kernel<<<dim3(24, 24), blk, 0, stream>>>(wv, Wt + (size_t)2 * H_ * H_, H_, H_);
        pack_qkv_bias_kernel<<<9, blk, 0, stream>>>(bq + (size_t)l * H_, bk + (size_t)l * H_, bv + (size_t)l * H_, qkvb);

        // QKV projection (fused N=2304) and rel K/V (fused N=1536)
        gemm_bf16_kernel<<<dim3(18, 16), blk, 0, stream>>>(xb, Wt, qkvb, qkv, nullptr, ROWS, 2304, H_, 0);
        gemm_bf16_kernel<<<dim3(12, 2), blk, 0, stream>>>(relb + (size_t)l * NR_ * H_, Wt + (size_t)H_ * H_,
                                                          qkvb + 768, kvrel, nullptr, NR_, 1536, H_, 0);

        attn_kernel<<<dim3(L_ / 16, NH_, B_), blk, 0, stream>>>(qkv, kvrel, maskp, ctxb);

        // O projection
        transpose_cvt_kernel<<<dim3(24, 24), blk, 0, stream>>>(wo, Wt, H_, H_);
        gemm_bf16_kernel<<<dim3(6, 16), blk, 0, stream>>>(ctxb, Wt, bo + (size_t)l * H_, y, nullptr, ROWS, H_, H_, 0);
        add_ln_kernel<<<ROWS, blk, 0, stream>>>(x, y, ln1s + (size_t)l * H_, ln1b + (size_t)l * H_, x2, x2b);

        // MLP
        transpose_cvt_kernel<<<dim3(96, 24), blk, 0, stream>>>(w1, Wt, H_, M_);
        gemm_bf16_kernel<<<dim3(24, 16), blk, 0, stream>>>(x2b, Wt, b1 + (size_t)l * M_, nullptr, h1b, ROWS, M_, H_, 1);
        transpose_cvt_kernel<<<dim3(24, 96), blk, 0, stream>>>(w2, Wt, M_, H_);
        gemm_bf16_kernel<<<dim3(6, 16), blk, 0, stream>>>(h1b, Wt, b2 + (size_t)l * H_, y, nullptr, ROWS, H_, M_, 0);

        float* outp = (l == NL_ - 1) ? (float*)d_out : x;
        __hip_bfloat16* outbp = (l == NL_ - 1) ? nullptr : xb;
        add_ln_kernel<<<ROWS, blk, 0, stream>>>(x2, y, ln2s + (size_t)l * H_, ln2b + (size_t)l * H_, outp, outbp);
    }
}

// Round 3
// 2553.637 us; speedup vs baseline: 5.8731x; 1.7973x over previous
//
#include <hip/hip_runtime.h>
#include <hip/hip_bf16.h>
#include <math.h>

#define B_   4
#define L_   512
#define H_   768
#define NH_  12
#define HD_  64
#define M_   3072
#define NL_  6
#define RD_  128
#define NR_  255          // 2*RD-1
#define ROWS (B_*L_)      // 2048
#define COEF_ 0.125f      // 1/sqrt(64)

typedef __attribute__((ext_vector_type(8))) short bf16x8;
typedef __attribute__((ext_vector_type(4))) float f32x4;

// ---------------- utility ----------------

static __device__ __forceinline__ float wave_reduce_sum(float v) {
#pragma unroll
    for (int off = 32; off > 0; off >>= 1) v += __shfl_xor(v, off, 64);
    return v;
}

static __device__ __forceinline__ float gelu_f(float x) {
    float x3 = x * x * x;
    return 0.5f * x * (1.f + tanhf(0.7978845608028654f * (x + 0.044715f * x3)));
}

static __device__ __forceinline__ unsigned short f2bfu(float v) {
    __hip_bfloat16 h = __float2bfloat16(v);
    return *(unsigned short*)&h;
}

static __device__ __forceinline__ float bfu2f(unsigned short u) {
    union { float f; unsigned int i; } x;
    x.i = ((unsigned int)u) << 16;
    return x.f;
}

// ---------------- embedding + LN (fp32 out + bf16 twin) ----------------

__global__ __launch_bounds__(256) void embed_ln_kernel(
    const int* __restrict__ tok, const int* __restrict__ seg,
    const float* __restrict__ temb, const float* __restrict__ semb,
    const float* __restrict__ sc, const float* __restrict__ bi,
    float* __restrict__ out, __hip_bfloat16* __restrict__ outb)
{
    int row = blockIdx.x;
    int t = threadIdx.x;
    int tid = tok[row], sid = seg[row];
    const float* tp = temb + (size_t)tid * H_;
    const float* sp = semb + (size_t)sid * H_;
    float v[3];
#pragma unroll
    for (int j = 0; j < 3; j++) { int idx = t + j * 256; v[j] = tp[idx] + sp[idx]; }

    __shared__ float red[4];
    __shared__ float bc;
    int lane = t & 63, wid = t >> 6;

    float s = v[0] + v[1] + v[2];
    s = wave_reduce_sum(s);
    if (lane == 0) red[wid] = s;
    __syncthreads();
    if (t == 0) bc = (red[0] + red[1] + red[2] + red[3]) * (1.f / H_);
    __syncthreads();
    float mean = bc;

    float c[3]; float ss = 0.f;
#pragma unroll
    for (int j = 0; j < 3; j++) { c[j] = v[j] - mean; ss += c[j] * c[j]; }
    ss = wave_reduce_sum(ss);
    __syncthreads();
    if (lane == 0) red[wid] = ss;
    __syncthreads();
    if (t == 0) bc = rsqrtf((red[0] + red[1] + red[2] + red[3]) * (1.f / H_) + 1e-12f);
    __syncthreads();
    float r = bc;
#pragma unroll
    for (int j = 0; j < 3; j++) {
        int idx = t + j * 256;
        float o = c[j] * r * sc[idx] + bi[idx];
        out[(size_t)row * H_ + idx] = o;
        outb[(size_t)row * H_ + idx] = __float2bfloat16(o);
    }
}

// ---------------- residual add + LN (fp32 out + optional bf16 twin) ----------------

__global__ __launch_bounds__(256) void add_ln_kernel(
    const float* __restrict__ x, const float* __restrict__ y,
    const float* __restrict__ sc, const float* __restrict__ bi,
    float* __restrict__ out, __hip_bfloat16* __restrict__ outb)
{
    int row = blockIdx.x;
    int t = threadIdx.x;
    const float* xp = x + (size_t)row * H_;
    const float* yp = y + (size_t)row * H_;
    float v[3];
#pragma unroll
    for (int j = 0; j < 3; j++) { int idx = t + j * 256; v[j] = xp[idx] + yp[idx]; }

    __shared__ float red[4];
    __shared__ float bc;
    int lane = t & 63, wid = t >> 6;

    float s = v[0] + v[1] + v[2];
    s = wave_reduce_sum(s);
    if (lane == 0) red[wid] = s;
    __syncthreads();
    if (t == 0) bc = (red[0] + red[1] + red[2] + red[3]) * (1.f / H_);
    __syncthreads();
    float mean = bc;

    float c[3]; float ss = 0.f;
#pragma unroll
    for (int j = 0; j < 3; j++) { c[j] = v[j] - mean; ss += c[j] * c[j]; }
    ss = wave_reduce_sum(ss);
    __syncthreads();
    if (lane == 0) red[wid] = ss;
    __syncthreads();
    if (t == 0) bc = rsqrtf((red[0] + red[1] + red[2] + red[3]) * (1.f / H_) + 1e-12f);
    __syncthreads();
    float r = bc;
#pragma unroll
    for (int j = 0; j < 3; j++) {
        int idx = t + j * 256;
        float o = c[j] * r * sc[idx] + bi[idx];
        out[(size_t)row * H_ + idx] = o;
        if (outb) outb[(size_t)row * H_ + idx] = __float2bfloat16(o);
    }
}

// ---------------- transpose + fp32->bf16 weight pack: in[K][N] f32 -> out[N][K] bf16 ----------------

__global__ __launch_bounds__(256) void transpose_cvt_kernel(
    const float* __restrict__ in, __hip_bfloat16* __restrict__ out, int K, int N)
{
    __shared__ float tile[32][33];
    int bx = blockIdx.x * 32;   // n
    int by = blockIdx.y * 32;   // k
    int tx = threadIdx.x & 31, ty = threadIdx.x >> 5;
#pragma unroll
    for (int i = 0; i < 4; i++)
        tile[ty + 8 * i][tx] = in[(size_t)(by + ty + 8 * i) * N + bx + tx];
    __syncthreads();
#pragma unroll
    for (int i = 0; i < 4; i++)
        out[(size_t)(bx + ty + 8 * i) * K + by + tx] = __float2bfloat16(tile[tx][ty + 8 * i]);
}

__global__ void cvt_kernel(const float* __restrict__ in, __hip_bfloat16* __restrict__ out, int n) {
    int i = blockIdx.x * blockDim.x + threadIdx.x;
    int stride = gridDim.x * blockDim.x;
    for (; i < n; i += stride) out[i] = __float2bfloat16(in[i]);
}

__global__ void pack_qkv_bias_kernel(const float* __restrict__ bq, const float* __restrict__ bk,
                                     const float* __restrict__ bv, float* __restrict__ out) {
    int i = blockIdx.x * 256 + threadIdx.x;
    if (i >= 2304) return;
    out[i] = i < 768 ? bq[i] : (i < 1536 ? bk[i - 768] : bv[i - 1536]);
}

__global__ void zero_vrt_pad_kernel(__hip_bfloat16* __restrict__ vrT) {
    int i = blockIdx.x * 256 + threadIdx.x;
    if (i < NH_ * 64) vrT[(size_t)i * 256 + 255] = __float2bfloat16(0.f);
}

// ---------------- bf16 MFMA GEMM: C[M,N] = A[M,K] @ Bt[N,K]^T + bias ----------------
// modes: 0 = f32 out Cf[M][N] (+gelu if act), 1 = bf16 out Cb[M][N] (+gelu),
//        2 = QKV: col<1536 -> Cb stride 1536 (Q|K); col>=1536 -> aux = vT[b][h][64][512] transposed
//        3 = REL: col<768  -> Cb stride 768  (KR);  col>=768  -> aux = vrT[h][64][256] transposed

#define TK 64

static __device__ __forceinline__ void gemm_load_tile(
    const __hip_bfloat16* A, const __hip_bfloat16* Bt, int M, int K,
    int bm, int bn, int srow, int scolb, int k0, uint4* av, uint4* bv)
{
#pragma unroll
    for (int c = 0; c < 4; c++) {
        int r = srow + c * 32;
        int gr = bm + r; if (gr >= M) gr = M - 1;
        av[c] = *(const uint4*)((const char*)(A + (size_t)gr * K + k0) + scolb);
        bv[c] = *(const uint4*)((const char*)(Bt + (size_t)(bn + r) * K + k0) + scolb);
    }
}

__global__ __launch_bounds__(256) void gemm_bf16_kernel(
    const __hip_bfloat16* __restrict__ A, const __hip_bfloat16* __restrict__ Bt,
    const float* __restrict__ bias, float* __restrict__ Cf, __hip_bfloat16* __restrict__ Cb,
    __hip_bfloat16* __restrict__ aux,
    int M, int N, int K, int act, int mode)
{
    __shared__ __hip_bfloat16 As[128 * TK];
    __shared__ __hip_bfloat16 Bs[128 * TK];
    const int t = threadIdx.x;
    const int lane = t & 63;
    const int wid = t >> 6;
    const int wm = (wid >> 1) * 64, wn = (wid & 1) * 64;
    const int bm = blockIdx.y * 128, bn = blockIdx.x * 128;

    f32x4 acc[4][4];
#pragma unroll
    for (int i = 0; i < 4; i++)
#pragma unroll
        for (int j = 0; j < 4; j++) acc[i][j] = (f32x4){0.f, 0.f, 0.f, 0.f};

    const int srow = t >> 3;
    const int scolb = (t & 7) * 16;
    const int nt = K / TK;
    uint4 av[4], bv[4];

    gemm_load_tile(A, Bt, M, K, bm, bn, srow, scolb, 0, av, bv);

    for (int kt = 0; kt < nt; kt++) {
        __syncthreads();
#pragma unroll
        for (int c = 0; c < 4; c++) {
            int r = srow + c * 32;
            int off = r * 128 + (scolb ^ ((r & 7) << 4));
            *(uint4*)((char*)As + off) = av[c];
            *(uint4*)((char*)Bs + off) = bv[c];
        }
        __syncthreads();
        if (kt + 1 < nt)
            gemm_load_tile(A, Bt, M, K, bm, bn, srow, scolb, (kt + 1) * TK, av, bv);
#pragma unroll
        for (int kh = 0; kh < 2; kh++) {
            const int kb = kh * 64 + (lane >> 4) * 16;
            bf16x8 af[4], bfr[4];
#pragma unroll
            for (int i = 0; i < 4; i++) {
                int ra = wm + i * 16 + (lane & 15);
                af[i] = *(const bf16x8*)((const char*)As + ra * 128 + (kb ^ ((ra & 7) << 4)));
                int rb = wn + i * 16 + (lane & 15);
                bfr[i] = *(const bf16x8*)((const char*)Bs + rb * 128 + (kb ^ ((rb & 7) << 4)));
            }
#pragma unroll
            for (int i = 0; i < 4; i++)
#pragma unroll
                for (int j = 0; j < 4; j++)
                    acc[i][j] = __builtin_amdgcn_mfma_f32_16x16x32_bf16(af[i], bfr[j], acc[i][j], 0, 0, 0);
        }
    }

    const int lr = (lane >> 4) * 4;
    const int lc = lane & 15;
#pragma unroll
    for (int i = 0; i < 4; i++) {
#pragma unroll
        for (int j = 0; j < 4; j++) {
            int col = bn + wn + j * 16 + lc;
            float bsv = bias[col];
            int row0 = bm + wm + i * 16 + lr;
            if (mode == 2) {
                if (col >= 1536) {
                    int hh = (col - 1536) >> 6, dd = (col - 1536) & 63;
                    int bb = row0 >> 9, key = row0 & 511;
                    ushort4 o;
                    o.x = f2bfu(acc[i][j][0] + bsv);
                    o.y = f2bfu(acc[i][j][1] + bsv);
                    o.z = f2bfu(acc[i][j][2] + bsv);
                    o.w = f2bfu(acc[i][j][3] + bsv);
                    *(ushort4*)(aux + ((((size_t)(bb * NH_ + hh)) << 6) + dd) * 512 + key) = o;
                } else {
#pragma unroll
                    for (int rr = 0; rr < 4; rr++)
                        Cb[(size_t)(row0 + rr) * 1536 + col] = __float2bfloat16(acc[i][j][rr] + bsv);
                }
            } else if (mode == 3) {
                if (col >= 768) {
                    int hh = (col - 768) >> 6, dd = (col - 768) & 63;
                    __hip_bfloat16* dst = aux + (((size_t)hh * 64 + dd) << 8);
                    if (row0 + 3 < M) {
                        ushort4 o;
                        o.x = f2bfu(acc[i][j][0] + bsv);
                        o.y = f2bfu(acc[i][j][1] + bsv);
                        o.z = f2bfu(acc[i][j][2] + bsv);
                        o.w = f2bfu(acc[i][j][3] + bsv);
                        *(ushort4*)(dst + row0) = o;
                    } else {
#pragma unroll
                        for (int rr = 0; rr < 4; rr++)
                            if (row0 + rr < M) dst[row0 + rr] = __float2bfloat16(acc[i][j][rr] + bsv);
                    }
                } else {
#pragma unroll
                    for (int rr = 0; rr < 4; rr++)
                        if (row0 + rr < M) Cb[(size_t)(row0 + rr) * 768 + col] = __float2bfloat16(acc[i][j][rr] + bsv);
                }
            } else {
#pragma unroll
                for (int rr = 0; rr < 4; rr++) {
                    int row = row0 + rr;
                    if (row >= M) continue;
                    float v = acc[i][j][rr] + bsv;
                    if (act) v = gelu_f(v);
                    if (mode == 1) Cb[(size_t)row * N + col] = __float2bfloat16(v);
                    else           Cf[(size_t)row * N + col] = v;
                }
            }
        }
    }
}

// ---------------- MFMA rel-pos attention ----------------
// grid (L/32, NH, B), 256 threads (4 waves). 32 q-rows per block.
// R = Q@KR^T (LDS bf16) ; S = Q@K^T + R[jc] + mask ; softmax (cross-wave stats) ;
// P -> LDS bf16 ; prel built in parallel ; out = (P@V^T + prel@VR^T) * inv.

#define PS_LD 520   // bf16 elems per Ps row (512 + 8 pad)
#define PR_LD 264   // bf16 elems per Rq/prel row (256 + 8 pad)

__global__ __launch_bounds__(256) void attn_kernel(
    const __hip_bfloat16* __restrict__ qkb,   // [2048][1536] = Q|K
    const __hip_bfloat16* __restrict__ vT,    // [B][NH][64][512]
    const __hip_bfloat16* __restrict__ krb,   // [255][768]
    const __hip_bfloat16* __restrict__ vrT,   // [NH][64][256] (col 255 zeroed)
    const int* __restrict__ mask,
    __hip_bfloat16* __restrict__ ctxb)        // [2048][768]
{
    __shared__ unsigned short RqPrel[32 * PR_LD];  // Rq (bf16), later prel (bf16)
    __shared__ unsigned short Ps[32 * PS_LD];      // probs (bf16, un-normalized)
    __shared__ float mstat[32 * 4];
    __shared__ float sstat[32 * 4];
    __shared__ float maskb[512];

    const int qt = blockIdx.x, h = blockIdx.y, b = blockIdx.z;
    const int t = threadIdx.x;
    const int lane = t & 63, w = t >> 6;
    const int lq = lane & 15, lg = lane >> 4;

    maskb[t]       = mask[b * L_ + t]       ? 0.f : -1e30f;
    maskb[t + 256] = mask[b * L_ + t + 256] ? 0.f : -1e30f;

    const char* Qbase = (const char*)qkb + ((size_t)(b * L_ + qt * 32) * 1536 + h * 64) * 2;
    const char* Kbase = (const char*)qkb + ((size_t)(b * L_) * 1536 + 768 + h * 64) * 2;

    // ---- R phase: Rq[32][256] = Q @ KR^T ----
    {
        f32x4 accr[2][4];
#pragma unroll
        for (int i = 0; i < 2; i++)
#pragma unroll
            for (int j = 0; j < 4; j++) accr[i][j] = (f32x4){0.f, 0.f, 0.f, 0.f};
#pragma unroll
        for (int ks = 0; ks < 2; ks++) {
            const int kofs = ks * 64 + lg * 16;
            bf16x8 af0 = *(const bf16x8*)(Qbase + (size_t)lq * 3072 + kofs);
            bf16x8 af1 = *(const bf16x8*)(Qbase + (size_t)(16 + lq) * 3072 + kofs);
#pragma unroll
            for (int jt = 0; jt < 4; jt++) {
                int j = w * 64 + jt * 16 + lq;
                int jr = j > 254 ? 254 : j;
                bf16x8 bf = *(const bf16x8*)((const char*)krb + ((size_t)jr * 768 + h * 64) * 2 + kofs);
                accr[0][jt] = __builtin_amdgcn_mfma_f32_16x16x32_bf16(af0, bf, accr[0][jt], 0, 0, 0);
                accr[1][jt] = __builtin_amdgcn_mfma_f32_16x16x32_bf16(af1, bf, accr[1][jt], 0, 0, 0);
            }
        }
#pragma unroll
        for (int it = 0; it < 2; it++)
#pragma unroll
            for (int jt = 0; jt < 4; jt++)
#pragma unroll
                for (int r = 0; r < 4; r++)
                    RqPrel[(it * 16 + lg * 4 + r) * PR_LD + w * 64 + jt * 16 + lq] = f2bfu(accr[it][jt][r]);
    }
    __syncthreads();

    // ---- S phase: accs[2][8] = Q @ K^T (wave w owns key strip w*128..+128) ----
    f32x4 accs[2][8];
#pragma unroll
    for (int i = 0; i < 2; i++)
#pragma unroll
        for (int j = 0; j < 8; j++) accs[i][j] = (f32x4){0.f, 0.f, 0.f, 0.f};
#pragma unroll
    for (int ks = 0; ks < 2; ks++) {
        const int kofs = ks * 64 + lg * 16;
        bf16x8 af0 = *(const bf16x8*)(Qbase + (size_t)lq * 3072 + kofs);
        bf16x8 af1 = *(const bf16x8*)(Qbase + (size_t)(16 + lq) * 3072 + kofs);
#pragma unroll
        for (int jt = 0; jt < 8; jt++) {
            int key = w * 128 + jt * 16 + lq;
            bf16x8 bf = *(const bf16x8*)(Kbase + (size_t)key * 3072 + kofs);
            accs[0][jt] = __builtin_amdgcn_mfma_f32_16x16x32_bf16(af0, bf, accs[0][jt], 0, 0, 0);
            accs[1][jt] = __builtin_amdgcn_mfma_f32_16x16x32_bf16(af1, bf, accs[1][jt], 0, 0, 0);
        }
    }

    // ---- S epilogue: add rel score + mask ----
    float rmx[2][4];
#pragma unroll
    for (int it = 0; it < 2; it++) {
#pragma unroll
        for (int r = 0; r < 4; r++) {
            int q = it * 16 + lg * 4 + r;
            int qg = qt * 32 + q;
            float mx = -INFINITY;
#pragma unroll
            for (int jt = 0; jt < 8; jt++) {
                int k = w * 128 + jt * 16 + lq;
                int jc = k - qg + 127;
                jc = jc < 0 ? 0 : (jc > 254 ? 254 : jc);
                float s = (accs[it][jt][r] + bfu2f(RqPrel[q * PR_LD + jc])) * COEF_ + maskb[k];
                accs[it][jt][r] = s;
                mx = fmaxf(mx, s);
            }
            // wave-local row max across the 16 col-lanes
#pragma unroll
            for (int off = 1; off < 16; off <<= 1) mx = fmaxf(mx, __shfl_xor(mx, off, 64));
            rmx[it][r] = mx;
            if (lq == 0) mstat[q * 4 + w] = mx;
        }
    }
    __syncthreads();

    // ---- exp + row sums + write P ----
#pragma unroll
    for (int it = 0; it < 2; it++) {
#pragma unroll
        for (int r = 0; r < 4; r++) {
            int q = it * 16 + lg * 4 + r;
            float4 mv = *(const float4*)&mstat[q * 4];
            float gm = fmaxf(fmaxf(mv.x, mv.y), fmaxf(mv.z, mv.w));
            float ssum = 0.f;
#pragma unroll
            for (int jt = 0; jt < 8; jt++) {
                int k = w * 128 + jt * 16 + lq;
                float p = __expf(accs[it][jt][r] - gm);
                ssum += p;
                Ps[q * PS_LD + k] = f2bfu(p);
            }
#pragma unroll
            for (int off = 1; off < 16; off <<= 1) ssum += __shfl_xor(ssum, off, 64);
            if (lq == 0) sstat[q * 4 + w] = ssum;
        }
    }
    __syncthreads();

    // ---- prel construction (into RqPrel, aliasing dead Rq) ----
    {
        int q = t >> 3, sub = t & 7;
        int qg = qt * 32 + q;
#pragma unroll
        for (int jj = 0; jj < 32; jj++) {
            int j = sub + 8 * jj;
            if (j == 0 || j == 254) continue;
            if (j == 255) { RqPrel[q * PR_LD + 255] = 0; continue; }
            int k = qg + j - 127;
            unsigned short val = ((unsigned)k < 512u) ? Ps[q * PS_LD + k] : (unsigned short)0;
            RqPrel[q * PR_LD + j] = val;
        }
    }
    {
        int task = t >> 2, ts = t & 3;
        int q = task >> 1, side = task & 1;
        int qg = qt * 32 + q;
        float sum = 0.f;
        if (side == 0) {
            int hi = qg - 127;
            for (int k = ts; k <= hi; k += 4) sum += bfu2f(Ps[q * PS_LD + k]);
        } else {
            for (int k = qg + 127 + ts; k < 512; k += 4) sum += bfu2f(Ps[q * PS_LD + k]);
        }
        sum += __shfl_xor(sum, 1, 64);
        sum += __shfl_xor(sum, 2, 64);
        if (ts == 0) RqPrel[q * PR_LD + (side == 0 ? 0 : 254)] = f2bfu(sum);
    }
    __syncthreads();

    // ---- PV phase: out strip d in [w*16, w*16+16) ----
    f32x4 accv[2];
    accv[0] = (f32x4){0.f, 0.f, 0.f, 0.f};
    accv[1] = (f32x4){0.f, 0.f, 0.f, 0.f};

    const __hip_bfloat16* vTb = vT + (((size_t)(b * NH_ + h) * 64) + w * 16 + lq) * 512 + lg * 8;
#pragma unroll
    for (int ks = 0; ks < 16; ks++) {
        bf16x8 bv = *(const bf16x8*)(vTb + ks * 32);
        bf16x8 pa0 = *(const bf16x8*)((const char*)Ps + (size_t)lq * (PS_LD * 2) + ks * 64 + lg * 16);
        bf16x8 pa1 = *(const bf16x8*)((const char*)Ps + (size_t)(16 + lq) * (PS_LD * 2) + ks * 64 + lg * 16);
        accv[0] = __builtin_amdgcn_mfma_f32_16x16x32_bf16(pa0, bv, accv[0], 0, 0, 0);
        accv[1] = __builtin_amdgcn_mfma_f32_16x16x32_bf16(pa1, bv, accv[1], 0, 0, 0);
    }
    const __hip_bfloat16* vrTb = vrT + ((size_t)(h * 64) + w * 16 + lq) * 256 + lg * 8;
#pragma unroll
    for (int ks = 0; ks < 8; ks++) {
        bf16x8 bv = *(const bf16x8*)(vrTb + ks * 32);
        bf16x8 pa0 = *(const bf16x8*)((const char*)RqPrel + (size_t)lq * (PR_LD * 2) + ks * 64 + lg * 16);
        bf16x8 pa1 = *(const bf16x8*)((const char*)RqPrel + (size_t)(16 + lq) * (PR_LD * 2) + ks * 64 + lg * 16);
        accv[0] = __builtin_amdgcn_mfma_f32_16x16x32_bf16(pa0, bv, accv[0], 0, 0, 0);
        accv[1] = __builtin_amdgcn_mfma_f32_16x16x32_bf16(pa1, bv, accv[1], 0, 0, 0);
    }

#pragma unroll
    for (int it = 0; it < 2; it++) {
#pragma unroll
        for (int r = 0; r < 4; r++) {
            int q = it * 16 + lg * 4 + r;
            float4 sv = *(const float4*)&sstat[q * 4];
            float inv = 1.f / (sv.x + sv.y + sv.z + sv.w);
            ctxb[(size_t)(b * L_ + qt * 32 + q) * 768 + h * 64 + w * 16 + lq] =
                __float2bfloat16(accv[it][r] * inv);
        }
    }
}

// ---------------- host ----------------

extern "C" void kernel_launch(void* const* d_in, const int* in_sizes, int n_in,
                              void* d_out, int out_size, void* d_ws, size_t ws_size,
                              hipStream_t stream)
{
    const int*   tok    = (const int*)d_in[0];
    const int*   seg    = (const int*)d_in[1];
    const int*   maskp  = (const int*)d_in[2];
    const float* temb   = (const float*)d_in[3];
    const float* semb   = (const float*)d_in[4];
    const float* esc    = (const float*)d_in[5];
    const float* ebi    = (const float*)d_in[6];
    const float* Wq     = (const float*)d_in[7];
    const float* bq     = (const float*)d_in[8];
    const float* Wk     = (const float*)d_in[9];
    const float* bk     = (const float*)d_in[10];
    const float* Wv     = (const float*)d_in[11];
    const float* bv     = (const float*)d_in[12];
    const float* relpos = (const float*)d_in[13];
    const float* Wo     = (const float*)d_in[14];
    const float* bo     = (const float*)d_in[15];
    const float* ln1s   = (const float*)d_in[16];
    const float* ln1b   = (const float*)d_in[17];
    const float* W1     = (const float*)d_in[18];
    const float* b1     = (const float*)d_in[19];
    const float* W2     = (const float*)d_in[20];
    const float* b2     = (const float*)d_in[21];
    const float* ln2s   = (const float*)d_in[22];
    const float* ln2b   = (const float*)d_in[23];

    const size_t NX = (size_t)ROWS * H_;
    float* x       = (float*)d_ws;
    float* x2      = x + NX;
    float* y       = x2 + NX;
    float* qkvbias = y + NX;                         // 2304 f32
    __hip_bfloat16* xb   = (__hip_bfloat16*)(qkvbias + 2304);
    __hip_bfloat16* x2b  = xb   + NX;
    __hip_bfloat16* ctxb = x2b  + NX;
    __hip_bfloat16* qkb  = ctxb + NX;                          // 2048*1536
    __hip_bfloat16* vT   = qkb  + (size_t)ROWS * 1536;         // 4*12*64*512
    __hip_bfloat16* krb  = vT   + (size_t)B_ * NH_ * 64 * 512; // 255*768
    __hip_bfloat16* vrT  = krb  + (size_t)NR_ * H_;            // 12*64*256
    __hip_bfloat16* relb = vrT  + (size_t)NH_ * 64 * 256;      // 6*255*768
    __hip_bfloat16* Wt   = relb + (size_t)NL_ * NR_ * H_;      // 3072*768
    __hip_bfloat16* h1b  = Wt   + (size_t)M_ * H_;             // 2048*3072

    dim3 blk(256);

    embed_ln_kernel<<<ROWS, blk, 0, stream>>>(tok, seg, temb, semb, esc, ebi, x, xb);
    cvt_kernel<<<1024, blk, 0, stream>>>(relpos, relb, NL_ * NR_ * H_);
    zero_vrt_pad_kernel<<<3, blk, 0, stream>>>(vrT);

    for (int l = 0; l < NL_; l++) {
        const float* wq = Wq + (size_t)l * H_ * H_;
        const float* wk = Wk + (size_t)l * H_ * H_;
        const float* wv = Wv + (size_t)l * H_ * H_;
        const float* wo = Wo + (size_t)l * H_ * H_;
        const float* w1 = W1 + (size_t)l * H_ * M_;
        const float* w2 = W2 + (size_t)l * M_ * H_;

        transpose_cvt_kernel<<<dim3(24, 24), blk, 0, stream>>>(wq, Wt, H_, H_);
        transpose_cvt_kernel<<<dim3(24, 24), blk, 0, stream>>>(wk, Wt + (size_t)H_ * H_, H_, H_);
        transpose_cvt_kernel<<<dim3(24, 24), blk, 0, stream>>>(wv, Wt + (size_t)2 * H_ * H_, H_, H_);
        pack_qkv_bias_kernel<<<9, blk, 0, stream>>>(bq + (size_t)l * H_, bk + (size_t)l * H_, bv + (size_t)l * H_, qkvbias);

        // QKV: Q|K row-major bf16 + V transposed
        gemm_bf16_kernel<<<dim3(18, 16), blk, 0, stream>>>(xb, Wt, qkvbias, nullptr, qkb, vT,
                                                           ROWS, 2304, H_, 0, 2);
        // rel K/V: KR row-major + VR transposed
        gemm_bf16_kernel<<<dim3(12, 2), blk, 0, stream>>>(relb + (size_t)l * NR_ * H_, Wt + (size_t)H_ * H_,
                                                          qkvbias + 768, nullptr, krb, vrT,
                                                          NR_, 1536, H_, 0, 3);

        attn_kernel<<<dim3(L_ / 32, NH_, B_), blk, 0, stream>>>(qkb, vT, krb, vrT, maskp, ctxb);

        transpose_cvt_kernel<<<dim3(24, 24), blk, 0, stream>>>(wo, Wt, H_, H_);
        gemm_bf16_kernel<<<dim3(6, 16), blk, 0, stream>>>(ctxb, Wt, bo + (size_t)l * H_, y, nullptr, nullptr,
                                                          ROWS, H_, H_, 0, 0);
        add_ln_kernel<<<ROWS, blk, 0, stream>>>(x, y, ln1s + (size_t)l * H_, ln1b + (size_t)l * H_, x2, x2b);

        transpose_cvt_kernel<<<dim3(96, 24), blk, 0, stream>>>(w1, Wt, H_, M_);
        gemm_bf16_kernel<<<dim3(24, 16), blk, 0, stream>>>(x2b, Wt, b1 + (size_t)l * M_, nullptr, h1b, nullptr,
                                                           ROWS, M_, H_, 1, 1);
        transpose_cvt_kernel<<<dim3(24, 96), blk, 0, stream>>>(w2, Wt, M_, H_);
        gemm_bf16_kernel<<<dim3(6, 16), blk, 0, stream>>>(h1b, Wt, b2 + (size_t)l * H_, y, nullptr, nullptr,
                                                          ROWS, H_, M_, 0, 0);

        float* outp = (l == NL_ - 1) ? (float*)d_out : x;
        __hip_bfloat16* outbp = (l == NL_ - 1) ? nullptr : xb;
        add_ln_kernel<<<ROWS, blk, 0, stream>>>(x2, y, ln2s + (size_t)l * H_, ln2b + (size_t)l * H_, outp, outbp);
    }
}

// Round 4
// 1480.142 us; speedup vs baseline: 10.1326x; 1.7253x over previous
//
#include <hip/hip_runtime.h>
#include <hip/hip_bf16.h>
#include <math.h>

#define B_   4
#define L_   512
#define H_   768
#define NH_  12
#define HD_  64
#define M_   3072
#define NL_  6
#define RD_  128
#define NR_  255          // 2*RD-1
#define ROWS (B_*L_)      // 2048
#define COEF_ 0.125f      // 1/sqrt(64)

typedef __attribute__((ext_vector_type(8))) short bf16x8;
typedef __attribute__((ext_vector_type(4))) float f32x4;

// ---------------- utility ----------------

static __device__ __forceinline__ float wave_reduce_sum(float v) {
#pragma unroll
    for (int off = 32; off > 0; off >>= 1) v += __shfl_xor(v, off, 64);
    return v;
}

static __device__ __forceinline__ float gelu_f(float x) {
    float x3 = x * x * x;
    return 0.5f * x * (1.f + tanhf(0.7978845608028654f * (x + 0.044715f * x3)));
}

static __device__ __forceinline__ unsigned short f2bfu(float v) {
    __hip_bfloat16 h = __float2bfloat16(v);
    return *(unsigned short*)&h;
}

static __device__ __forceinline__ float bfu2f(unsigned short u) {
    union { float f; unsigned int i; } x;
    x.i = ((unsigned int)u) << 16;
    return x.f;
}

// async global->LDS, 16B per lane; LDS dest = wave-uniform base + lane*16
static __device__ __forceinline__ void gload16(const void* g, void* l) {
    __builtin_amdgcn_global_load_lds(
        (const __attribute__((address_space(1))) void*)g,
        (__attribute__((address_space(3))) void*)l,
        16, 0, 0);
}

// ---------------- embedding + LN (fp32 out + bf16 twin) ----------------

__global__ __launch_bounds__(256) void embed_ln_kernel(
    const int* __restrict__ tok, const int* __restrict__ seg,
    const float* __restrict__ temb, const float* __restrict__ semb,
    const float* __restrict__ sc, const float* __restrict__ bi,
    float* __restrict__ out, __hip_bfloat16* __restrict__ outb)
{
    int row = blockIdx.x;
    int t = threadIdx.x;
    int tid = tok[row], sid = seg[row];
    const float* tp = temb + (size_t)tid * H_;
    const float* sp = semb + (size_t)sid * H_;
    float v[3];
#pragma unroll
    for (int j = 0; j < 3; j++) { int idx = t + j * 256; v[j] = tp[idx] + sp[idx]; }

    __shared__ float red[4];
    __shared__ float bc;
    int lane = t & 63, wid = t >> 6;

    float s = v[0] + v[1] + v[2];
    s = wave_reduce_sum(s);
    if (lane == 0) red[wid] = s;
    __syncthreads();
    if (t == 0) bc = (red[0] + red[1] + red[2] + red[3]) * (1.f / H_);
    __syncthreads();
    float mean = bc;

    float c[3]; float ss = 0.f;
#pragma unroll
    for (int j = 0; j < 3; j++) { c[j] = v[j] - mean; ss += c[j] * c[j]; }
    ss = wave_reduce_sum(ss);
    __syncthreads();
    if (lane == 0) red[wid] = ss;
    __syncthreads();
    if (t == 0) bc = rsqrtf((red[0] + red[1] + red[2] + red[3]) * (1.f / H_) + 1e-12f);
    __syncthreads();
    float r = bc;
#pragma unroll
    for (int j = 0; j < 3; j++) {
        int idx = t + j * 256;
        float o = c[j] * r * sc[idx] + bi[idx];
        out[(size_t)row * H_ + idx] = o;
        outb[(size_t)row * H_ + idx] = __float2bfloat16(o);
    }
}

// ---------------- residual add + LN (fp32 out + optional bf16 twin) ----------------

__global__ __launch_bounds__(256) void add_ln_kernel(
    const float* __restrict__ x, const float* __restrict__ y,
    const float* __restrict__ sc, const float* __restrict__ bi,
    float* __restrict__ out, __hip_bfloat16* __restrict__ outb)
{
    int row = blockIdx.x;
    int t = threadIdx.x;
    const float* xp = x + (size_t)row * H_;
    const float* yp = y + (size_t)row * H_;
    float v[3];
#pragma unroll
    for (int j = 0; j < 3; j++) { int idx = t + j * 256; v[j] = xp[idx] + yp[idx]; }

    __shared__ float red[4];
    __shared__ float bc;
    int lane = t & 63, wid = t >> 6;

    float s = v[0] + v[1] + v[2];
    s = wave_reduce_sum(s);
    if (lane == 0) red[wid] = s;
    __syncthreads();
    if (t == 0) bc = (red[0] + red[1] + red[2] + red[3]) * (1.f / H_);
    __syncthreads();
    float mean = bc;

    float c[3]; float ss = 0.f;
#pragma unroll
    for (int j = 0; j < 3; j++) { c[j] = v[j] - mean; ss += c[j] * c[j]; }
    ss = wave_reduce_sum(ss);
    __syncthreads();
    if (lane == 0) red[wid] = ss;
    __syncthreads();
    if (t == 0) bc = rsqrtf((red[0] + red[1] + red[2] + red[3]) * (1.f / H_) + 1e-12f);
    __syncthreads();
    float r = bc;
#pragma unroll
    for (int j = 0; j < 3; j++) {
        int idx = t + j * 256;
        float o = c[j] * r * sc[idx] + bi[idx];
        out[(size_t)row * H_ + idx] = o;
        if (outb) outb[(size_t)row * H_ + idx] = __float2bfloat16(o);
    }
}

// ---------------- transpose + fp32->bf16 weight pack: in[K][N] f32 -> out[N][K] bf16 ----------------

__global__ __launch_bounds__(256) void transpose_cvt_kernel(
    const float* __restrict__ in, __hip_bfloat16* __restrict__ out, int K, int N)
{
    __shared__ float tile[32][33];
    int bx = blockIdx.x * 32;   // n
    int by = blockIdx.y * 32;   // k
    int tx = threadIdx.x & 31, ty = threadIdx.x >> 5;
#pragma unroll
    for (int i = 0; i < 4; i++)
        tile[ty + 8 * i][tx] = in[(size_t)(by + ty + 8 * i) * N + bx + tx];
    __syncthreads();
#pragma unroll
    for (int i = 0; i < 4; i++)
        out[(size_t)(bx + ty + 8 * i) * K + by + tx] = __float2bfloat16(tile[tx][ty + 8 * i]);
}

__global__ void cvt_kernel(const float* __restrict__ in, __hip_bfloat16* __restrict__ out, int n) {
    int i = blockIdx.x * blockDim.x + threadIdx.x;
    int stride = gridDim.x * blockDim.x;
    for (; i < n; i += stride) out[i] = __float2bfloat16(in[i]);
}

__global__ void pack_qkv_bias_kernel(const float* __restrict__ bq, const float* __restrict__ bk,
                                     const float* __restrict__ bv, float* __restrict__ out) {
    int i = blockIdx.x * 256 + threadIdx.x;
    if (i >= 2304) return;
    out[i] = i < 768 ? bq[i] : (i < 1536 ? bk[i - 768] : bv[i - 1536]);
}

// ---------------- V transpose: qkvb[2048][2304] cols 1536.. -> vT[b][h][64][512] ----------------

__global__ __launch_bounds__(256) void transpose_v_kernel(
    const __hip_bfloat16* __restrict__ qkvb, __hip_bfloat16* __restrict__ vT)
{
    __shared__ unsigned short tile[64][72];
    const int kb = blockIdx.x * 64;          // global row block (b*512 + key)
    const int h  = blockIdx.y;
    const int t = threadIdx.x;
    const int r = t >> 2, c0 = (t & 3) * 16;
    const unsigned short* src = (const unsigned short*)qkvb + (size_t)(kb + r) * 2304 + 1536 + h * 64 + c0;
    *(uint4*)&tile[r][c0]     = *(const uint4*)src;
    *(uint4*)&tile[r][c0 + 8] = *(const uint4*)(src + 8);
    __syncthreads();
    const int d = r, k0 = c0;
    unsigned short outv[16];
#pragma unroll
    for (int i = 0; i < 16; i++) outv[i] = tile[k0 + i][d];
    unsigned short* dst = (unsigned short*)vT +
        ((size_t)((kb >> 9) * NH_ + h) * 64 + d) * 512 + (kb & 511) + k0;
    *(uint4*)dst       = *(uint4*)&outv[0];
    *(uint4*)(dst + 8) = *(uint4*)&outv[8];
}

// ---------------- VR transpose: krvr[255][1536] cols 768.. -> vrT[h][64][256] (j>=255 -> 0) ----------------

__global__ __launch_bounds__(256) void transpose_vr_kernel(
    const __hip_bfloat16* __restrict__ krvr, __hip_bfloat16* __restrict__ vrT)
{
    __shared__ unsigned short tile[64][72];
    const int jb = blockIdx.x * 64;
    const int h  = blockIdx.y;
    const int t = threadIdx.x;
    const int r = t >> 2, c0 = (t & 3) * 16;
    const int j = jb + r;
    if (j < NR_) {
        const unsigned short* src = (const unsigned short*)krvr + (size_t)j * 1536 + 768 + h * 64 + c0;
        *(uint4*)&tile[r][c0]     = *(const uint4*)src;
        *(uint4*)&tile[r][c0 + 8] = *(const uint4*)(src + 8);
    } else {
#pragma unroll
        for (int i = 0; i < 16; i++) tile[r][c0 + i] = 0;
    }
    __syncthreads();
    const int d = r, k0 = c0;
    unsigned short outv[16];
#pragma unroll
    for (int i = 0; i < 16; i++) outv[i] = tile[k0 + i][d];
    unsigned short* dst = (unsigned short*)vrT + ((size_t)(h * 64) + d) * 256 + jb + k0;
    *(uint4*)dst       = *(uint4*)&outv[0];
    *(uint4*)(dst + 8) = *(uint4*)&outv[8];
}

// ---------------- bf16 MFMA GEMM (m97 recipe): C[M,N] = A[M,K] @ Bt[N,K]^T + bias ----------------
// global_load_lds width-16 staging, linear LDS dest + pre-swizzled global src,
// XOR-swizzled ds_read_b128, 2-barrier K-loop, XCD-contiguous block remap.
// Cb != nullptr -> bf16 out, else fp32 out. act=1 -> gelu. Requires N%128==0, K%64==0, nwg%8==0.

#define TK 64

__global__ __launch_bounds__(256) void gemm_bf16_kernel(
    const __hip_bfloat16* __restrict__ A, const __hip_bfloat16* __restrict__ Bt,
    const float* __restrict__ bias, float* __restrict__ Cf, __hip_bfloat16* __restrict__ Cb,
    int M, int N, int K, int act)
{
    __shared__ __hip_bfloat16 As[128 * TK];
    __shared__ __hip_bfloat16 Bs[128 * TK];
    const int t = threadIdx.x;
    const int lane = t & 63;
    const int w = t >> 6;
    const int lq = lane & 15, lg = lane >> 4;
    const int wm = (w >> 1) * 64, wn = (w & 1) * 64;

    // XCD-contiguous remap (consecutive HW ids round-robin XCDs; make each XCD's chunk contiguous)
    const int nbx = gridDim.x;
    const int nwg = nbx * gridDim.y;
    int wgid = blockIdx.y * nbx + blockIdx.x;
    { int qq = nwg >> 3; wgid = (wgid & 7) * qq + (wgid >> 3); }
    const int bm = (wgid / nbx) * 128, bn = (wgid % nbx) * 128;

    f32x4 acc[4][4];
#pragma unroll
    for (int i = 0; i < 4; i++)
#pragma unroll
        for (int j = 0; j < 4; j++) acc[i][j] = (f32x4){0.f, 0.f, 0.f, 0.f};

    // staging addresses: lane covers row (base + lane>>3), 16B at pre-swizzled col
    const int rlane = lane >> 3;
    const int cswz = (((lane & 7) * 16) ^ ((rlane & 7) << 4)) >> 1;   // elements
    const __hip_bfloat16* ga[4];
    const __hip_bfloat16* gb[4];
    __hip_bfloat16* la[4];
    __hip_bfloat16* lb[4];
#pragma unroll
    for (int c = 0; c < 4; c++) {
        int rowa = bm + w * 32 + c * 8 + rlane; if (rowa >= M) rowa = M - 1;
        int rowb = bn + w * 32 + c * 8 + rlane;
        ga[c] = A  + (size_t)rowa * K + cswz;
        gb[c] = Bt + (size_t)rowb * K + cswz;
        la[c] = &As[(w * 32 + c * 8) * TK];
        lb[c] = &Bs[(w * 32 + c * 8) * TK];
    }

    const int nt = K / TK;
    for (int kt = 0; kt < nt; kt++) {
        __syncthreads();
#pragma unroll
        for (int c = 0; c < 4; c++) {
            gload16(ga[c], la[c]);
            gload16(gb[c], lb[c]);
            ga[c] += TK; gb[c] += TK;
        }
        __syncthreads();   // compiler drains vmcnt before barrier
#pragma unroll
        for (int kh = 0; kh < 2; kh++) {
            const int kb = kh * 64 + lg * 16;
            bf16x8 af[4], bfr[4];
#pragma unroll
            for (int i = 0; i < 4; i++) {
                int ra = wm + i * 16 + lq;
                af[i]  = *(const bf16x8*)((const char*)As + ra * 128 + (kb ^ ((ra & 7) << 4)));
                int rb = wn + i * 16 + lq;
                bfr[i] = *(const bf16x8*)((const char*)Bs + rb * 128 + (kb ^ ((rb & 7) << 4)));
            }
#pragma unroll
            for (int i = 0; i < 4; i++)
#pragma unroll
                for (int j = 0; j < 4; j++)
                    acc[i][j] = __builtin_amdgcn_mfma_f32_16x16x32_bf16(af[i], bfr[j], acc[i][j], 0, 0, 0);
        }
    }

    const int lr = lg * 4;
#pragma unroll
    for (int i = 0; i < 4; i++) {
#pragma unroll
        for (int j = 0; j < 4; j++) {
            int col = bn + wn + j * 16 + lq;
            float bsv = bias[col];
            int row0 = bm + wm + i * 16 + lr;
#pragma unroll
            for (int rr = 0; rr < 4; rr++) {
                int row = row0 + rr;
                if (row >= M) continue;
                float v = acc[i][j][rr] + bsv;
                if (act) v = gelu_f(v);
                if (Cb) Cb[(size_t)row * N + col] = __float2bfloat16(v);
                else    Cf[(size_t)row * N + col] = v;
            }
        }
    }
}

// ---------------- MFMA rel-pos attention ----------------
// grid (L/32, NH, B), 256 threads (4 waves). 32 q-rows per block.
// qkvb [2048][2304] = Q|K|V (V consumed via vT). krvr [255][1536] = KR|VR (VR via vrT).

#define PS_LD 520   // bf16 elems per Ps row (512 + 8 pad)
#define PR_LD 264   // bf16 elems per Rq/prel row (256 + 8 pad)

__global__ __launch_bounds__(256) void attn_kernel(
    const __hip_bfloat16* __restrict__ qkvb,  // [2048][2304]
    const __hip_bfloat16* __restrict__ vT,    // [B][NH][64][512]
    const __hip_bfloat16* __restrict__ krvr,  // [255][1536]
    const __hip_bfloat16* __restrict__ vrT,   // [NH][64][256] (col 255 zero)
    const int* __restrict__ mask,
    __hip_bfloat16* __restrict__ ctxb)        // [2048][768]
{
    __shared__ unsigned short RqPrel[32 * PR_LD];
    __shared__ unsigned short Ps[32 * PS_LD];
    __shared__ float mstat[32 * 4];
    __shared__ float sstat[32 * 4];
    __shared__ float maskb[512];

    const int qt = blockIdx.x, h = blockIdx.y, b = blockIdx.z;
    const int t = threadIdx.x;
    const int lane = t & 63, w = t >> 6;
    const int lq = lane & 15, lg = lane >> 4;

    maskb[t]       = mask[b * L_ + t]       ? 0.f : -1e30f;
    maskb[t + 256] = mask[b * L_ + t + 256] ? 0.f : -1e30f;

    const char* Qbase = (const char*)qkvb + ((size_t)(b * L_ + qt * 32) * 2304 + h * 64) * 2;
    const char* Kbase = (const char*)qkvb + ((size_t)(b * L_) * 2304 + 768 + h * 64) * 2;

    // ---- R phase: Rq[32][256] = Q @ KR^T ----
    {
        f32x4 accr[2][4];
#pragma unroll
        for (int i = 0; i < 2; i++)
#pragma unroll
            for (int j = 0; j < 4; j++) accr[i][j] = (f32x4){0.f, 0.f, 0.f, 0.f};
#pragma unroll
        for (int ks = 0; ks < 2; ks++) {
            const int kofs = ks * 64 + lg * 16;
            bf16x8 af0 = *(const bf16x8*)(Qbase + (size_t)lq * 4608 + kofs);
            bf16x8 af1 = *(const bf16x8*)(Qbase + (size_t)(16 + lq) * 4608 + kofs);
#pragma unroll
            for (int jt = 0; jt < 4; jt++) {
                int j = w * 64 + jt * 16 + lq;
                int jr = j > 254 ? 254 : j;
                bf16x8 bf = *(const bf16x8*)((const char*)krvr + (size_t)jr * 3072 + h * 128 + kofs);
                accr[0][jt] = __builtin_amdgcn_mfma_f32_16x16x32_bf16(af0, bf, accr[0][jt], 0, 0, 0);
                accr[1][jt] = __builtin_amdgcn_mfma_f32_16x16x32_bf16(af1, bf, accr[1][jt], 0, 0, 0);
            }
        }
#pragma unroll
        for (int it = 0; it < 2; it++)
#pragma unroll
            for (int jt = 0; jt < 4; jt++)
#pragma unroll
                for (int r = 0; r < 4; r++)
                    RqPrel[(it * 16 + lg * 4 + r) * PR_LD + w * 64 + jt * 16 + lq] = f2bfu(accr[it][jt][r]);
    }
    __syncthreads();

    // ---- S phase: Q @ K^T (wave w owns key strip w*128..+128) ----
    f32x4 accs[2][8];
#pragma unroll
    for (int i = 0; i < 2; i++)
#pragma unroll
        for (int j = 0; j < 8; j++) accs[i][j] = (f32x4){0.f, 0.f, 0.f, 0.f};
#pragma unroll
    for (int ks = 0; ks < 2; ks++) {
        const int kofs = ks * 64 + lg * 16;
        bf16x8 af0 = *(const bf16x8*)(Qbase + (size_t)lq * 4608 + kofs);
        bf16x8 af1 = *(const bf16x8*)(Qbase + (size_t)(16 + lq) * 4608 + kofs);
#pragma unroll
        for (int jt = 0; jt < 8; jt++) {
            int key = w * 128 + jt * 16 + lq;
            bf16x8 bf = *(const bf16x8*)(Kbase + (size_t)key * 4608 + kofs);
            accs[0][jt] = __builtin_amdgcn_mfma_f32_16x16x32_bf16(af0, bf, accs[0][jt], 0, 0, 0);
            accs[1][jt] = __builtin_amdgcn_mfma_f32_16x16x32_bf16(af1, bf, accs[1][jt], 0, 0, 0);
        }
    }

    // ---- S epilogue: add rel score + mask ----
#pragma unroll
    for (int it = 0; it < 2; it++) {
#pragma unroll
        for (int r = 0; r < 4; r++) {
            int q = it * 16 + lg * 4 + r;
            int qg = qt * 32 + q;
            float mx = -INFINITY;
#pragma unroll
            for (int jt = 0; jt < 8; jt++) {
                int k = w * 128 + jt * 16 + lq;
                int jc = k - qg + 127;
                jc = jc < 0 ? 0 : (jc > 254 ? 254 : jc);
                float s = (accs[it][jt][r] + bfu2f(RqPrel[q * PR_LD + jc])) * COEF_ + maskb[k];
                accs[it][jt][r] = s;
                mx = fmaxf(mx, s);
            }
#pragma unroll
            for (int off = 1; off < 16; off <<= 1) mx = fmaxf(mx, __shfl_xor(mx, off, 64));
            if (lq == 0) mstat[q * 4 + w] = mx;
        }
    }
    __syncthreads();

    // ---- exp + row sums + write P ----
#pragma unroll
    for (int it = 0; it < 2; it++) {
#pragma unroll
        for (int r = 0; r < 4; r++) {
            int q = it * 16 + lg * 4 + r;
            float4 mv = *(const float4*)&mstat[q * 4];
            float gm = fmaxf(fmaxf(mv.x, mv.y), fmaxf(mv.z, mv.w));
            float ssum = 0.f;
#pragma unroll
            for (int jt = 0; jt < 8; jt++) {
                int k = w * 128 + jt * 16 + lq;
                float p = __expf(accs[it][jt][r] - gm);
                ssum += p;
                Ps[q * PS_LD + k] = f2bfu(p);
            }
#pragma unroll
            for (int off = 1; off < 16; off <<= 1) ssum += __shfl_xor(ssum, off, 64);
            if (lq == 0) sstat[q * 4 + w] = ssum;
        }
    }
    __syncthreads();

    // ---- prel construction (into RqPrel) ----
    {
        int q = t >> 3, sub = t & 7;
        int qg = qt * 32 + q;
#pragma unroll
        for (int jj = 0; jj < 32; jj++) {
            int j = sub + 8 * jj;
            if (j == 0 || j == 254) continue;
            if (j == 255) { RqPrel[q * PR_LD + 255] = 0; continue; }
            int k = qg + j - 127;
            unsigned short val = ((unsigned)k < 512u) ? Ps[q * PS_LD + k] : (unsigned short)0;
            RqPrel[q * PR_LD + j] = val;
        }
    }
    {
        int task = t >> 2, ts = t & 3;
        int q = task >> 1, side = task & 1;
        int qg = qt * 32 + q;
        float sum = 0.f;
        if (side == 0) {
            int hi = qg - 127;
            for (int k = ts; k <= hi; k += 4) sum += bfu2f(Ps[q * PS_LD + k]);
        } else {
            for (int k = qg + 127 + ts; k < 512; k += 4) sum += bfu2f(Ps[q * PS_LD + k]);
        }
        sum += __shfl_xor(sum, 1, 64);
        sum += __shfl_xor(sum, 2, 64);
        if (ts == 0) RqPrel[q * PR_LD + (side == 0 ? 0 : 254)] = f2bfu(sum);
    }
    __syncthreads();

    // ---- PV phase: out strip d in [w*16, w*16+16) ----
    f32x4 accv[2];
    accv[0] = (f32x4){0.f, 0.f, 0.f, 0.f};
    accv[1] = (f32x4){0.f, 0.f, 0.f, 0.f};

    const __hip_bfloat16* vTb = vT + (((size_t)(b * NH_ + h) * 64) + w * 16 + lq) * 512 + lg * 8;
#pragma unroll
    for (int ks = 0; ks < 16; ks++) {
        bf16x8 bv = *(const bf16x8*)(vTb + ks * 32);
        bf16x8 pa0 = *(const bf16x8*)((const char*)Ps + (size_t)lq * (PS_LD * 2) + ks * 64 + lg * 16);
        bf16x8 pa1 = *(const bf16x8*)((const char*)Ps + (size_t)(16 + lq) * (PS_LD * 2) + ks * 64 + lg * 16);
        accv[0] = __builtin_amdgcn_mfma_f32_16x16x32_bf16(pa0, bv, accv[0], 0, 0, 0);
        accv[1] = __builtin_amdgcn_mfma_f32_16x16x32_bf16(pa1, bv, accv[1], 0, 0, 0);
    }
    const __hip_bfloat16* vrTb = vrT + ((size_t)(h * 64) + w * 16 + lq) * 256 + lg * 8;
#pragma unroll
    for (int ks = 0; ks < 8; ks++) {
        bf16x8 bv = *(const bf16x8*)(vrTb + ks * 32);
        bf16x8 pa0 = *(const bf16x8*)((const char*)RqPrel + (size_t)lq * (PR_LD * 2) + ks * 64 + lg * 16);
        bf16x8 pa1 = *(const bf16x8*)((const char*)RqPrel + (size_t)(16 + lq) * (PR_LD * 2) + ks * 64 + lg * 16);
        accv[0] = __builtin_amdgcn_mfma_f32_16x16x32_bf16(pa0, bv, accv[0], 0, 0, 0);
        accv[1] = __builtin_amdgcn_mfma_f32_16x16x32_bf16(pa1, bv, accv[1], 0, 0, 0);
    }

#pragma unroll
    for (int it = 0; it < 2; it++) {
#pragma unroll
        for (int r = 0; r < 4; r++) {
            int q = it * 16 + lg * 4 + r;
            float4 sv = *(const float4*)&sstat[q * 4];
            float inv = 1.f / (sv.x + sv.y + sv.z + sv.w);
            ctxb[(size_t)(b * L_ + qt * 32 + q) * 768 + h * 64 + w * 16 + lq] =
                __float2bfloat16(accv[it][r] * inv);
        }
    }
}

// ---------------- host ----------------

extern "C" void kernel_launch(void* const* d_in, const int* in_sizes, int n_in,
                              void* d_out, int out_size, void* d_ws, size_t ws_size,
                              hipStream_t stream)
{
    const int*   tok    = (const int*)d_in[0];
    const int*   seg    = (const int*)d_in[1];
    const int*   maskp  = (const int*)d_in[2];
    const float* temb   = (const float*)d_in[3];
    const float* semb   = (const float*)d_in[4];
    const float* esc    = (const float*)d_in[5];
    const float* ebi    = (const float*)d_in[6];
    const float* Wq     = (const float*)d_in[7];
    const float* bq     = (const float*)d_in[8];
    const float* Wk     = (const float*)d_in[9];
    const float* bk     = (const float*)d_in[10];
    const float* Wv     = (const float*)d_in[11];
    const float* bv     = (const float*)d_in[12];
    const float* relpos = (const float*)d_in[13];
    const float* Wo     = (const float*)d_in[14];
    const float* bo     = (const float*)d_in[15];
    const float* ln1s   = (const float*)d_in[16];
    const float* ln1b   = (const float*)d_in[17];
    const float* W1     = (const float*)d_in[18];
    const float* b1     = (const float*)d_in[19];
    const float* W2     = (const float*)d_in[20];
    const float* b2     = (const float*)d_in[21];
    const float* ln2s   = (const float*)d_in[22];
    const float* ln2b   = (const float*)d_in[23];

    const size_t NX = (size_t)ROWS * H_;
    float* x       = (float*)d_ws;
    float* x2      = x + NX;
    float* y       = x2 + NX;
    float* qkvbias = y + NX;                                   // 2304 f32
    __hip_bfloat16* xb    = (__hip_bfloat16*)(qkvbias + 2304);
    __hip_bfloat16* x2b   = xb    + NX;
    __hip_bfloat16* ctxb  = x2b   + NX;
    __hip_bfloat16* qkvb  = ctxb  + NX;                        // 2048*2304
    __hip_bfloat16* vT    = qkvb  + (size_t)ROWS * 2304;       // 4*12*64*512
    __hip_bfloat16* krvr  = vT    + (size_t)B_ * NH_ * 64 * 512; // 255*1536
    __hip_bfloat16* vrT   = krvr  + (size_t)NR_ * 1536;        // 12*64*256
    __hip_bfloat16* relb  = vrT   + (size_t)NH_ * 64 * 256;    // 6*255*768
    __hip_bfloat16* Wt    = relb  + (size_t)NL_ * NR_ * H_;    // 3072*768
    __hip_bfloat16* h1b   = Wt    + (size_t)M_ * H_;           // 2048*3072

    dim3 blk(256);

    embed_ln_kernel<<<ROWS, blk, 0, stream>>>(tok, seg, temb, semb, esc, ebi, x, xb);
    cvt_kernel<<<1024, blk, 0, stream>>>(relpos, relb, NL_ * NR_ * H_);

    for (int l = 0; l < NL_; l++) {
        const float* wq = Wq + (size_t)l * H_ * H_;
        const float* wk = Wk + (size_t)l * H_ * H_;
        const float* wv = Wv + (size_t)l * H_ * H_;
        const float* wo = Wo + (size_t)l * H_ * H_;
        const float* w1 = W1 + (size_t)l * H_ * M_;
        const float* w2 = W2 + (size_t)l * M_ * H_;

        transpose_cvt_kernel<<<dim3(24, 24), blk, 0, stream>>>(wq, Wt, H_, H_);
        transpose_cvt_kernel<<<dim3(24, 24), blk, 0, stream>>>(wk, Wt + (size_t)H_ * H_, H_, H_);
        transpose_cvt_kernel<<<dim3(24, 24), blk, 0, stream>>>(wv, Wt + (size_t)2 * H_ * H_, H_, H_);
        pack_qkv_bias_kernel<<<9, blk, 0, stream>>>(bq + (size_t)l * H_, bk + (size_t)l * H_, bv + (size_t)l * H_, qkvbias);

        // QKV projection -> row-major Q|K|V
        gemm_bf16_kernel<<<dim3(18, 16), blk, 0, stream>>>(xb, Wt, qkvbias, nullptr, qkvb,
                                                           ROWS, 2304, H_, 0);
        transpose_v_kernel<<<dim3(32, 12), blk, 0, stream>>>(qkvb, vT);

        // rel K/V -> row-major KR|VR
        gemm_bf16_kernel<<<dim3(12, 2), blk, 0, stream>>>(relb + (size_t)l * NR_ * H_, Wt + (size_t)H_ * H_,
                                                          qkvbias + 768, nullptr, krvr,
                                                          NR_, 1536, H_, 0);
        transpose_vr_kernel<<<dim3(4, 12), blk, 0, stream>>>(krvr, vrT);

        attn_kernel<<<dim3(L_ / 32, NH_, B_), blk, 0, stream>>>(qkvb, vT, krvr, vrT, maskp, ctxb);

        transpose_cvt_kernel<<<dim3(24, 24), blk, 0, stream>>>(wo, Wt, H_, H_);
        gemm_bf16_kernel<<<dim3(6, 16), blk, 0, stream>>>(ctxb, Wt, bo + (size_t)l * H_, y, nullptr,
                                                          ROWS, H_, H_, 0);
        add_ln_kernel<<<ROWS, blk, 0, stream>>>(x, y, ln1s + (size_t)l * H_, ln1b + (size_t)l * H_, x2, x2b);

        transpose_cvt_kernel<<<dim3(96, 24), blk, 0, stream>>>(w1, Wt, H_, M_);
        gemm_bf16_kernel<<<dim3(24, 16), blk, 0, stream>>>(x2b, Wt, b1 + (size_t)l * M_, nullptr, h1b,
                                                           ROWS, M_, H_, 1);
        transpose_cvt_kernel<<<dim3(24, 96), blk, 0, stream>>>(w2, Wt, M_, H_);
        gemm_bf16_kernel<<<dim3(6, 16), blk, 0, stream>>>(h1b, Wt, b2 + (size_t)l * H_, y, nullptr,
                                                          ROWS, H_, M_, 0);

        float* outp = (l == NL_ - 1) ? (float*)d_out : x;
        __hip_bfloat16* outbp = (l == NL_ - 1) ? nullptr : xb;
        add_ln_kernel<<<ROWS, blk, 0, stream>>>(x2, y, ln2s + (size_t)l * H_, ln2b + (size_t)l * H_, outp, outbp);
    }
}

// Round 5
// 1274.479 us; speedup vs baseline: 11.7677x; 1.1614x over previous
//
#include <hip/hip_runtime.h>
#include <hip/hip_bf16.h>
#include <math.h>

#define B_   4
#define L_   512
#define H_   768
#define NH_  12
#define HD_  64
#define M_   3072
#define NL_  6
#define RD_  128
#define NR_  255          // 2*RD-1
#define ROWS (B_*L_)      // 2048
#define COEF_ 0.125f      // 1/sqrt(64)

typedef __attribute__((ext_vector_type(8))) short bf16x8;
typedef __attribute__((ext_vector_type(4))) float f32x4;

// ---------------- utility ----------------

static __device__ __forceinline__ float wave_reduce_sum(float v) {
#pragma unroll
    for (int off = 32; off > 0; off >>= 1) v += __shfl_xor(v, off, 64);
    return v;
}

static __device__ __forceinline__ float gelu_f(float x) {
    float x3 = x * x * x;
    return 0.5f * x * (1.f + tanhf(0.7978845608028654f * (x + 0.044715f * x3)));
}

static __device__ __forceinline__ unsigned short f2bfu(float v) {
    __hip_bfloat16 h = __float2bfloat16(v);
    return *(unsigned short*)&h;
}

static __device__ __forceinline__ float bfu2f(unsigned short u) {
    union { float f; unsigned int i; } x;
    x.i = ((unsigned int)u) << 16;
    return x.f;
}

// async global->LDS, 16B per lane; LDS dest = wave-uniform base + lane*16
static __device__ __forceinline__ void gload16(const void* g, void* l) {
    __builtin_amdgcn_global_load_lds(
        (const __attribute__((address_space(1))) void*)g,
        (__attribute__((address_space(3))) void*)l,
        16, 0, 0);
}

// ---------------- embedding + LN (fp32 out + bf16 twin) ----------------

__global__ __launch_bounds__(256) void embed_ln_kernel(
    const int* __restrict__ tok, const int* __restrict__ seg,
    const float* __restrict__ temb, const float* __restrict__ semb,
    const float* __restrict__ sc, const float* __restrict__ bi,
    float* __restrict__ out, __hip_bfloat16* __restrict__ outb)
{
    int row = blockIdx.x;
    int t = threadIdx.x;
    int tid = tok[row], sid = seg[row];
    const float* tp = temb + (size_t)tid * H_;
    const float* sp = semb + (size_t)sid * H_;
    float v[3];
#pragma unroll
    for (int j = 0; j < 3; j++) { int idx = t + j * 256; v[j] = tp[idx] + sp[idx]; }

    __shared__ float red[4];
    __shared__ float bc;
    int lane = t & 63, wid = t >> 6;

    float s = v[0] + v[1] + v[2];
    s = wave_reduce_sum(s);
    if (lane == 0) red[wid] = s;
    __syncthreads();
    if (t == 0) bc = (red[0] + red[1] + red[2] + red[3]) * (1.f / H_);
    __syncthreads();
    float mean = bc;

    float c[3]; float ss = 0.f;
#pragma unroll
    for (int j = 0; j < 3; j++) { c[j] = v[j] - mean; ss += c[j] * c[j]; }
    ss = wave_reduce_sum(ss);
    __syncthreads();
    if (lane == 0) red[wid] = ss;
    __syncthreads();
    if (t == 0) bc = rsqrtf((red[0] + red[1] + red[2] + red[3]) * (1.f / H_) + 1e-12f);
    __syncthreads();
    float r = bc;
#pragma unroll
    for (int j = 0; j < 3; j++) {
        int idx = t + j * 256;
        float o = c[j] * r * sc[idx] + bi[idx];
        out[(size_t)row * H_ + idx] = o;
        outb[(size_t)row * H_ + idx] = __float2bfloat16(o);
    }
}

// ---------------- residual add (+partials +bias) + LN (fp32 out + optional bf16 twin) ----------------

__global__ __launch_bounds__(256) void add_ln_kernel(
    const float* __restrict__ x, const float* __restrict__ p0,
    const float* __restrict__ p1, const float* __restrict__ p2,
    const float* __restrict__ bias,
    const float* __restrict__ sc, const float* __restrict__ bi,
    float* __restrict__ out, __hip_bfloat16* __restrict__ outb)
{
    int row = blockIdx.x;
    int t = threadIdx.x;
    const float* xp = x + (size_t)row * H_;
    const float* q0 = p0 + (size_t)row * H_;
    const float* q1 = p1 ? p1 + (size_t)row * H_ : nullptr;
    const float* q2 = p2 ? p2 + (size_t)row * H_ : nullptr;
    float v[3];
#pragma unroll
    for (int j = 0; j < 3; j++) {
        int idx = t + j * 256;
        float a = xp[idx] + q0[idx];
        if (q1) a += q1[idx];
        if (q2) a += q2[idx];
        if (bias) a += bias[idx];
        v[j] = a;
    }

    __shared__ float red[4];
    __shared__ float bc;
    int lane = t & 63, wid = t >> 6;

    float s = v[0] + v[1] + v[2];
    s = wave_reduce_sum(s);
    if (lane == 0) red[wid] = s;
    __syncthreads();
    if (t == 0) bc = (red[0] + red[1] + red[2] + red[3]) * (1.f / H_);
    __syncthreads();
    float mean = bc;

    float c[3]; float ss = 0.f;
#pragma unroll
    for (int j = 0; j < 3; j++) { c[j] = v[j] - mean; ss += c[j] * c[j]; }
    ss = wave_reduce_sum(ss);
    __syncthreads();
    if (lane == 0) red[wid] = ss;
    __syncthreads();
    if (t == 0) bc = rsqrtf((red[0] + red[1] + red[2] + red[3]) * (1.f / H_) + 1e-12f);
    __syncthreads();
    float r = bc;
#pragma unroll
    for (int j = 0; j < 3; j++) {
        int idx = t + j * 256;
        float o = c[j] * r * sc[idx] + bi[idx];
        out[(size_t)row * H_ + idx] = o;
        if (outb) outb[(size_t)row * H_ + idx] = __float2bfloat16(o);
    }
}

// ---------------- transpose + fp32->bf16 weight pack: in[K][N] f32 -> out[N][K] bf16 ----------------

__global__ __launch_bounds__(256) void transpose_cvt_kernel(
    const float* __restrict__ in, __hip_bfloat16* __restrict__ out, int K, int N)
{
    __shared__ float tile[32][33];
    int bx = blockIdx.x * 32;   // n
    int by = blockIdx.y * 32;   // k
    int tx = threadIdx.x & 31, ty = threadIdx.x >> 5;
#pragma unroll
    for (int i = 0; i < 4; i++)
        tile[ty + 8 * i][tx] = in[(size_t)(by + ty + 8 * i) * N + bx + tx];
    __syncthreads();
#pragma unroll
    for (int i = 0; i < 4; i++)
        out[(size_t)(bx + ty + 8 * i) * K + by + tx] = __float2bfloat16(tile[tx][ty + 8 * i]);
}

// batched variant for 3 same-shape square weights (wq,wk,wv), K=N=768
__global__ __launch_bounds__(256) void transpose_cvt3_kernel(
    const float* __restrict__ in0, const float* __restrict__ in1, const float* __restrict__ in2,
    __hip_bfloat16* __restrict__ out)
{
    const float* in = blockIdx.z == 0 ? in0 : (blockIdx.z == 1 ? in1 : in2);
    __hip_bfloat16* o = out + (size_t)blockIdx.z * H_ * H_;
    __shared__ float tile[32][33];
    int bx = blockIdx.x * 32;
    int by = blockIdx.y * 32;
    int tx = threadIdx.x & 31, ty = threadIdx.x >> 5;
#pragma unroll
    for (int i = 0; i < 4; i++)
        tile[ty + 8 * i][tx] = in[(size_t)(by + ty + 8 * i) * H_ + bx + tx];
    __syncthreads();
#pragma unroll
    for (int i = 0; i < 4; i++)
        o[(size_t)(bx + ty + 8 * i) * H_ + by + tx] = __float2bfloat16(tile[tx][ty + 8 * i]);
}

__global__ void cvt_kernel(const float* __restrict__ in, __hip_bfloat16* __restrict__ out, int n) {
    int i = blockIdx.x * blockDim.x + threadIdx.x;
    int stride = gridDim.x * blockDim.x;
    for (; i < n; i += stride) out[i] = __float2bfloat16(in[i]);
}

__global__ void pack_qkv_bias_kernel(const float* __restrict__ bq, const float* __restrict__ bk,
                                     const float* __restrict__ bv, float* __restrict__ out) {
    int i = blockIdx.x * 256 + threadIdx.x;
    if (i >= 2304) return;
    out[i] = i < 768 ? bq[i] : (i < 1536 ? bk[i - 768] : bv[i - 1536]);
}

// ---------------- fused V / VR transpose ----------------
// bx<32: qkvb[2048][2304] cols 1536.. -> vT[b][h][64][512]
// bx>=32: krvr[255][1536] cols 768..  -> vrT[h][64][256] (j>=255 -> 0)

__global__ __launch_bounds__(256) void transpose_vvr_kernel(
    const __hip_bfloat16* __restrict__ qkvb, const __hip_bfloat16* __restrict__ krvr,
    __hip_bfloat16* __restrict__ vT, __hip_bfloat16* __restrict__ vrT)
{
    __shared__ unsigned short tile[64][72];
    const int bx = blockIdx.x;
    const int h  = blockIdx.y;
    const int t = threadIdx.x;
    const int r = t >> 2, c0 = (t & 3) * 16;
    if (bx < 32) {
        const int kb = bx * 64;
        const unsigned short* src = (const unsigned short*)qkvb + (size_t)(kb + r) * 2304 + 1536 + h * 64 + c0;
        *(uint4*)&tile[r][c0]     = *(const uint4*)src;
        *(uint4*)&tile[r][c0 + 8] = *(const uint4*)(src + 8);
        __syncthreads();
        unsigned short outv[16];
#pragma unroll
        for (int i = 0; i < 16; i++) outv[i] = tile[c0 + i][r];
        unsigned short* dst = (unsigned short*)vT +
            ((size_t)((kb >> 9) * NH_ + h) * 64 + r) * 512 + (kb & 511) + c0;
        *(uint4*)dst       = *(uint4*)&outv[0];
        *(uint4*)(dst + 8) = *(uint4*)&outv[8];
    } else {
        const int jb = (bx - 32) * 64;
        const int j = jb + r;
        if (j < NR_) {
            const unsigned short* src = (const unsigned short*)krvr + (size_t)j * 1536 + 768 + h * 64 + c0;
            *(uint4*)&tile[r][c0]     = *(const uint4*)src;
            *(uint4*)&tile[r][c0 + 8] = *(const uint4*)(src + 8);
        } else {
#pragma unroll
            for (int i = 0; i < 16; i++) tile[r][c0 + i] = 0;
        }
        __syncthreads();
        unsigned short outv[16];
#pragma unroll
        for (int i = 0; i < 16; i++) outv[i] = tile[c0 + i][r];
        unsigned short* dst = (unsigned short*)vrT + ((size_t)(h * 64) + r) * 256 + jb + c0;
        *(uint4*)dst       = *(uint4*)&outv[0];
        *(uint4*)(dst + 8) = *(uint4*)&outv[8];
    }
}

// ---------------- bf16 MFMA GEMM, 2-phase double-buffered, optional split-K ----------------
// C[M,N] = A[M,K] @ Bt[N,K]^T (+bias,+gelu). grid.z = K-splits; slice z covers
// K-range [z*ksplit, (z+1)*ksplit). z==0 -> Cf/Cb; z>0 -> CfX + (z-1)*xstride (fp32, no bias/act).
// global_load_lds width-16 staging, linear LDS dest + pre-swizzled global src,
// XOR-swizzled ds_read_b128, one barrier per K-step, XCD-contiguous remap.

#define TK 64

__global__ __launch_bounds__(256) void gemm_bf16_kernel(
    const __hip_bfloat16* __restrict__ A, const __hip_bfloat16* __restrict__ Bt,
    const float* __restrict__ bias, float* __restrict__ Cf, __hip_bfloat16* __restrict__ Cb,
    float* __restrict__ CfX, size_t xstride,
    int M, int N, int K, int act, int ksplit)
{
    __shared__ __hip_bfloat16 As[2][128 * TK];
    __shared__ __hip_bfloat16 Bs[2][128 * TK];
    const int t = threadIdx.x;
    const int lane = t & 63;
    const int w = t >> 6;
    const int lq = lane & 15, lg = lane >> 4;
    const int wm = (w >> 1) * 64, wn = (w & 1) * 64;

    const int nbx = gridDim.x;
    const int nwg = nbx * gridDim.y;
    int wgid = blockIdx.y * nbx + blockIdx.x;
    if ((nwg & 7) == 0) { int qq = nwg >> 3; wgid = (wgid & 7) * qq + (wgid >> 3); }
    const int bm = (wgid / nbx) * 128, bn = (wgid % nbx) * 128;
    const int kbase = blockIdx.z * ksplit;

    f32x4 acc[4][4];
#pragma unroll
    for (int i = 0; i < 4; i++)
#pragma unroll
        for (int j = 0; j < 4; j++) acc[i][j] = (f32x4){0.f, 0.f, 0.f, 0.f};

    const int rlane = lane >> 3;
    const int cswz = (((lane & 7) * 16) ^ ((rlane & 7) << 4)) >> 1;   // elements
    const __hip_bfloat16* ga[4];
    const __hip_bfloat16* gb[4];
    int lofs[4];
#pragma unroll
    for (int c = 0; c < 4; c++) {
        int rowa = bm + w * 32 + c * 8 + rlane; if (rowa >= M) rowa = M - 1;
        int rowb = bn + w * 32 + c * 8 + rlane;
        ga[c] = A  + (size_t)rowa * K + kbase + cswz;
        gb[c] = Bt + (size_t)rowb * K + kbase + cswz;
        lofs[c] = (w * 32 + c * 8) * TK;
    }

    const int nt = ksplit / TK;
    // prologue: stage tile 0 into buf 0
#pragma unroll
    for (int c = 0; c < 4; c++) {
        gload16(ga[c], &As[0][lofs[c]]);
        gload16(gb[c], &Bs[0][lofs[c]]);
    }
    __syncthreads();

    int cur = 0;
    for (int kt = 0; kt < nt; kt++) {
        if (kt + 1 < nt) {
#pragma unroll
            for (int c = 0; c < 4; c++) {
                gload16(ga[c] + (kt + 1) * TK, &As[cur ^ 1][lofs[c]]);
                gload16(gb[c] + (kt + 1) * TK, &Bs[cur ^ 1][lofs[c]]);
            }
        }
#pragma unroll
        for (int kh = 0; kh < 2; kh++) {
            const int kb = kh * 64 + lg * 16;
            bf16x8 af[4], bfr[4];
#pragma unroll
            for (int i = 0; i < 4; i++) {
                int ra = wm + i * 16 + lq;
                af[i]  = *(const bf16x8*)((const char*)&As[cur][0] + ra * 128 + (kb ^ ((ra & 7) << 4)));
                int rb = wn + i * 16 + lq;
                bfr[i] = *(const bf16x8*)((const char*)&Bs[cur][0] + rb * 128 + (kb ^ ((rb & 7) << 4)));
            }
#pragma unroll
            for (int i = 0; i < 4; i++)
#pragma unroll
                for (int j = 0; j < 4; j++)
                    acc[i][j] = __builtin_amdgcn_mfma_f32_16x16x32_bf16(af[i], bfr[j], acc[i][j], 0, 0, 0);
        }
        __syncthreads();   // drains vmcnt (next-tile loads landed) + lgkm, swaps roles
        cur ^= 1;
    }

    const int lr = lg * 4;
    float* outf = (blockIdx.z == 0) ? Cf : (CfX + (size_t)(blockIdx.z - 1) * xstride);
#pragma unroll
    for (int i = 0; i < 4; i++) {
#pragma unroll
        for (int j = 0; j < 4; j++) {
            int col = bn + wn + j * 16 + lq;
            float bsv = bias ? bias[col] : 0.f;
            int row0 = bm + wm + i * 16 + lr;
#pragma unroll
            for (int rr = 0; rr < 4; rr++) {
                int row = row0 + rr;
                if (row >= M) continue;
                float v = acc[i][j][rr] + bsv;
                if (act) v = gelu_f(v);
                if (Cb && blockIdx.z == 0) Cb[(size_t)row * N + col] = __float2bfloat16(v);
                else                       outf[(size_t)row * N + col] = v;
            }
        }
    }
}

// ---------------- MFMA rel-pos attention ----------------
// grid (L/32, NH, B), 256 threads (4 waves). 32 q-rows per block.
// qkvb [2048][2304] = Q|K|V (V consumed via vT). krvr [255][1536] = KR|VR (VR via vrT).

#define PS_LD 520   // bf16 elems per Ps row (512 + 8 pad)
#define PR_LD 264   // bf16 elems per Rq/prel row (256 + 8 pad)

__global__ __launch_bounds__(256) void attn_kernel(
    const __hip_bfloat16* __restrict__ qkvb,  // [2048][2304]
    const __hip_bfloat16* __restrict__ vT,    // [B][NH][64][512]
    const __hip_bfloat16* __restrict__ krvr,  // [255][1536]
    const __hip_bfloat16* __restrict__ vrT,   // [NH][64][256] (col 255 zero)
    const int* __restrict__ mask,
    __hip_bfloat16* __restrict__ ctxb)        // [2048][768]
{
    __shared__ unsigned short RqPrel[32 * PR_LD];
    __shared__ unsigned short Ps[32 * PS_LD];
    __shared__ float mstat[32 * 4];
    __shared__ float sstat[32 * 4];
    __shared__ float maskb[512];

    const int qt = blockIdx.x, h = blockIdx.y, b = blockIdx.z;
    const int t = threadIdx.x;
    const int lane = t & 63, w = t >> 6;
    const int lq = lane & 15, lg = lane >> 4;

    maskb[t]       = mask[b * L_ + t]       ? 0.f : -1e30f;
    maskb[t + 256] = mask[b * L_ + t + 256] ? 0.f : -1e30f;

    const char* Qbase = (const char*)qkvb + ((size_t)(b * L_ + qt * 32) * 2304 + h * 64) * 2;
    const char* Kbase = (const char*)qkvb + ((size_t)(b * L_) * 2304 + 768 + h * 64) * 2;

    // ---- R phase: Rq[32][256] = Q @ KR^T ----
    {
        f32x4 accr[2][4];
#pragma unroll
        for (int i = 0; i < 2; i++)
#pragma unroll
            for (int j = 0; j < 4; j++) accr[i][j] = (f32x4){0.f, 0.f, 0.f, 0.f};
#pragma unroll
        for (int ks = 0; ks < 2; ks++) {
            const int kofs = ks * 64 + lg * 16;
            bf16x8 af0 = *(const bf16x8*)(Qbase + (size_t)lq * 4608 + kofs);
            bf16x8 af1 = *(const bf16x8*)(Qbase + (size_t)(16 + lq) * 4608 + kofs);
#pragma unroll
            for (int jt = 0; jt < 4; jt++) {
                int j = w * 64 + jt * 16 + lq;
                int jr = j > 254 ? 254 : j;
                bf16x8 bf = *(const bf16x8*)((const char*)krvr + (size_t)jr * 3072 + h * 128 + kofs);
                accr[0][jt] = __builtin_amdgcn_mfma_f32_16x16x32_bf16(af0, bf, accr[0][jt], 0, 0, 0);
                accr[1][jt] = __builtin_amdgcn_mfma_f32_16x16x32_bf16(af1, bf, accr[1][jt], 0, 0, 0);
            }
        }
#pragma unroll
        for (int it = 0; it < 2; it++)
#pragma unroll
            for (int jt = 0; jt < 4; jt++)
#pragma unroll
                for (int r = 0; r < 4; r++)
                    RqPrel[(it * 16 + lg * 4 + r) * PR_LD + w * 64 + jt * 16 + lq] = f2bfu(accr[it][jt][r]);
    }
    __syncthreads();

    // ---- S phase: Q @ K^T (wave w owns key strip w*128..+128) ----
    f32x4 accs[2][8];
#pragma unroll
    for (int i = 0; i < 2; i++)
#pragma unroll
        for (int j = 0; j < 8; j++) accs[i][j] = (f32x4){0.f, 0.f, 0.f, 0.f};
#pragma unroll
    for (int ks = 0; ks < 2; ks++) {
        const int kofs = ks * 64 + lg * 16;
        bf16x8 af0 = *(const bf16x8*)(Qbase + (size_t)lq * 4608 + kofs);
        bf16x8 af1 = *(const bf16x8*)(Qbase + (size_t)(16 + lq) * 4608 + kofs);
#pragma unroll
        for (int jt = 0; jt < 8; jt++) {
            int key = w * 128 + jt * 16 + lq;
            bf16x8 bf = *(const bf16x8*)(Kbase + (size_t)key * 4608 + kofs);
            accs[0][jt] = __builtin_amdgcn_mfma_f32_16x16x32_bf16(af0, bf, accs[0][jt], 0, 0, 0);
            accs[1][jt] = __builtin_amdgcn_mfma_f32_16x16x32_bf16(af1, bf, accs[1][jt], 0, 0, 0);
        }
    }

    // ---- S epilogue: add rel score + mask ----
#pragma unroll
    for (int it = 0; it < 2; it++) {
#pragma unroll
        for (int r = 0; r < 4; r++) {
            int q = it * 16 + lg * 4 + r;
            int qg = qt * 32 + q;
            float mx = -INFINITY;
#pragma unroll
            for (int jt = 0; jt < 8; jt++) {
                int k = w * 128 + jt * 16 + lq;
                int jc = k - qg + 127;
                jc = jc < 0 ? 0 : (jc > 254 ? 254 : jc);
                float s = (accs[it][jt][r] + bfu2f(RqPrel[q * PR_LD + jc])) * COEF_ + maskb[k];
                accs[it][jt][r] = s;
                mx = fmaxf(mx, s);
            }
#pragma unroll
            for (int off = 1; off < 16; off <<= 1) mx = fmaxf(mx, __shfl_xor(mx, off, 64));
            if (lq == 0) mstat[q * 4 + w] = mx;
        }
    }
    __syncthreads();

    // ---- exp + row sums + write P ----
#pragma unroll
    for (int it = 0; it < 2; it++) {
#pragma unroll
        for (int r = 0; r < 4; r++) {
            int q = it * 16 + lg * 4 + r;
            float4 mv = *(const float4*)&mstat[q * 4];
            float gm = fmaxf(fmaxf(mv.x, mv.y), fmaxf(mv.z, mv.w));
            float ssum = 0.f;
#pragma unroll
            for (int jt = 0; jt < 8; jt++) {
                int k = w * 128 + jt * 16 + lq;
                float p = __expf(accs[it][jt][r] - gm);
                ssum += p;
                Ps[q * PS_LD + k] = f2bfu(p);
            }
#pragma unroll
            for (int off = 1; off < 16; off <<= 1) ssum += __shfl_xor(ssum, off, 64);
            if (lq == 0) sstat[q * 4 + w] = ssum;
        }
    }
    __syncthreads();

    // ---- prel construction (into RqPrel) ----
    {
        int q = t >> 3, sub = t & 7;
        int qg = qt * 32 + q;
#pragma unroll
        for (int jj = 0; jj < 32; jj++) {
            int j = sub + 8 * jj;
            if (j == 0 || j == 254) continue;
            if (j == 255) { RqPrel[q * PR_LD + 255] = 0; continue; }
            int k = qg + j - 127;
            unsigned short val = ((unsigned)k < 512u) ? Ps[q * PS_LD + k] : (unsigned short)0;
            RqPrel[q * PR_LD + j] = val;
        }
    }
    {
        int task = t >> 2, ts = t & 3;
        int q = task >> 1, side = task & 1;
        int qg = qt * 32 + q;
        float sum = 0.f;
        if (side == 0) {
            int hi = qg - 127;
            for (int k = ts; k <= hi; k += 4) sum += bfu2f(Ps[q * PS_LD + k]);
        } else {
            for (int k = qg + 127 + ts; k < 512; k += 4) sum += bfu2f(Ps[q * PS_LD + k]);
        }
        sum += __shfl_xor(sum, 1, 64);
        sum += __shfl_xor(sum, 2, 64);
        if (ts == 0) RqPrel[q * PR_LD + (side == 0 ? 0 : 254)] = f2bfu(sum);
    }
    __syncthreads();

    // ---- PV phase: out strip d in [w*16, w*16+16) ----
    f32x4 accv[2];
    accv[0] = (f32x4){0.f, 0.f, 0.f, 0.f};
    accv[1] = (f32x4){0.f, 0.f, 0.f, 0.f};

    const __hip_bfloat16* vTb = vT + (((size_t)(b * NH_ + h) * 64) + w * 16 + lq) * 512 + lg * 8;
#pragma unroll
    for (int ks = 0; ks < 16; ks++) {
        bf16x8 bv = *(const bf16x8*)(vTb + ks * 32);
        bf16x8 pa0 = *(const bf16x8*)((const char*)Ps + (size_t)lq * (PS_LD * 2) + ks * 64 + lg * 16);
        bf16x8 pa1 = *(const bf16x8*)((const char*)Ps + (size_t)(16 + lq) * (PS_LD * 2) + ks * 64 + lg * 16);
        accv[0] = __builtin_amdgcn_mfma_f32_16x16x32_bf16(pa0, bv, accv[0], 0, 0, 0);
        accv[1] = __builtin_amdgcn_mfma_f32_16x16x32_bf16(pa1, bv, accv[1], 0, 0, 0);
    }
    const __hip_bfloat16* vrTb = vrT + ((size_t)(h * 64) + w * 16 + lq) * 256 + lg * 8;
#pragma unroll
    for (int ks = 0; ks < 8; ks++) {
        bf16x8 bv = *(const bf16x8*)(vrTb + ks * 32);
        bf16x8 pa0 = *(const bf16x8*)((const char*)RqPrel + (size_t)lq * (PR_LD * 2) + ks * 64 + lg * 16);
        bf16x8 pa1 = *(const bf16x8*)((const char*)RqPrel + (size_t)(16 + lq) * (PR_LD * 2) + ks * 64 + lg * 16);
        accv[0] = __builtin_amdgcn_mfma_f32_16x16x32_bf16(pa0, bv, accv[0], 0, 0, 0);
        accv[1] = __builtin_amdgcn_mfma_f32_16x16x32_bf16(pa1, bv, accv[1], 0, 0, 0);
    }

#pragma unroll
    for (int it = 0; it < 2; it++) {
#pragma unroll
        for (int r = 0; r < 4; r++) {
            int q = it * 16 + lg * 4 + r;
            float4 sv = *(const float4*)&sstat[q * 4];
            float inv = 1.f / (sv.x + sv.y + sv.z + sv.w);
            ctxb[(size_t)(b * L_ + qt * 32 + q) * 768 + h * 64 + w * 16 + lq] =
                __float2bfloat16(accv[it][r] * inv);
        }
    }
}

// ---------------- host ----------------

extern "C" void kernel_launch(void* const* d_in, const int* in_sizes, int n_in,
                              void* d_out, int out_size, void* d_ws, size_t ws_size,
                              hipStream_t stream)
{
    const int*   tok    = (const int*)d_in[0];
    const int*   seg    = (const int*)d_in[1];
    const int*   maskp  = (const int*)d_in[2];
    const float* temb   = (const float*)d_in[3];
    const float* semb   = (const float*)d_in[4];
    const float* esc    = (const float*)d_in[5];
    const float* ebi    = (const float*)d_in[6];
    const float* Wq     = (const float*)d_in[7];
    const float* bq     = (const float*)d_in[8];
    const float* Wk     = (const float*)d_in[9];
    const float* bk     = (const float*)d_in[10];
    const float* Wv     = (const float*)d_in[11];
    const float* bv     = (const float*)d_in[12];
    const float* relpos = (const float*)d_in[13];
    const float* Wo     = (const float*)d_in[14];
    const float* bo     = (const float*)d_in[15];
    const float* ln1s   = (const float*)d_in[16];
    const float* ln1b   = (const float*)d_in[17];
    const float* W1     = (const float*)d_in[18];
    const float* b1     = (const float*)d_in[19];
    const float* W2     = (const float*)d_in[20];
    const float* b2     = (const float*)d_in[21];
    const float* ln2s   = (const float*)d_in[22];
    const float* ln2b   = (const float*)d_in[23];

    const size_t NX = (size_t)ROWS * H_;
    float* x       = (float*)d_ws;
    float* x2      = x + NX;
    float* y       = x2 + NX;
    float* qkvbias = y + NX;                                   // 2304 f32
    __hip_bfloat16* xb    = (__hip_bfloat16*)(qkvbias + 2304);
    __hip_bfloat16* x2b   = xb    + NX;
    __hip_bfloat16* ctxb  = x2b   + NX;
    __hip_bfloat16* qkvb  = ctxb  + NX;                        // 2048*2304
    __hip_bfloat16* vT    = qkvb  + (size_t)ROWS * 2304;       // 4*12*64*512
    __hip_bfloat16* krvr  = vT    + (size_t)B_ * NH_ * 64 * 512; // 255*1536
    __hip_bfloat16* vrT   = krvr  + (size_t)NR_ * 1536;        // 12*64*256
    __hip_bfloat16* relb  = vrT   + (size_t)NH_ * 64 * 256;    // 6*255*768
    __hip_bfloat16* Wt    = relb  + (size_t)NL_ * NR_ * H_;    // 3072*768
    __hip_bfloat16* h1b   = Wt    + (size_t)M_ * H_;           // 2048*3072

    // split-K partial buffers alias the qkvb/vT region (dead once attn has run)
    float* spill = (float*)qkvb;   // capacity: (2048*2304 + 4*12*64*512) bf16 = 4.2M floats >= 2*NX

    dim3 blk(256);

    embed_ln_kernel<<<ROWS, blk, 0, stream>>>(tok, seg, temb, semb, esc, ebi, x, xb);
    cvt_kernel<<<1024, blk, 0, stream>>>(relpos, relb, NL_ * NR_ * H_);

    for (int l = 0; l < NL_; l++) {
        const float* wq = Wq + (size_t)l * H_ * H_;
        const float* wk = Wk + (size_t)l * H_ * H_;
        const float* wv = Wv + (size_t)l * H_ * H_;
        const float* wo = Wo + (size_t)l * H_ * H_;
        const float* w1 = W1 + (size_t)l * H_ * M_;
        const float* w2 = W2 + (size_t)l * M_ * H_;

        transpose_cvt3_kernel<<<dim3(24, 24, 3), blk, 0, stream>>>(wq, wk, wv, Wt);
        pack_qkv_bias_kernel<<<9, blk, 0, stream>>>(bq + (size_t)l * H_, bk + (size_t)l * H_, bv + (size_t)l * H_, qkvbias);

        // rel K/V -> row-major KR|VR (before QKV so both transposes can fuse)
        gemm_bf16_kernel<<<dim3(12, 2), blk, 0, stream>>>(relb + (size_t)l * NR_ * H_, Wt + (size_t)H_ * H_,
                                                          qkvbias + 768, nullptr, krvr, nullptr, 0,
                                                          NR_, 1536, H_, 0, H_);
        // QKV projection -> row-major Q|K|V
        gemm_bf16_kernel<<<dim3(18, 16), blk, 0, stream>>>(xb, Wt, qkvbias, nullptr, qkvb, nullptr, 0,
                                                           ROWS, 2304, H_, 0, H_);
        transpose_vvr_kernel<<<dim3(36, 12), blk, 0, stream>>>(qkvb, krvr, vT, vrT);

        attn_kernel<<<dim3(L_ / 32, NH_, B_), blk, 0, stream>>>(qkvb, vT, krvr, vrT, maskp, ctxb);

        // O projection: split-K x2 (768 -> 2x384); bias added in add_ln
        transpose_cvt_kernel<<<dim3(24, 24), blk, 0, stream>>>(wo, Wt, H_, H_);
        gemm_bf16_kernel<<<dim3(6, 16, 2), blk, 0, stream>>>(ctxb, Wt, nullptr, y, nullptr, spill, NX,
                                                             ROWS, H_, H_, 0, 384);
        add_ln_kernel<<<ROWS, blk, 0, stream>>>(x, y, spill, nullptr, bo + (size_t)l * H_,
                                                ln1s + (size_t)l * H_, ln1b + (size_t)l * H_, x2, x2b);

        // MLP
        transpose_cvt_kernel<<<dim3(96, 24), blk, 0, stream>>>(w1, Wt, H_, M_);
        gemm_bf16_kernel<<<dim3(24, 16), blk, 0, stream>>>(x2b, Wt, b1 + (size_t)l * M_, nullptr, h1b, nullptr, 0,
                                                           ROWS, M_, H_, 1, H_);
        // W2: split-K x3 (3072 -> 3x1024); bias added in add_ln
        transpose_cvt_kernel<<<dim3(24, 96), blk, 0, stream>>>(w2, Wt, M_, H_);
        gemm_bf16_kernel<<<dim3(6, 16, 3), blk, 0, stream>>>(h1b, Wt, nullptr, y, nullptr, spill, NX,
                                                             ROWS, H_, M_, 0, 1024);

        float* outp = (l == NL_ - 1) ? (float*)d_out : x;
        __hip_bfloat16* outbp = (l == NL_ - 1) ? nullptr : xb;
        add_ln_kernel<<<ROWS, blk, 0, stream>>>(x2, y, spill, spill + NX, b2 + (size_t)l * H_,
                                                ln2s + (size_t)l * H_, ln2b + (size_t)l * H_, outp, outbp);
    }
}

// Round 6
// 1193.170 us; speedup vs baseline: 12.5696x; 1.0681x over previous
//
#include <hip/hip_runtime.h>
#include <hip/hip_bf16.h>
#include <math.h>

#define B_   4
#define L_   512
#define H_   768
#define NH_  12
#define HD_  64
#define M_   3072
#define NL_  6
#define RD_  128
#define NR_  255          // 2*RD-1
#define ROWS (B_*L_)      // 2048
#define COEF_ 0.125f      // 1/sqrt(64)

typedef __attribute__((ext_vector_type(8))) short bf16x8;
typedef __attribute__((ext_vector_type(4))) float f32x4;

// ---------------- utility ----------------

static __device__ __forceinline__ float wave_reduce_sum(float v) {
#pragma unroll
    for (int off = 32; off > 0; off >>= 1) v += __shfl_xor(v, off, 64);
    return v;
}

static __device__ __forceinline__ float gelu_f(float x) {
    float x3 = x * x * x;
    return 0.5f * x * (1.f + tanhf(0.7978845608028654f * (x + 0.044715f * x3)));
}

static __device__ __forceinline__ unsigned short f2bfu(float v) {
    __hip_bfloat16 h = __float2bfloat16(v);
    return *(unsigned short*)&h;
}

static __device__ __forceinline__ float bfu2f(unsigned short u) {
    union { float f; unsigned int i; } x;
    x.i = ((unsigned int)u) << 16;
    return x.f;
}

// async global->LDS, 16B per lane; LDS dest = wave-uniform base + lane*16
static __device__ __forceinline__ void gload16(const void* g, void* l) {
    __builtin_amdgcn_global_load_lds(
        (const __attribute__((address_space(1))) void*)g,
        (__attribute__((address_space(3))) void*)l,
        16, 0, 0);
}

// ---------------- embedding + LN (fp32 out + bf16 twin) ----------------

__global__ __launch_bounds__(256) void embed_ln_kernel(
    const int* __restrict__ tok, const int* __restrict__ seg,
    const float* __restrict__ temb, const float* __restrict__ semb,
    const float* __restrict__ sc, const float* __restrict__ bi,
    float* __restrict__ out, __hip_bfloat16* __restrict__ outb)
{
    int row = blockIdx.x;
    int t = threadIdx.x;
    int tid = tok[row], sid = seg[row];
    const float* tp = temb + (size_t)tid * H_;
    const float* sp = semb + (size_t)sid * H_;
    float v[3];
#pragma unroll
    for (int j = 0; j < 3; j++) { int idx = t + j * 256; v[j] = tp[idx] + sp[idx]; }

    __shared__ float red[4];
    __shared__ float bc;
    int lane = t & 63, wid = t >> 6;

    float s = v[0] + v[1] + v[2];
    s = wave_reduce_sum(s);
    if (lane == 0) red[wid] = s;
    __syncthreads();
    if (t == 0) bc = (red[0] + red[1] + red[2] + red[3]) * (1.f / H_);
    __syncthreads();
    float mean = bc;

    float c[3]; float ss = 0.f;
#pragma unroll
    for (int j = 0; j < 3; j++) { c[j] = v[j] - mean; ss += c[j] * c[j]; }
    ss = wave_reduce_sum(ss);
    __syncthreads();
    if (lane == 0) red[wid] = ss;
    __syncthreads();
    if (t == 0) bc = rsqrtf((red[0] + red[1] + red[2] + red[3]) * (1.f / H_) + 1e-12f);
    __syncthreads();
    float r = bc;
#pragma unroll
    for (int j = 0; j < 3; j++) {
        int idx = t + j * 256;
        float o = c[j] * r * sc[idx] + bi[idx];
        out[(size_t)row * H_ + idx] = o;
        outb[(size_t)row * H_ + idx] = __float2bfloat16(o);
    }
}

// ---------------- residual add (+partials +bias) + LN (fp32 out + optional bf16 twin) ----------------

__global__ __launch_bounds__(256) void add_ln_kernel(
    const float* __restrict__ x, const float* __restrict__ p0,
    const float* __restrict__ p1, const float* __restrict__ p2,
    const float* __restrict__ bias,
    const float* __restrict__ sc, const float* __restrict__ bi,
    float* __restrict__ out, __hip_bfloat16* __restrict__ outb)
{
    int row = blockIdx.x;
    int t = threadIdx.x;
    const float* xp = x + (size_t)row * H_;
    const float* q0 = p0 + (size_t)row * H_;
    const float* q1 = p1 ? p1 + (size_t)row * H_ : nullptr;
    const float* q2 = p2 ? p2 + (size_t)row * H_ : nullptr;
    float v[3];
#pragma unroll
    for (int j = 0; j < 3; j++) {
        int idx = t + j * 256;
        float a = xp[idx] + q0[idx];
        if (q1) a += q1[idx];
        if (q2) a += q2[idx];
        if (bias) a += bias[idx];
        v[j] = a;
    }

    __shared__ float red[4];
    __shared__ float bc;
    int lane = t & 63, wid = t >> 6;

    float s = v[0] + v[1] + v[2];
    s = wave_reduce_sum(s);
    if (lane == 0) red[wid] = s;
    __syncthreads();
    if (t == 0) bc = (red[0] + red[1] + red[2] + red[3]) * (1.f / H_);
    __syncthreads();
    float mean = bc;

    float c[3]; float ss = 0.f;
#pragma unroll
    for (int j = 0; j < 3; j++) { c[j] = v[j] - mean; ss += c[j] * c[j]; }
    ss = wave_reduce_sum(ss);
    __syncthreads();
    if (lane == 0) red[wid] = ss;
    __syncthreads();
    if (t == 0) bc = rsqrtf((red[0] + red[1] + red[2] + red[3]) * (1.f / H_) + 1e-12f);
    __syncthreads();
    float r = bc;
#pragma unroll
    for (int j = 0; j < 3; j++) {
        int idx = t + j * 256;
        float o = c[j] * r * sc[idx] + bi[idx];
        out[(size_t)row * H_ + idx] = o;
        if (outb) outb[(size_t)row * H_ + idx] = __float2bfloat16(o);
    }
}

// ---------------- transpose + fp32->bf16 weight pack: in[K][N] f32 -> out[N][K] bf16 ----------------

__global__ __launch_bounds__(256) void transpose_cvt_kernel(
    const float* __restrict__ in, __hip_bfloat16* __restrict__ out, int K, int N)
{
    __shared__ float tile[32][33];
    int bx = blockIdx.x * 32;   // n
    int by = blockIdx.y * 32;   // k
    int tx = threadIdx.x & 31, ty = threadIdx.x >> 5;
#pragma unroll
    for (int i = 0; i < 4; i++)
        tile[ty + 8 * i][tx] = in[(size_t)(by + ty + 8 * i) * N + bx + tx];
    __syncthreads();
#pragma unroll
    for (int i = 0; i < 4; i++)
        out[(size_t)(bx + ty + 8 * i) * K + by + tx] = __float2bfloat16(tile[tx][ty + 8 * i]);
}

// batched variant for 3 same-shape square weights (wq,wk,wv), K=N=768
__global__ __launch_bounds__(256) void transpose_cvt3_kernel(
    const float* __restrict__ in0, const float* __restrict__ in1, const float* __restrict__ in2,
    __hip_bfloat16* __restrict__ out)
{
    const float* in = blockIdx.z == 0 ? in0 : (blockIdx.z == 1 ? in1 : in2);
    __hip_bfloat16* o = out + (size_t)blockIdx.z * H_ * H_;
    __shared__ float tile[32][33];
    int bx = blockIdx.x * 32;
    int by = blockIdx.y * 32;
    int tx = threadIdx.x & 31, ty = threadIdx.x >> 5;
#pragma unroll
    for (int i = 0; i < 4; i++)
        tile[ty + 8 * i][tx] = in[(size_t)(by + ty + 8 * i) * H_ + bx + tx];
    __syncthreads();
#pragma unroll
    for (int i = 0; i < 4; i++)
        o[(size_t)(bx + ty + 8 * i) * H_ + by + tx] = __float2bfloat16(tile[tx][ty + 8 * i]);
}

__global__ void cvt_kernel(const float* __restrict__ in, __hip_bfloat16* __restrict__ out, int n) {
    int i = blockIdx.x * blockDim.x + threadIdx.x;
    int stride = gridDim.x * blockDim.x;
    for (; i < n; i += stride) out[i] = __float2bfloat16(in[i]);
}

__global__ void pack_qkv_bias_kernel(const float* __restrict__ bq, const float* __restrict__ bk,
                                     const float* __restrict__ bv, float* __restrict__ out) {
    int i = blockIdx.x * 256 + threadIdx.x;
    if (i >= 2304) return;
    out[i] = i < 768 ? bq[i] : (i < 1536 ? bk[i - 768] : bv[i - 1536]);
}

// ---------------- fused V / VR transpose ----------------
// bx<32: qkvb[2048][2304] cols 1536.. -> vT[b][h][64][512]
// bx>=32: krvr[255][1536] cols 768..  -> vrT[h][64][256] (j>=255 -> 0)

__global__ __launch_bounds__(256) void transpose_vvr_kernel(
    const __hip_bfloat16* __restrict__ qkvb, const __hip_bfloat16* __restrict__ krvr,
    __hip_bfloat16* __restrict__ vT, __hip_bfloat16* __restrict__ vrT)
{
    __shared__ unsigned short tile[64][72];
    const int bx = blockIdx.x;
    const int h  = blockIdx.y;
    const int t = threadIdx.x;
    const int r = t >> 2, c0 = (t & 3) * 16;
    if (bx < 32) {
        const int kb = bx * 64;
        const unsigned short* src = (const unsigned short*)qkvb + (size_t)(kb + r) * 2304 + 1536 + h * 64 + c0;
        *(uint4*)&tile[r][c0]     = *(const uint4*)src;
        *(uint4*)&tile[r][c0 + 8] = *(const uint4*)(src + 8);
        __syncthreads();
        unsigned short outv[16];
#pragma unroll
        for (int i = 0; i < 16; i++) outv[i] = tile[c0 + i][r];
        unsigned short* dst = (unsigned short*)vT +
            ((size_t)((kb >> 9) * NH_ + h) * 64 + r) * 512 + (kb & 511) + c0;
        *(uint4*)dst       = *(uint4*)&outv[0];
        *(uint4*)(dst + 8) = *(uint4*)&outv[8];
    } else {
        const int jb = (bx - 32) * 64;
        const int j = jb + r;
        if (j < NR_) {
            const unsigned short* src = (const unsigned short*)krvr + (size_t)j * 1536 + 768 + h * 64 + c0;
            *(uint4*)&tile[r][c0]     = *(const uint4*)src;
            *(uint4*)&tile[r][c0 + 8] = *(const uint4*)(src + 8);
        } else {
#pragma unroll
            for (int i = 0; i < 16; i++) tile[r][c0 + i] = 0;
        }
        __syncthreads();
        unsigned short outv[16];
#pragma unroll
        for (int i = 0; i < 16; i++) outv[i] = tile[c0 + i][r];
        unsigned short* dst = (unsigned short*)vrT + ((size_t)(h * 64) + r) * 256 + jb + c0;
        *(uint4*)dst       = *(uint4*)&outv[0];
        *(uint4*)(dst + 8) = *(uint4*)&outv[8];
    }
}

// ---------------- bf16 MFMA GEMM, 2-phase double-buffered, optional split-K ----------------

#define TK 64

__global__ __launch_bounds__(256) void gemm_bf16_kernel(
    const __hip_bfloat16* __restrict__ A, const __hip_bfloat16* __restrict__ Bt,
    const float* __restrict__ bias, float* __restrict__ Cf, __hip_bfloat16* __restrict__ Cb,
    float* __restrict__ CfX, size_t xstride,
    int M, int N, int K, int act, int ksplit)
{
    __shared__ __hip_bfloat16 As[2][128 * TK];
    __shared__ __hip_bfloat16 Bs[2][128 * TK];
    const int t = threadIdx.x;
    const int lane = t & 63;
    const int w = t >> 6;
    const int lq = lane & 15, lg = lane >> 4;
    const int wm = (w >> 1) * 64, wn = (w & 1) * 64;

    const int nbx = gridDim.x;
    const int nwg = nbx * gridDim.y;
    int wgid = blockIdx.y * nbx + blockIdx.x;
    if ((nwg & 7) == 0) { int qq = nwg >> 3; wgid = (wgid & 7) * qq + (wgid >> 3); }
    const int bm = (wgid / nbx) * 128, bn = (wgid % nbx) * 128;
    const int kbase = blockIdx.z * ksplit;

    f32x4 acc[4][4];
#pragma unroll
    for (int i = 0; i < 4; i++)
#pragma unroll
        for (int j = 0; j < 4; j++) acc[i][j] = (f32x4){0.f, 0.f, 0.f, 0.f};

    const int rlane = lane >> 3;
    const int cswz = (((lane & 7) * 16) ^ ((rlane & 7) << 4)) >> 1;   // elements
    const __hip_bfloat16* ga[4];
    const __hip_bfloat16* gb[4];
    int lofs[4];
#pragma unroll
    for (int c = 0; c < 4; c++) {
        int rowa = bm + w * 32 + c * 8 + rlane; if (rowa >= M) rowa = M - 1;
        int rowb = bn + w * 32 + c * 8 + rlane;
        ga[c] = A  + (size_t)rowa * K + kbase + cswz;
        gb[c] = Bt + (size_t)rowb * K + kbase + cswz;
        lofs[c] = (w * 32 + c * 8) * TK;
    }

    const int nt = ksplit / TK;
#pragma unroll
    for (int c = 0; c < 4; c++) {
        gload16(ga[c], &As[0][lofs[c]]);
        gload16(gb[c], &Bs[0][lofs[c]]);
    }
    __syncthreads();

    int cur = 0;
    for (int kt = 0; kt < nt; kt++) {
        if (kt + 1 < nt) {
#pragma unroll
            for (int c = 0; c < 4; c++) {
                gload16(ga[c] + (kt + 1) * TK, &As[cur ^ 1][lofs[c]]);
                gload16(gb[c] + (kt + 1) * TK, &Bs[cur ^ 1][lofs[c]]);
            }
        }
#pragma unroll
        for (int kh = 0; kh < 2; kh++) {
            const int kb = kh * 64 + lg * 16;
            bf16x8 af[4], bfr[4];
#pragma unroll
            for (int i = 0; i < 4; i++) {
                int ra = wm + i * 16 + lq;
                af[i]  = *(const bf16x8*)((const char*)&As[cur][0] + ra * 128 + (kb ^ ((ra & 7) << 4)));
                int rb = wn + i * 16 + lq;
                bfr[i] = *(const bf16x8*)((const char*)&Bs[cur][0] + rb * 128 + (kb ^ ((rb & 7) << 4)));
            }
#pragma unroll
            for (int i = 0; i < 4; i++)
#pragma unroll
                for (int j = 0; j < 4; j++)
                    acc[i][j] = __builtin_amdgcn_mfma_f32_16x16x32_bf16(af[i], bfr[j], acc[i][j], 0, 0, 0);
        }
        __syncthreads();
        cur ^= 1;
    }

    const int lr = lg * 4;
    float* outf = (blockIdx.z == 0) ? Cf : (CfX + (size_t)(blockIdx.z - 1) * xstride);
#pragma unroll
    for (int i = 0; i < 4; i++) {
#pragma unroll
        for (int j = 0; j < 4; j++) {
            int col = bn + wn + j * 16 + lq;
            float bsv = bias ? bias[col] : 0.f;
            int row0 = bm + wm + i * 16 + lr;
#pragma unroll
            for (int rr = 0; rr < 4; rr++) {
                int row = row0 + rr;
                if (row >= M) continue;
                float v = acc[i][j][rr] + bsv;
                if (act) v = gelu_f(v);
                if (Cb && blockIdx.z == 0) Cb[(size_t)row * N + col] = __float2bfloat16(v);
                else                       outf[(size_t)row * N + col] = v;
            }
        }
    }
}

// ---------------- MFMA rel-pos attention ----------------
// 1D grid of 768, XCD-aware decode: block i -> xcd=i&7 owns pairs p = xcd+8m.
// 256 threads (4 waves). 32 q-rows per block.

#define PS_LD 520   // bf16 elems per Ps row (512 + 8 pad)
#define PR_LD 264   // bf16 elems per Rq/prel row (256 + 8 pad)

__global__ __launch_bounds__(256, 3) void attn_kernel(
    const __hip_bfloat16* __restrict__ qkvb,  // [2048][2304]
    const __hip_bfloat16* __restrict__ vT,    // [B][NH][64][512]
    const __hip_bfloat16* __restrict__ krvr,  // [255][1536]
    const __hip_bfloat16* __restrict__ vrT,   // [NH][64][256] (col 255 zero)
    const int* __restrict__ mask,
    __hip_bfloat16* __restrict__ ctxb)        // [2048][768]
{
    __shared__ unsigned short RqPrel[32 * PR_LD];
    __shared__ unsigned short Ps[32 * PS_LD];
    __shared__ float mstat[32 * 4];
    __shared__ float sstat[32 * 4];
    __shared__ float maskb[512];

    // XCD-aware decode: hw id i -> xcd c = i&7, slot s = i>>3;
    // pair p = c + 8*(s>>4) (6 pairs per XCD), qt = s&15.
    const int i_ = blockIdx.x;
    const int c_ = i_ & 7, s_ = i_ >> 3;
    const int p_ = c_ + 8 * (s_ >> 4);
    const int qt = s_ & 15;
    const int b = p_ / 12, h = p_ % 12;

    const int t = threadIdx.x;
    const int lane = t & 63, w = t >> 6;
    const int lq = lane & 15, lg = lane >> 4;

    maskb[t]       = mask[b * L_ + t]       ? 0.f : -1e30f;
    maskb[t + 256] = mask[b * L_ + t + 256] ? 0.f : -1e30f;

    const char* Qbase = (const char*)qkvb + ((size_t)(b * L_ + qt * 32) * 2304 + h * 64) * 2;
    const char* Kbase = (const char*)qkvb + ((size_t)(b * L_) * 2304 + 768 + h * 64) * 2;

    // hoist Q fragments once (reused by R and S phases)
    bf16x8 afq[2][2];
#pragma unroll
    for (int ks = 0; ks < 2; ks++) {
        const int kofs = ks * 64 + lg * 16;
        afq[ks][0] = *(const bf16x8*)(Qbase + (size_t)lq * 4608 + kofs);
        afq[ks][1] = *(const bf16x8*)(Qbase + (size_t)(16 + lq) * 4608 + kofs);
    }

    // ---- R phase: Rq[32][256] = Q @ KR^T ----
    {
        f32x4 accr[2][4];
#pragma unroll
        for (int i = 0; i < 2; i++)
#pragma unroll
            for (int j = 0; j < 4; j++) accr[i][j] = (f32x4){0.f, 0.f, 0.f, 0.f};
#pragma unroll
        for (int ks = 0; ks < 2; ks++) {
            const int kofs = ks * 64 + lg * 16;
            bf16x8 bkr_[4];
#pragma unroll
            for (int jt = 0; jt < 4; jt++) {
                int j = w * 64 + jt * 16 + lq;
                int jr = j > 254 ? 254 : j;
                bkr_[jt] = *(const bf16x8*)((const char*)krvr + (size_t)jr * 3072 + h * 128 + kofs);
            }
#pragma unroll
            for (int jt = 0; jt < 4; jt++) {
                accr[0][jt] = __builtin_amdgcn_mfma_f32_16x16x32_bf16(afq[ks][0], bkr_[jt], accr[0][jt], 0, 0, 0);
                accr[1][jt] = __builtin_amdgcn_mfma_f32_16x16x32_bf16(afq[ks][1], bkr_[jt], accr[1][jt], 0, 0, 0);
            }
        }
#pragma unroll
        for (int it = 0; it < 2; it++)
#pragma unroll
            for (int jt = 0; jt < 4; jt++)
#pragma unroll
                for (int r = 0; r < 4; r++)
                    RqPrel[(it * 16 + lg * 4 + r) * PR_LD + w * 64 + jt * 16 + lq] = f2bfu(accr[it][jt][r]);
    }
    __syncthreads();

    // ---- S phase: Q @ K^T (wave w owns key strip w*128..+128), batched loads ----
    f32x4 accs[2][8];
#pragma unroll
    for (int i = 0; i < 2; i++)
#pragma unroll
        for (int j = 0; j < 8; j++) accs[i][j] = (f32x4){0.f, 0.f, 0.f, 0.f};
#pragma unroll
    for (int ks = 0; ks < 2; ks++) {
        const int kofs = ks * 64 + lg * 16;
        bf16x8 bk_[8];
#pragma unroll
        for (int jt = 0; jt < 8; jt++) {
            int key = w * 128 + jt * 16 + lq;
            bk_[jt] = *(const bf16x8*)(Kbase + (size_t)key * 4608 + kofs);
        }
#pragma unroll
        for (int jt = 0; jt < 8; jt++) {
            accs[0][jt] = __builtin_amdgcn_mfma_f32_16x16x32_bf16(afq[ks][0], bk_[jt], accs[0][jt], 0, 0, 0);
            accs[1][jt] = __builtin_amdgcn_mfma_f32_16x16x32_bf16(afq[ks][1], bk_[jt], accs[1][jt], 0, 0, 0);
        }
    }

    // ---- S epilogue: add rel score + mask ----
#pragma unroll
    for (int it = 0; it < 2; it++) {
#pragma unroll
        for (int r = 0; r < 4; r++) {
            int q = it * 16 + lg * 4 + r;
            int qg = qt * 32 + q;
            float mx = -INFINITY;
#pragma unroll
            for (int jt = 0; jt < 8; jt++) {
                int k = w * 128 + jt * 16 + lq;
                int jc = k - qg + 127;
                jc = jc < 0 ? 0 : (jc > 254 ? 254 : jc);
                float s = (accs[it][jt][r] + bfu2f(RqPrel[q * PR_LD + jc])) * COEF_ + maskb[k];
                accs[it][jt][r] = s;
                mx = fmaxf(mx, s);
            }
#pragma unroll
            for (int off = 1; off < 16; off <<= 1) mx = fmaxf(mx, __shfl_xor(mx, off, 64));
            if (lq == 0) mstat[q * 4 + w] = mx;
        }
    }
    __syncthreads();

    // ---- exp + row sums + write P ----
#pragma unroll
    for (int it = 0; it < 2; it++) {
#pragma unroll
        for (int r = 0; r < 4; r++) {
            int q = it * 16 + lg * 4 + r;
            float4 mv = *(const float4*)&mstat[q * 4];
            float gm = fmaxf(fmaxf(mv.x, mv.y), fmaxf(mv.z, mv.w));
            float ssum = 0.f;
#pragma unroll
            for (int jt = 0; jt < 8; jt++) {
                int k = w * 128 + jt * 16 + lq;
                float p = __expf(accs[it][jt][r] - gm);
                ssum += p;
                Ps[q * PS_LD + k] = f2bfu(p);
            }
#pragma unroll
            for (int off = 1; off < 16; off <<= 1) ssum += __shfl_xor(ssum, off, 64);
            if (lq == 0) sstat[q * 4 + w] = ssum;
        }
    }
    __syncthreads();

    // ---- prel construction + PV operand prefetch (loads land under prel work) ----
    const __hip_bfloat16* vTb  = vT  + (((size_t)(b * NH_ + h) * 64) + w * 16 + lq) * 512 + lg * 8;
    const __hip_bfloat16* vrTb = vrT + ((size_t)(h * 64) + w * 16 + lq) * 256 + lg * 8;
    bf16x8 bvpre[8], vrpre[8];
#pragma unroll
    for (int ks = 0; ks < 8; ks++) {
        bvpre[ks] = *(const bf16x8*)(vTb + ks * 32);
        vrpre[ks] = *(const bf16x8*)(vrTb + ks * 32);
    }
    {
        int q = t >> 3, sub = t & 7;
        int qg = qt * 32 + q;
#pragma unroll
        for (int jj = 0; jj < 32; jj++) {
            int j = sub + 8 * jj;
            if (j == 0 || j == 254) continue;
            if (j == 255) { RqPrel[q * PR_LD + 255] = 0; continue; }
            int k = qg + j - 127;
            unsigned short val = ((unsigned)k < 512u) ? Ps[q * PS_LD + k] : (unsigned short)0;
            RqPrel[q * PR_LD + j] = val;
        }
    }
    {
        int task = t >> 2, ts = t & 3;
        int q = task >> 1, side = task & 1;
        int qg = qt * 32 + q;
        float sum = 0.f;
        if (side == 0) {
            int hi = qg - 127;
            for (int k = ts; k <= hi; k += 4) sum += bfu2f(Ps[q * PS_LD + k]);
        } else {
            for (int k = qg + 127 + ts; k < 512; k += 4) sum += bfu2f(Ps[q * PS_LD + k]);
        }
        sum += __shfl_xor(sum, 1, 64);
        sum += __shfl_xor(sum, 2, 64);
        if (ts == 0) RqPrel[q * PR_LD + (side == 0 ? 0 : 254)] = f2bfu(sum);
    }
    __syncthreads();

    // ---- PV phase: out strip d in [w*16, w*16+16) ----
    f32x4 accv[2];
    accv[0] = (f32x4){0.f, 0.f, 0.f, 0.f};
    accv[1] = (f32x4){0.f, 0.f, 0.f, 0.f};

#pragma unroll
    for (int ks = 0; ks < 8; ks++) {
        bf16x8 pa0 = *(const bf16x8*)((const char*)Ps + (size_t)lq * (PS_LD * 2) + ks * 64 + lg * 16);
        bf16x8 pa1 = *(const bf16x8*)((const char*)Ps + (size_t)(16 + lq) * (PS_LD * 2) + ks * 64 + lg * 16);
        accv[0] = __builtin_amdgcn_mfma_f32_16x16x32_bf16(pa0, bvpre[ks], accv[0], 0, 0, 0);
        accv[1] = __builtin_amdgcn_mfma_f32_16x16x32_bf16(pa1, bvpre[ks], accv[1], 0, 0, 0);
    }
#pragma unroll
    for (int ks = 8; ks < 16; ks++) {
        bf16x8 bv = *(const bf16x8*)(vTb + ks * 32);
        bf16x8 pa0 = *(const bf16x8*)((const char*)Ps + (size_t)lq * (PS_LD * 2) + ks * 64 + lg * 16);
        bf16x8 pa1 = *(const bf16x8*)((const char*)Ps + (size_t)(16 + lq) * (PS_LD * 2) + ks * 64 + lg * 16);
        accv[0] = __builtin_amdgcn_mfma_f32_16x16x32_bf16(pa0, bv, accv[0], 0, 0, 0);
        accv[1] = __builtin_amdgcn_mfma_f32_16x16x32_bf16(pa1, bv, accv[1], 0, 0, 0);
    }
#pragma unroll
    for (int ks = 0; ks < 8; ks++) {
        bf16x8 pa0 = *(const bf16x8*)((const char*)RqPrel + (size_t)lq * (PR_LD * 2) + ks * 64 + lg * 16);
        bf16x8 pa1 = *(const bf16x8*)((const char*)RqPrel + (size_t)(16 + lq) * (PR_LD * 2) + ks * 64 + lg * 16);
        accv[0] = __builtin_amdgcn_mfma_f32_16x16x32_bf16(pa0, vrpre[ks], accv[0], 0, 0, 0);
        accv[1] = __builtin_amdgcn_mfma_f32_16x16x32_bf16(pa1, vrpre[ks], accv[1], 0, 0, 0);
    }

#pragma unroll
    for (int it = 0; it < 2; it++) {
#pragma unroll
        for (int r = 0; r < 4; r++) {
            int q = it * 16 + lg * 4 + r;
            float4 sv = *(const float4*)&sstat[q * 4];
            float inv = 1.f / (sv.x + sv.y + sv.z + sv.w);
            ctxb[(size_t)(b * L_ + qt * 32 + q) * 768 + h * 64 + w * 16 + lq] =
                __float2bfloat16(accv[it][r] * inv);
        }
    }
}

// ---------------- host ----------------

extern "C" void kernel_launch(void* const* d_in, const int* in_sizes, int n_in,
                              void* d_out, int out_size, void* d_ws, size_t ws_size,
                              hipStream_t stream)
{
    const int*   tok    = (const int*)d_in[0];
    const int*   seg    = (const int*)d_in[1];
    const int*   maskp  = (const int*)d_in[2];
    const float* temb   = (const float*)d_in[3];
    const float* semb   = (const float*)d_in[4];
    const float* esc    = (const float*)d_in[5];
    const float* ebi    = (const float*)d_in[6];
    const float* Wq     = (const float*)d_in[7];
    const float* bq     = (const float*)d_in[8];
    const float* Wk     = (const float*)d_in[9];
    const float* bk     = (const float*)d_in[10];
    const float* Wv     = (const float*)d_in[11];
    const float* bv     = (const float*)d_in[12];
    const float* relpos = (const float*)d_in[13];
    const float* Wo     = (const float*)d_in[14];
    const float* bo     = (const float*)d_in[15];
    const float* ln1s   = (const float*)d_in[16];
    const float* ln1b   = (const float*)d_in[17];
    const float* W1     = (const float*)d_in[18];
    const float* b1     = (const float*)d_in[19];
    const float* W2     = (const float*)d_in[20];
    const float* b2     = (const float*)d_in[21];
    const float* ln2s   = (const float*)d_in[22];
    const float* ln2b   = (const float*)d_in[23];

    const size_t NX = (size_t)ROWS * H_;
    float* x       = (float*)d_ws;
    float* x2      = x + NX;
    float* y       = x2 + NX;
    float* qkvbias = y + NX;                                   // 2304 f32
    __hip_bfloat16* xb    = (__hip_bfloat16*)(qkvbias + 2304);
    __hip_bfloat16* x2b   = xb    + NX;
    __hip_bfloat16* ctxb  = x2b   + NX;
    __hip_bfloat16* qkvb  = ctxb  + NX;                        // 2048*2304
    __hip_bfloat16* vT    = qkvb  + (size_t)ROWS * 2304;       // 4*12*64*512
    __hip_bfloat16* krvr  = vT    + (size_t)B_ * NH_ * 64 * 512; // 255*1536
    __hip_bfloat16* vrT   = krvr  + (size_t)NR_ * 1536;        // 12*64*256
    __hip_bfloat16* relb  = vrT   + (size_t)NH_ * 64 * 256;    // 6*255*768
    __hip_bfloat16* Wt    = relb  + (size_t)NL_ * NR_ * H_;    // 3072*768
    __hip_bfloat16* h1b   = Wt    + (size_t)M_ * H_;           // 2048*3072

    float* spill = (float*)qkvb;   // split-K partials alias qkvb/vT (dead after attn)

    dim3 blk(256);

    embed_ln_kernel<<<ROWS, blk, 0, stream>>>(tok, seg, temb, semb, esc, ebi, x, xb);
    cvt_kernel<<<1024, blk, 0, stream>>>(relpos, relb, NL_ * NR_ * H_);

    for (int l = 0; l < NL_; l++) {
        const float* wq = Wq + (size_t)l * H_ * H_;
        const float* wk = Wk + (size_t)l * H_ * H_;
        const float* wv = Wv + (size_t)l * H_ * H_;
        const float* wo = Wo + (size_t)l * H_ * H_;
        const float* w1 = W1 + (size_t)l * H_ * M_;
        const float* w2 = W2 + (size_t)l * M_ * H_;

        transpose_cvt3_kernel<<<dim3(24, 24, 3), blk, 0, stream>>>(wq, wk, wv, Wt);
        pack_qkv_bias_kernel<<<9, blk, 0, stream>>>(bq + (size_t)l * H_, bk + (size_t)l * H_, bv + (size_t)l * H_, qkvbias);

        gemm_bf16_kernel<<<dim3(12, 2), blk, 0, stream>>>(relb + (size_t)l * NR_ * H_, Wt + (size_t)H_ * H_,
                                                          qkvbias + 768, nullptr, krvr, nullptr, 0,
                                                          NR_, 1536, H_, 0, H_);
        gemm_bf16_kernel<<<dim3(18, 16), blk, 0, stream>>>(xb, Wt, qkvbias, nullptr, qkvb, nullptr, 0,
                                                           ROWS, 2304, H_, 0, H_);
        transpose_vvr_kernel<<<dim3(36, 12), blk, 0, stream>>>(qkvb, krvr, vT, vrT);

        attn_kernel<<<dim3(768), blk, 0, stream>>>(qkvb, vT, krvr, vrT, maskp, ctxb);

        transpose_cvt_kernel<<<dim3(24, 24), blk, 0, stream>>>(wo, Wt, H_, H_);
        gemm_bf16_kernel<<<dim3(6, 16, 2), blk, 0, stream>>>(ctxb, Wt, nullptr, y, nullptr, spill, NX,
                                                             ROWS, H_, H_, 0, 384);
        add_ln_kernel<<<ROWS, blk, 0, stream>>>(x, y, spill, nullptr, bo + (size_t)l * H_,
                                                ln1s + (size_t)l * H_, ln1b + (size_t)l * H_, x2, x2b);

        transpose_cvt_kernel<<<dim3(96, 24), blk, 0, stream>>>(w1, Wt, H_, M_);
        gemm_bf16_kernel<<<dim3(24, 16), blk, 0, stream>>>(x2b, Wt, b1 + (size_t)l * M_, nullptr, h1b, nullptr, 0,
                                                           ROWS, M_, H_, 1, H_);
        transpose_cvt_kernel<<<dim3(24, 96), blk, 0, stream>>>(w2, Wt, M_, H_);
        gemm_bf16_kernel<<<dim3(6, 16, 3), blk, 0, stream>>>(h1b, Wt, nullptr, y, nullptr, spill, NX,
                                                             ROWS, H_, M_, 0, 1024);

        float* outp = (l == NL_ - 1) ? (float*)d_out : x;
        __hip_bfloat16* outbp = (l == NL_ - 1) ? nullptr : xb;
        add_ln_kernel<<<ROWS, blk, 0, stream>>>(x2, y, spill, spill + NX, b2 + (size_t)l * H_,
                                                ln2s + (size_t)l * H_, ln2b + (size_t)l * H_, outp, outbp);
    }
}

// Round 7
// 899.409 us; speedup vs baseline: 16.6750x; 1.3266x over previous
//
#include <hip/hip_runtime.h>
#include <hip/hip_bf16.h>
#include <math.h>

#define B_   4
#define L_   512
#define H_   768
#define NH_  12
#define HD_  64
#define M_   3072
#define NL_  6
#define RD_  128
#define NR_  255          // 2*RD-1
#define ROWS (B_*L_)      // 2048
#define MEXT 2304         // ROWS + NR_ + 1 pad (merged QKV+rel A rows)
#define COEF_ 0.125f      // 1/sqrt(64)

typedef __attribute__((ext_vector_type(8))) short bf16x8;
typedef __attribute__((ext_vector_type(4))) float f32x4;

// ---------------- utility ----------------

static __device__ __forceinline__ float wave_reduce_sum(float v) {
#pragma unroll
    for (int off = 32; off > 0; off >>= 1) v += __shfl_xor(v, off, 64);
    return v;
}

static __device__ __forceinline__ float gelu_f(float x) {
    float x3 = x * x * x;
    return 0.5f * x * (1.f + tanhf(0.7978845608028654f * (x + 0.044715f * x3)));
}

static __device__ __forceinline__ unsigned short f2bfu(float v) {
    __hip_bfloat16 h = __float2bfloat16(v);
    return *(unsigned short*)&h;
}

static __device__ __forceinline__ float bfu2f(unsigned short u) {
    union { float f; unsigned int i; } x;
    x.i = ((unsigned int)u) << 16;
    return x.f;
}

// async global->LDS, 16B per lane; LDS dest = wave-uniform base + lane*16
static __device__ __forceinline__ void gload16(const void* g, void* l) {
    __builtin_amdgcn_global_load_lds(
        (const __attribute__((address_space(1))) void*)g,
        (__attribute__((address_space(3))) void*)l,
        16, 0, 0);
}

// ---------------- embedding + LN (fp32 out + bf16 twin) ----------------

__global__ __launch_bounds__(256) void embed_ln_kernel(
    const int* __restrict__ tok, const int* __restrict__ seg,
    const float* __restrict__ temb, const float* __restrict__ semb,
    const float* __restrict__ sc, const float* __restrict__ bi,
    float* __restrict__ out, __hip_bfloat16* __restrict__ outb)
{
    int row = blockIdx.x;
    int t = threadIdx.x;
    int tid = tok[row], sid = seg[row];
    const float* tp = temb + (size_t)tid * H_;
    const float* sp = semb + (size_t)sid * H_;
    float v[3];
#pragma unroll
    for (int j = 0; j < 3; j++) { int idx = t + j * 256; v[j] = tp[idx] + sp[idx]; }

    __shared__ float red[4];
    __shared__ float bc;
    int lane = t & 63, wid = t >> 6;

    float s = v[0] + v[1] + v[2];
    s = wave_reduce_sum(s);
    if (lane == 0) red[wid] = s;
    __syncthreads();
    if (t == 0) bc = (red[0] + red[1] + red[2] + red[3]) * (1.f / H_);
    __syncthreads();
    float mean = bc;

    float c[3]; float ss = 0.f;
#pragma unroll
    for (int j = 0; j < 3; j++) { c[j] = v[j] - mean; ss += c[j] * c[j]; }
    ss = wave_reduce_sum(ss);
    __syncthreads();
    if (lane == 0) red[wid] = ss;
    __syncthreads();
    if (t == 0) bc = rsqrtf((red[0] + red[1] + red[2] + red[3]) * (1.f / H_) + 1e-12f);
    __syncthreads();
    float r = bc;
#pragma unroll
    for (int j = 0; j < 3; j++) {
        int idx = t + j * 256;
        float o = c[j] * r * sc[idx] + bi[idx];
        out[(size_t)row * H_ + idx] = o;
        outb[(size_t)row * H_ + idx] = __float2bfloat16(o);
    }
}

// ---------------- residual add (+partials +bias) + LN (fp32 out + optional bf16 twin) ----------------

__global__ __launch_bounds__(256) void add_ln_kernel(
    const float* __restrict__ x, const float* __restrict__ p0,
    const float* __restrict__ p1, const float* __restrict__ p2,
    const float* __restrict__ bias,
    const float* __restrict__ sc, const float* __restrict__ bi,
    float* __restrict__ out, __hip_bfloat16* __restrict__ outb)
{
    int row = blockIdx.x;
    int t = threadIdx.x;
    const float* xp = x + (size_t)row * H_;
    const float* q0 = p0 + (size_t)row * H_;
    const float* q1 = p1 ? p1 + (size_t)row * H_ : nullptr;
    const float* q2 = p2 ? p2 + (size_t)row * H_ : nullptr;
    float v[3];
#pragma unroll
    for (int j = 0; j < 3; j++) {
        int idx = t + j * 256;
        float a = xp[idx] + q0[idx];
        if (q1) a += q1[idx];
        if (q2) a += q2[idx];
        if (bias) a += bias[idx];
        v[j] = a;
    }

    __shared__ float red[4];
    __shared__ float bc;
    int lane = t & 63, wid = t >> 6;

    float s = v[0] + v[1] + v[2];
    s = wave_reduce_sum(s);
    if (lane == 0) red[wid] = s;
    __syncthreads();
    if (t == 0) bc = (red[0] + red[1] + red[2] + red[3]) * (1.f / H_);
    __syncthreads();
    float mean = bc;

    float c[3]; float ss = 0.f;
#pragma unroll
    for (int j = 0; j < 3; j++) { c[j] = v[j] - mean; ss += c[j] * c[j]; }
    ss = wave_reduce_sum(ss);
    __syncthreads();
    if (lane == 0) red[wid] = ss;
    __syncthreads();
    if (t == 0) bc = rsqrtf((red[0] + red[1] + red[2] + red[3]) * (1.f / H_) + 1e-12f);
    __syncthreads();
    float r = bc;
#pragma unroll
    for (int j = 0; j < 3; j++) {
        int idx = t + j * 256;
        float o = c[j] * r * sc[idx] + bi[idx];
        out[(size_t)row * H_ + idx] = o;
        if (outb) outb[(size_t)row * H_ + idx] = __float2bfloat16(o);
    }
}

// ---------------- transpose + fp32->bf16 weight pack: in[K][N] f32 -> out[N][K] bf16 ----------------

__global__ __launch_bounds__(256) void transpose_cvt_kernel(
    const float* __restrict__ in, __hip_bfloat16* __restrict__ out, int K, int N)
{
    __shared__ float tile[32][33];
    int bx = blockIdx.x * 32;   // n
    int by = blockIdx.y * 32;   // k
    int tx = threadIdx.x & 31, ty = threadIdx.x >> 5;
#pragma unroll
    for (int i = 0; i < 4; i++)
        tile[ty + 8 * i][tx] = in[(size_t)(by + ty + 8 * i) * N + bx + tx];
    __syncthreads();
#pragma unroll
    for (int i = 0; i < 4; i++)
        out[(size_t)(bx + ty + 8 * i) * K + by + tx] = __float2bfloat16(tile[tx][ty + 8 * i]);
}

// batched variant for 3 same-shape square weights (wq,wk,wv), K=N=768
__global__ __launch_bounds__(256) void transpose_cvt3_kernel(
    const float* __restrict__ in0, const float* __restrict__ in1, const float* __restrict__ in2,
    __hip_bfloat16* __restrict__ out)
{
    const float* in = blockIdx.z == 0 ? in0 : (blockIdx.z == 1 ? in1 : in2);
    __hip_bfloat16* o = out + (size_t)blockIdx.z * H_ * H_;
    __shared__ float tile[32][33];
    int bx = blockIdx.x * 32;
    int by = blockIdx.y * 32;
    int tx = threadIdx.x & 31, ty = threadIdx.x >> 5;
#pragma unroll
    for (int i = 0; i < 4; i++)
        tile[ty + 8 * i][tx] = in[(size_t)(by + ty + 8 * i) * H_ + bx + tx];
    __syncthreads();
#pragma unroll
    for (int i = 0; i < 4; i++)
        o[(size_t)(bx + ty + 8 * i) * H_ + by + tx] = __float2bfloat16(tile[tx][ty + 8 * i]);
}

__global__ void cvt_kernel(const float* __restrict__ in, __hip_bfloat16* __restrict__ out, int n) {
    int i = blockIdx.x * blockDim.x + threadIdx.x;
    int stride = gridDim.x * blockDim.x;
    for (; i < n; i += stride) out[i] = __float2bfloat16(in[i]);
}

__global__ void pack_qkv_bias_kernel(const float* __restrict__ bq, const float* __restrict__ bk,
                                     const float* __restrict__ bv, float* __restrict__ out) {
    int i = blockIdx.x * 256 + threadIdx.x;
    if (i >= 2304) return;
    out[i] = i < 768 ? bq[i] : (i < 1536 ? bk[i - 768] : bv[i - 1536]);
}

// ---------------- fused V / VR transpose ----------------
// bx<32: qkvb[MEXT][2304] rows 0..2047 cols 1536.. -> vT[b][h][64][512]
// bx>=32: qkvb rows 2048+j cols 1536..              -> vrT[h][64][256] (j>=255 -> 0)

__global__ __launch_bounds__(256) void transpose_vvr_kernel(
    const __hip_bfloat16* __restrict__ qkvb,
    __hip_bfloat16* __restrict__ vT, __hip_bfloat16* __restrict__ vrT)
{
    __shared__ unsigned short tile[64][72];
    const int bx = blockIdx.x;
    const int h  = blockIdx.y;
    const int t = threadIdx.x;
    const int r = t >> 2, c0 = (t & 3) * 16;
    if (bx < 32) {
        const int kb = bx * 64;
        const unsigned short* src = (const unsigned short*)qkvb + (size_t)(kb + r) * 2304 + 1536 + h * 64 + c0;
        *(uint4*)&tile[r][c0]     = *(const uint4*)src;
        *(uint4*)&tile[r][c0 + 8] = *(const uint4*)(src + 8);
        __syncthreads();
        unsigned short outv[16];
#pragma unroll
        for (int i = 0; i < 16; i++) outv[i] = tile[c0 + i][r];
        unsigned short* dst = (unsigned short*)vT +
            ((size_t)((kb >> 9) * NH_ + h) * 64 + r) * 512 + (kb & 511) + c0;
        *(uint4*)dst       = *(uint4*)&outv[0];
        *(uint4*)(dst + 8) = *(uint4*)&outv[8];
    } else {
        const int jb = (bx - 32) * 64;
        const int j = jb + r;
        if (j < NR_) {
            const unsigned short* src = (const unsigned short*)qkvb + (size_t)(2048 + j) * 2304 + 1536 + h * 64 + c0;
            *(uint4*)&tile[r][c0]     = *(const uint4*)src;
            *(uint4*)&tile[r][c0 + 8] = *(const uint4*)(src + 8);
        } else {
#pragma unroll
            for (int i = 0; i < 16; i++) tile[r][c0 + i] = 0;
        }
        __syncthreads();
        unsigned short outv[16];
#pragma unroll
        for (int i = 0; i < 16; i++) outv[i] = tile[c0 + i][r];
        unsigned short* dst = (unsigned short*)vrT + ((size_t)(h * 64) + r) * 256 + jb + c0;
        *(uint4*)dst       = *(uint4*)&outv[0];
        *(uint4*)(dst + 8) = *(uint4*)&outv[8];
    }
}

// ---------------- bf16 MFMA GEMM: 512 threads (8 waves), 2-phase dbuf, optional split-K ----------------
// C[M,N] = A[M,K] @ Bt[N,K]^T (+bias,+gelu). grid.z = K-splits.
// 128x128 tile; wave (wid&3)*32 rows x (wid>>2)*64 cols; 64 KB LDS -> 2 blocks/CU = 16 waves/CU.

#define TK 64

__global__ __launch_bounds__(512, 4) void gemm_bf16_kernel(
    const __hip_bfloat16* __restrict__ A, const __hip_bfloat16* __restrict__ Bt,
    const float* __restrict__ bias, float* __restrict__ Cf, __hip_bfloat16* __restrict__ Cb,
    float* __restrict__ CfX, size_t xstride,
    int M, int N, int K, int act, int ksplit)
{
    __shared__ __hip_bfloat16 As[2][128 * TK];
    __shared__ __hip_bfloat16 Bs[2][128 * TK];
    const int t = threadIdx.x;
    const int lane = t & 63;
    const int wid = t >> 6;                 // 0..7
    const int lq = lane & 15, lg = lane >> 4;
    const int wm = (wid & 3) * 32, wn = (wid >> 2) * 64;

    const int nbx = gridDim.x;
    const int nwg = nbx * gridDim.y;
    int wgid = blockIdx.y * nbx + blockIdx.x;
    if ((nwg & 7) == 0) { int qq = nwg >> 3; wgid = (wgid & 7) * qq + (wgid >> 3); }
    const int bm = (wgid / nbx) * 128, bn = (wgid % nbx) * 128;
    const int kbase = blockIdx.z * ksplit;

    f32x4 acc[2][4];
#pragma unroll
    for (int i = 0; i < 2; i++)
#pragma unroll
        for (int j = 0; j < 4; j++) acc[i][j] = (f32x4){0.f, 0.f, 0.f, 0.f};

    // staging: per c in {0,1}, thread covers row c*64 + (t>>3), 16B at pre-swizzled col
    const int rl = t >> 3;                              // 0..63
    const int cswz = (((t & 7) * 16) ^ ((rl & 7) << 4)) >> 1;   // elements
    const __hip_bfloat16* ga[2];
    const __hip_bfloat16* gb[2];
    int lofs[2];
#pragma unroll
    for (int c = 0; c < 2; c++) {
        int rowa = bm + c * 64 + rl; if (rowa >= M) rowa = M - 1;
        int rowb = bn + c * 64 + rl;
        ga[c] = A  + (size_t)rowa * K + kbase + cswz;
        gb[c] = Bt + (size_t)rowb * K + kbase + cswz;
        lofs[c] = (c * 64 + wid * 8) * TK;              // wave-uniform LDS base
    }

    const int nt = ksplit / TK;
#pragma unroll
    for (int c = 0; c < 2; c++) {
        gload16(ga[c], &As[0][lofs[c]]);
        gload16(gb[c], &Bs[0][lofs[c]]);
    }
    __syncthreads();

    int cur = 0;
    for (int kt = 0; kt < nt; kt++) {
        if (kt + 1 < nt) {
#pragma unroll
            for (int c = 0; c < 2; c++) {
                gload16(ga[c] + (kt + 1) * TK, &As[cur ^ 1][lofs[c]]);
                gload16(gb[c] + (kt + 1) * TK, &Bs[cur ^ 1][lofs[c]]);
            }
        }
#pragma unroll
        for (int kh = 0; kh < 2; kh++) {
            const int kb = kh * 64 + lg * 16;
            bf16x8 af[2], bfr[4];
#pragma unroll
            for (int i = 0; i < 2; i++) {
                int ra = wm + i * 16 + lq;
                af[i] = *(const bf16x8*)((const char*)&As[cur][0] + ra * 128 + (kb ^ ((ra & 7) << 4)));
            }
#pragma unroll
            for (int j = 0; j < 4; j++) {
                int rb = wn + j * 16 + lq;
                bfr[j] = *(const bf16x8*)((const char*)&Bs[cur][0] + rb * 128 + (kb ^ ((rb & 7) << 4)));
            }
#pragma unroll
            for (int i = 0; i < 2; i++)
#pragma unroll
                for (int j = 0; j < 4; j++)
                    acc[i][j] = __builtin_amdgcn_mfma_f32_16x16x32_bf16(af[i], bfr[j], acc[i][j], 0, 0, 0);
        }
        __syncthreads();
        cur ^= 1;
    }

    float* outf = (blockIdx.z == 0) ? Cf : (CfX + (size_t)(blockIdx.z - 1) * xstride);
#pragma unroll
    for (int i = 0; i < 2; i++) {
#pragma unroll
        for (int j = 0; j < 4; j++) {
            int col = bn + wn + j * 16 + lq;
            float bsv = bias ? bias[col] : 0.f;
            int row0 = bm + wm + i * 16 + lg * 4;
#pragma unroll
            for (int rr = 0; rr < 4; rr++) {
                int row = row0 + rr;
                if (row >= M) continue;
                float v = acc[i][j][rr] + bsv;
                if (act) v = gelu_f(v);
                if (Cb && blockIdx.z == 0) Cb[(size_t)row * N + col] = __float2bfloat16(v);
                else                       outf[(size_t)row * N + col] = v;
            }
        }
    }
}

// ---------------- MFMA rel-pos attention ----------------
// 1D grid of 768, XCD-aware decode. 256 threads (4 waves). 32 q-rows per block.
// qkvb [MEXT][2304]: rows 0..2047 = Q|K|V of tokens; rows 2048..2302 = *|KR|VR of rel emb.

#define PS_LD 520   // bf16 elems per Ps row (512 + 8 pad)
#define PR_LD 264   // bf16 elems per Rq/prel row (256 + 8 pad)

__global__ __launch_bounds__(256, 3) void attn_kernel(
    const __hip_bfloat16* __restrict__ qkvb,  // [MEXT][2304]
    const __hip_bfloat16* __restrict__ vT,    // [B][NH][64][512]
    const __hip_bfloat16* __restrict__ vrT,   // [NH][64][256] (col 255 zero)
    const int* __restrict__ mask,
    __hip_bfloat16* __restrict__ ctxb)        // [2048][768]
{
    __shared__ unsigned short RqPrel[32 * PR_LD];
    __shared__ unsigned short Ps[32 * PS_LD];
    __shared__ float mstat[32 * 4];
    __shared__ float sstat[32 * 4];
    __shared__ float maskb[512];

    const int i_ = blockIdx.x;
    const int c_ = i_ & 7, s_ = i_ >> 3;
    const int p_ = c_ + 8 * (s_ >> 4);
    const int qt = s_ & 15;
    const int b = p_ / 12, h = p_ % 12;

    const int t = threadIdx.x;
    const int lane = t & 63, w = t >> 6;
    const int lq = lane & 15, lg = lane >> 4;

    maskb[t]       = mask[b * L_ + t]       ? 0.f : -1e30f;
    maskb[t + 256] = mask[b * L_ + t + 256] ? 0.f : -1e30f;

    const char* Qbase  = (const char*)qkvb + ((size_t)(b * L_ + qt * 32) * 2304 + h * 64) * 2;
    const char* Kbase  = (const char*)qkvb + ((size_t)(b * L_) * 2304 + 768 + h * 64) * 2;
    const char* KRbase = (const char*)qkvb + ((size_t)2048 * 2304 + 768 + h * 64) * 2;

    // hoist Q fragments once (reused by R and S phases)
    bf16x8 afq[2][2];
#pragma unroll
    for (int ks = 0; ks < 2; ks++) {
        const int kofs = ks * 64 + lg * 16;
        afq[ks][0] = *(const bf16x8*)(Qbase + (size_t)lq * 4608 + kofs);
        afq[ks][1] = *(const bf16x8*)(Qbase + (size_t)(16 + lq) * 4608 + kofs);
    }

    // ---- R phase: Rq[32][256] = Q @ KR^T ----
    {
        f32x4 accr[2][4];
#pragma unroll
        for (int i = 0; i < 2; i++)
#pragma unroll
            for (int j = 0; j < 4; j++) accr[i][j] = (f32x4){0.f, 0.f, 0.f, 0.f};
#pragma unroll
        for (int ks = 0; ks < 2; ks++) {
            const int kofs = ks * 64 + lg * 16;
            bf16x8 bkr_[4];
#pragma unroll
            for (int jt = 0; jt < 4; jt++) {
                int j = w * 64 + jt * 16 + lq;
                int jr = j > 254 ? 254 : j;
                bkr_[jt] = *(const bf16x8*)(KRbase + (size_t)jr * 4608 + kofs);
            }
#pragma unroll
            for (int jt = 0; jt < 4; jt++) {
                accr[0][jt] = __builtin_amdgcn_mfma_f32_16x16x32_bf16(afq[ks][0], bkr_[jt], accr[0][jt], 0, 0, 0);
                accr[1][jt] = __builtin_amdgcn_mfma_f32_16x16x32_bf16(afq[ks][1], bkr_[jt], accr[1][jt], 0, 0, 0);
            }
        }
#pragma unroll
        for (int it = 0; it < 2; it++)
#pragma unroll
            for (int jt = 0; jt < 4; jt++)
#pragma unroll
                for (int r = 0; r < 4; r++)
                    RqPrel[(it * 16 + lg * 4 + r) * PR_LD + w * 64 + jt * 16 + lq] = f2bfu(accr[it][jt][r]);
    }
    __syncthreads();

    // ---- S phase: Q @ K^T (wave w owns key strip w*128..+128), batched loads ----
    f32x4 accs[2][8];
#pragma unroll
    for (int i = 0; i < 2; i++)
#pragma unroll
        for (int j = 0; j < 8; j++) accs[i][j] = (f32x4){0.f, 0.f, 0.f, 0.f};
#pragma unroll
    for (int ks = 0; ks < 2; ks++) {
        const int kofs = ks * 64 + lg * 16;
        bf16x8 bk_[8];
#pragma unroll
        for (int jt = 0; jt < 8; jt++) {
            int key = w * 128 + jt * 16 + lq;
            bk_[jt] = *(const bf16x8*)(Kbase + (size_t)key * 4608 + kofs);
        }
#pragma unroll
        for (int jt = 0; jt < 8; jt++) {
            accs[0][jt] = __builtin_amdgcn_mfma_f32_16x16x32_bf16(afq[ks][0], bk_[jt], accs[0][jt], 0, 0, 0);
            accs[1][jt] = __builtin_amdgcn_mfma_f32_16x16x32_bf16(afq[ks][1], bk_[jt], accs[1][jt], 0, 0, 0);
        }
    }

    // ---- S epilogue: add rel score + mask ----
#pragma unroll
    for (int it = 0; it < 2; it++) {
#pragma unroll
        for (int r = 0; r < 4; r++) {
            int q = it * 16 + lg * 4 + r;
            int qg = qt * 32 + q;
            float mx = -INFINITY;
#pragma unroll
            for (int jt = 0; jt < 8; jt++) {
                int k = w * 128 + jt * 16 + lq;
                int jc = k - qg + 127;
                jc = jc < 0 ? 0 : (jc > 254 ? 254 : jc);
                float s = (accs[it][jt][r] + bfu2f(RqPrel[q * PR_LD + jc])) * COEF_ + maskb[k];
                accs[it][jt][r] = s;
                mx = fmaxf(mx, s);
            }
#pragma unroll
            for (int off = 1; off < 16; off <<= 1) mx = fmaxf(mx, __shfl_xor(mx, off, 64));
            if (lq == 0) mstat[q * 4 + w] = mx;
        }
    }
    __syncthreads();

    // ---- exp + row sums + write P ----
#pragma unroll
    for (int it = 0; it < 2; it++) {
#pragma unroll
        for (int r = 0; r < 4; r++) {
            int q = it * 16 + lg * 4 + r;
            float4 mv = *(const float4*)&mstat[q * 4];
            float gm = fmaxf(fmaxf(mv.x, mv.y), fmaxf(mv.z, mv.w));
            float ssum = 0.f;
#pragma unroll
            for (int jt = 0; jt < 8; jt++) {
                int k = w * 128 + jt * 16 + lq;
                float p = __expf(accs[it][jt][r] - gm);
                ssum += p;
                Ps[q * PS_LD + k] = f2bfu(p);
            }
#pragma unroll
            for (int off = 1; off < 16; off <<= 1) ssum += __shfl_xor(ssum, off, 64);
            if (lq == 0) sstat[q * 4 + w] = ssum;
        }
    }
    __syncthreads();

    // ---- prel construction + PV operand prefetch ----
    const __hip_bfloat16* vTb  = vT  + (((size_t)(b * NH_ + h) * 64) + w * 16 + lq) * 512 + lg * 8;
    const __hip_bfloat16* vrTb = vrT + ((size_t)(h * 64) + w * 16 + lq) * 256 + lg * 8;
    bf16x8 bvpre[8], vrpre[8];
#pragma unroll
    for (int ks = 0; ks < 8; ks++) {
        bvpre[ks] = *(const bf16x8*)(vTb + ks * 32);
        vrpre[ks] = *(const bf16x8*)(vrTb + ks * 32);
    }
    {
        int q = t >> 3, sub = t & 7;
        int qg = qt * 32 + q;
#pragma unroll
        for (int jj = 0; jj < 32; jj++) {
            int j = sub + 8 * jj;
            if (j == 0 || j == 254) continue;
            if (j == 255) { RqPrel[q * PR_LD + 255] = 0; continue; }
            int k = qg + j - 127;
            unsigned short val = ((unsigned)k < 512u) ? Ps[q * PS_LD + k] : (unsigned short)0;
            RqPrel[q * PR_LD + j] = val;
        }
    }
    {
        int task = t >> 2, ts = t & 3;
        int q = task >> 1, side = task & 1;
        int qg = qt * 32 + q;
        float sum = 0.f;
        if (side == 0) {
            int hi = qg - 127;
            for (int k = ts; k <= hi; k += 4) sum += bfu2f(Ps[q * PS_LD + k]);
        } else {
            for (int k = qg + 127 + ts; k < 512; k += 4) sum += bfu2f(Ps[q * PS_LD + k]);
        }
        sum += __shfl_xor(sum, 1, 64);
        sum += __shfl_xor(sum, 2, 64);
        if (ts == 0) RqPrel[q * PR_LD + (side == 0 ? 0 : 254)] = f2bfu(sum);
    }
    __syncthreads();

    // ---- PV phase: out strip d in [w*16, w*16+16) ----
    f32x4 accv[2];
    accv[0] = (f32x4){0.f, 0.f, 0.f, 0.f};
    accv[1] = (f32x4){0.f, 0.f, 0.f, 0.f};

#pragma unroll
    for (int ks = 0; ks < 8; ks++) {
        bf16x8 pa0 = *(const bf16x8*)((const char*)Ps + (size_t)lq * (PS_LD * 2) + ks * 64 + lg * 16);
        bf16x8 pa1 = *(const bf16x8*)((const char*)Ps + (size_t)(16 + lq) * (PS_LD * 2) + ks * 64 + lg * 16);
        accv[0] = __builtin_amdgcn_mfma_f32_16x16x32_bf16(pa0, bvpre[ks], accv[0], 0, 0, 0);
        accv[1] = __builtin_amdgcn_mfma_f32_16x16x32_bf16(pa1, bvpre[ks], accv[1], 0, 0, 0);
    }
#pragma unroll
    for (int ks = 8; ks < 16; ks++) {
        bf16x8 bv = *(const bf16x8*)(vTb + ks * 32);
        bf16x8 pa0 = *(const bf16x8*)((const char*)Ps + (size_t)lq * (PS_LD * 2) + ks * 64 + lg * 16);
        bf16x8 pa1 = *(const bf16x8*)((const char*)Ps + (size_t)(16 + lq) * (PS_LD * 2) + ks * 64 + lg * 16);
        accv[0] = __builtin_amdgcn_mfma_f32_16x16x32_bf16(pa0, bv, accv[0], 0, 0, 0);
        accv[1] = __builtin_amdgcn_mfma_f32_16x16x32_bf16(pa1, bv, accv[1], 0, 0, 0);
    }
#pragma unroll
    for (int ks = 0; ks < 8; ks++) {
        bf16x8 pa0 = *(const bf16x8*)((const char*)RqPrel + (size_t)lq * (PR_LD * 2) + ks * 64 + lg * 16);
        bf16x8 pa1 = *(const bf16x8*)((const char*)RqPrel + (size_t)(16 + lq) * (PR_LD * 2) + ks * 64 + lg * 16);
        accv[0] = __builtin_amdgcn_mfma_f32_16x16x32_bf16(pa0, vrpre[ks], accv[0], 0, 0, 0);
        accv[1] = __builtin_amdgcn_mfma_f32_16x16x32_bf16(pa1, vrpre[ks], accv[1], 0, 0, 0);
    }

#pragma unroll
    for (int it = 0; it < 2; it++) {
#pragma unroll
        for (int r = 0; r < 4; r++) {
            int q = it * 16 + lg * 4 + r;
            float4 sv = *(const float4*)&sstat[q * 4];
            float inv = 1.f / (sv.x + sv.y + sv.z + sv.w);
            ctxb[(size_t)(b * L_ + qt * 32 + q) * 768 + h * 64 + w * 16 + lq] =
                __float2bfloat16(accv[it][r] * inv);
        }
    }
}

// ---------------- host ----------------

extern "C" void kernel_launch(void* const* d_in, const int* in_sizes, int n_in,
                              void* d_out, int out_size, void* d_ws, size_t ws_size,
                              hipStream_t stream)
{
    const int*   tok    = (const int*)d_in[0];
    const int*   seg    = (const int*)d_in[1];
    const int*   maskp  = (const int*)d_in[2];
    const float* temb   = (const float*)d_in[3];
    const float* semb   = (const float*)d_in[4];
    const float* esc    = (const float*)d_in[5];
    const float* ebi    = (const float*)d_in[6];
    const float* Wq     = (const float*)d_in[7];
    const float* bq     = (const float*)d_in[8];
    const float* Wk     = (const float*)d_in[9];
    const float* bk     = (const float*)d_in[10];
    const float* Wv     = (const float*)d_in[11];
    const float* bv     = (const float*)d_in[12];
    const float* relpos = (const float*)d_in[13];
    const float* Wo     = (const float*)d_in[14];
    const float* bo     = (const float*)d_in[15];
    const float* ln1s   = (const float*)d_in[16];
    const float* ln1b   = (const float*)d_in[17];
    const float* W1     = (const float*)d_in[18];
    const float* b1     = (const float*)d_in[19];
    const float* W2     = (const float*)d_in[20];
    const float* b2     = (const float*)d_in[21];
    const float* ln2s   = (const float*)d_in[22];
    const float* ln2b   = (const float*)d_in[23];

    const size_t NX = (size_t)ROWS * H_;
    float* x       = (float*)d_ws;
    float* x2      = x + NX;
    float* y       = x2 + NX;
    float* qkvbias = y + NX;                                   // 2304 f32
    __hip_bfloat16* xb    = (__hip_bfloat16*)(qkvbias + 2304); // [MEXT][768] (rows 2048.. = rel emb)
    __hip_bfloat16* x2b   = xb    + (size_t)MEXT * H_;
    __hip_bfloat16* ctxb  = x2b   + NX;
    __hip_bfloat16* qkvb  = ctxb  + NX;                        // [MEXT][2304]
    __hip_bfloat16* vT    = qkvb  + (size_t)MEXT * 2304;       // 4*12*64*512
    __hip_bfloat16* vrT   = vT    + (size_t)B_ * NH_ * 64 * 512; // 12*64*256
    __hip_bfloat16* Wt    = vrT   + (size_t)NH_ * 64 * 256;    // 3072*768
    __hip_bfloat16* h1b   = Wt    + (size_t)M_ * H_;           // 2048*3072

    float* spill = (float*)qkvb;   // split-K partials alias qkvb/vT (dead after attn); 13.7MB >= 2*NX f32

    dim3 blk(256);
    dim3 blk512(512);

    embed_ln_kernel<<<ROWS, blk, 0, stream>>>(tok, seg, temb, semb, esc, ebi, x, xb);

    for (int l = 0; l < NL_; l++) {
        const float* wq = Wq + (size_t)l * H_ * H_;
        const float* wk = Wk + (size_t)l * H_ * H_;
        const float* wv = Wv + (size_t)l * H_ * H_;
        const float* wo = Wo + (size_t)l * H_ * H_;
        const float* w1 = W1 + (size_t)l * H_ * M_;
        const float* w2 = W2 + (size_t)l * M_ * H_;

        transpose_cvt3_kernel<<<dim3(24, 24, 3), blk, 0, stream>>>(wq, wk, wv, Wt);
        pack_qkv_bias_kernel<<<9, blk, 0, stream>>>(bq + (size_t)l * H_, bk + (size_t)l * H_, bv + (size_t)l * H_, qkvbias);
        // rel embedding slice -> A rows 2048..2302 (bf16)
        cvt_kernel<<<192, blk, 0, stream>>>(relpos + (size_t)l * NR_ * H_, xb + (size_t)ROWS * H_, NR_ * H_);

        // merged QKV + rel projection: [MEXT][768] @ [2304][768]^T -> qkvb [MEXT][2304]
        gemm_bf16_kernel<<<dim3(18, 18), blk512, 0, stream>>>(xb, Wt, qkvbias, nullptr, qkvb, nullptr, 0,
                                                              MEXT, 2304, H_, 0, H_);
        transpose_vvr_kernel<<<dim3(36, 12), blk, 0, stream>>>(qkvb, vT, vrT);

        attn_kernel<<<dim3(768), blk, 0, stream>>>(qkvb, vT, vrT, maskp, ctxb);

        // O projection: split-K x2 (768 -> 2x384); bias added in add_ln
        transpose_cvt_kernel<<<dim3(24, 24), blk, 0, stream>>>(wo, Wt, H_, H_);
        gemm_bf16_kernel<<<dim3(6, 16, 2), blk512, 0, stream>>>(ctxb, Wt, nullptr, y, nullptr, spill, NX,
                                                                ROWS, H_, H_, 0, 384);
        add_ln_kernel<<<ROWS, blk, 0, stream>>>(x, y, spill, nullptr, bo + (size_t)l * H_,
                                                ln1s + (size_t)l * H_, ln1b + (size_t)l * H_, x2, x2b);

        // MLP
        transpose_cvt_kernel<<<dim3(96, 24), blk, 0, stream>>>(w1, Wt, H_, M_);
        gemm_bf16_kernel<<<dim3(24, 16), blk512, 0, stream>>>(x2b, Wt, b1 + (size_t)l * M_, nullptr, h1b, nullptr, 0,
                                                              ROWS, M_, H_, 1, H_);
        transpose_cvt_kernel<<<dim3(24, 96), blk, 0, stream>>>(w2, Wt, M_, H_);
        gemm_bf16_kernel<<<dim3(6, 16, 3), blk512, 0, stream>>>(h1b, Wt, nullptr, y, nullptr, spill, NX,
                                                                ROWS, H_, M_, 0, 1024);

        float* outp = (l == NL_ - 1) ? (float*)d_out : x;
        __hip_bfloat16* outbp = (l == NL_ - 1) ? nullptr : xb;
        add_ln_kernel<<<ROWS, blk, 0, stream>>>(x2, y, spill, spill + NX, b2 + (size_t)l * H_,
                                                ln2s + (size_t)l * H_, ln2b + (size_t)l * H_, outp, outbp);
    }
}

// Round 8
// 730.600 us; speedup vs baseline: 20.5279x; 1.2311x over previous
//
#include <hip/hip_runtime.h>
#include <hip/hip_bf16.h>
#include <math.h>

#define B_   4
#define L_   512
#define H_   768
#define NH_  12
#define HD_  64
#define M_   3072
#define NL_  6
#define RD_  128
#define NR_  255          // 2*RD-1
#define ROWS (B_*L_)      // 2048
#define MEXT 2304         // ROWS + NR_ + 1 pad (merged QKV+rel A rows)
#define COEF_ 0.125f      // 1/sqrt(64)

typedef __attribute__((ext_vector_type(8))) short bf16x8;
typedef __attribute__((ext_vector_type(4))) float f32x4;

// ---------------- utility ----------------

static __device__ __forceinline__ float wave_reduce_sum(float v) {
#pragma unroll
    for (int off = 32; off > 0; off >>= 1) v += __shfl_xor(v, off, 64);
    return v;
}

static __device__ __forceinline__ float gelu_f(float x) {
    float x3 = x * x * x;
    return 0.5f * x * (1.f + tanhf(0.7978845608028654f * (x + 0.044715f * x3)));
}

static __device__ __forceinline__ unsigned short f2bfu(float v) {
    __hip_bfloat16 h = __float2bfloat16(v);
    return *(unsigned short*)&h;
}

static __device__ __forceinline__ float bfu2f(unsigned short u) {
    union { float f; unsigned int i; } x;
    x.i = ((unsigned int)u) << 16;
    return x.f;
}

// async global->LDS, 16B per lane; LDS dest = wave-uniform base + lane*16
static __device__ __forceinline__ void gload16(const void* g, void* l) {
    __builtin_amdgcn_global_load_lds(
        (const __attribute__((address_space(1))) void*)g,
        (__attribute__((address_space(3))) void*)l,
        16, 0, 0);
}

// ---------------- embedding + LN (fp32 out + bf16 twin) ----------------

__global__ __launch_bounds__(256) void embed_ln_kernel(
    const int* __restrict__ tok, const int* __restrict__ seg,
    const float* __restrict__ temb, const float* __restrict__ semb,
    const float* __restrict__ sc, const float* __restrict__ bi,
    float* __restrict__ out, __hip_bfloat16* __restrict__ outb)
{
    int row = blockIdx.x;
    int t = threadIdx.x;
    int tid = tok[row], sid = seg[row];
    const float* tp = temb + (size_t)tid * H_;
    const float* sp = semb + (size_t)sid * H_;
    float v[3];
#pragma unroll
    for (int j = 0; j < 3; j++) { int idx = t + j * 256; v[j] = tp[idx] + sp[idx]; }

    __shared__ float red[4];
    __shared__ float bc;
    int lane = t & 63, wid = t >> 6;

    float s = v[0] + v[1] + v[2];
    s = wave_reduce_sum(s);
    if (lane == 0) red[wid] = s;
    __syncthreads();
    if (t == 0) bc = (red[0] + red[1] + red[2] + red[3]) * (1.f / H_);
    __syncthreads();
    float mean = bc;

    float c[3]; float ss = 0.f;
#pragma unroll
    for (int j = 0; j < 3; j++) { c[j] = v[j] - mean; ss += c[j] * c[j]; }
    ss = wave_reduce_sum(ss);
    __syncthreads();
    if (lane == 0) red[wid] = ss;
    __syncthreads();
    if (t == 0) bc = rsqrtf((red[0] + red[1] + red[2] + red[3]) * (1.f / H_) + 1e-12f);
    __syncthreads();
    float r = bc;
#pragma unroll
    for (int j = 0; j < 3; j++) {
        int idx = t + j * 256;
        float o = c[j] * r * sc[idx] + bi[idx];
        out[(size_t)row * H_ + idx] = o;
        outb[(size_t)row * H_ + idx] = __float2bfloat16(o);
    }
}

// ---------------- residual add (+partials +bias) + LN (fp32 out + optional bf16 twin) ----------------

__global__ __launch_bounds__(256) void add_ln_kernel(
    const float* __restrict__ x, const float* __restrict__ p0,
    const float* __restrict__ p1, const float* __restrict__ p2,
    const float* __restrict__ bias,
    const float* __restrict__ sc, const float* __restrict__ bi,
    float* __restrict__ out, __hip_bfloat16* __restrict__ outb)
{
    int row = blockIdx.x;
    int t = threadIdx.x;
    const float* xp = x + (size_t)row * H_;
    const float* q0 = p0 + (size_t)row * H_;
    const float* q1 = p1 ? p1 + (size_t)row * H_ : nullptr;
    const float* q2 = p2 ? p2 + (size_t)row * H_ : nullptr;
    float v[3];
#pragma unroll
    for (int j = 0; j < 3; j++) {
        int idx = t + j * 256;
        float a = xp[idx] + q0[idx];
        if (q1) a += q1[idx];
        if (q2) a += q2[idx];
        if (bias) a += bias[idx];
        v[j] = a;
    }

    __shared__ float red[4];
    __shared__ float bc;
    int lane = t & 63, wid = t >> 6;

    float s = v[0] + v[1] + v[2];
    s = wave_reduce_sum(s);
    if (lane == 0) red[wid] = s;
    __syncthreads();
    if (t == 0) bc = (red[0] + red[1] + red[2] + red[3]) * (1.f / H_);
    __syncthreads();
    float mean = bc;

    float c[3]; float ss = 0.f;
#pragma unroll
    for (int j = 0; j < 3; j++) { c[j] = v[j] - mean; ss += c[j] * c[j]; }
    ss = wave_reduce_sum(ss);
    __syncthreads();
    if (lane == 0) red[wid] = ss;
    __syncthreads();
    if (t == 0) bc = rsqrtf((red[0] + red[1] + red[2] + red[3]) * (1.f / H_) + 1e-12f);
    __syncthreads();
    float r = bc;
#pragma unroll
    for (int j = 0; j < 3; j++) {
        int idx = t + j * 256;
        float o = c[j] * r * sc[idx] + bi[idx];
        out[(size_t)row * H_ + idx] = o;
        if (outb) outb[(size_t)row * H_ + idx] = __float2bfloat16(o);
    }
}

// ---------------- consolidated per-layer weight/bias/rel pack ----------------
// grid (96, 24, 7), 256 threads.
// z=0..2: wq/wk/wv [768][768] -> WtQ+z*H*H (transposed bf16); blocks with bx>=24 idle.
// z=3:    wo -> WtO. z=4: w1 [768][3072] -> WtW1. z=5: w2 [3072][768] -> WtW2 (bx/by swapped).
// z=6:    id<765: rel cvt (255*768 f32->bf16); id 765..773: qkv bias pack.

__global__ __launch_bounds__(256) void pack_layer_kernel(
    const float* __restrict__ wq, const float* __restrict__ wk, const float* __restrict__ wv,
    const float* __restrict__ wo, const float* __restrict__ w1, const float* __restrict__ w2,
    const float* __restrict__ bqL, const float* __restrict__ bkL, const float* __restrict__ bvL,
    const float* __restrict__ relL,
    __hip_bfloat16* __restrict__ WtQ, __hip_bfloat16* __restrict__ WtO,
    __hip_bfloat16* __restrict__ WtW1, __hip_bfloat16* __restrict__ WtW2,
    float* __restrict__ qkvbias, __hip_bfloat16* __restrict__ relb)
{
    const int z = blockIdx.z;
    const int t = threadIdx.x;
    if (z == 6) {
        int id = blockIdx.y * 96 + blockIdx.x;
        if (id < 765) {
            int i = id * 256 + t;              // 765*256 = 195840 = 255*768 exactly
            relb[i] = __float2bfloat16(relL[i]);
        } else if (id < 774) {
            int i = (id - 765) * 256 + t;
            if (i < 2304)
                qkvbias[i] = i < 768 ? bqL[i] : (i < 1536 ? bkL[i - 768] : bvL[i - 1536]);
        }
        return;
    }
    const float* in; __hip_bfloat16* out; int K, N;
    int bx = blockIdx.x, by = blockIdx.y;
    if (z < 4) {
        if (bx >= 24) return;
        K = 768; N = 768;
        in = (z == 0) ? wq : (z == 1) ? wk : (z == 2) ? wv : wo;
        out = (z < 3) ? WtQ + (size_t)z * H_ * H_ : WtO;
    } else if (z == 4) {
        K = 768; N = 3072; in = w1; out = WtW1;
    } else {
        K = 3072; N = 768; in = w2; out = WtW2;
        int tmp = bx; bx = by; by = tmp;       // bx<24 (N), by<96 (K)
    }
    __shared__ float tile[32][33];
    int bX = bx * 32, bY = by * 32;
    int tx = t & 31, ty = t >> 5;
#pragma unroll
    for (int i = 0; i < 4; i++)
        tile[ty + 8 * i][tx] = in[(size_t)(bY + ty + 8 * i) * N + bX + tx];
    __syncthreads();
#pragma unroll
    for (int i = 0; i < 4; i++)
        out[(size_t)(bX + ty + 8 * i) * K + bY + tx] = __float2bfloat16(tile[tx][ty + 8 * i]);
}

// ---------------- fused V / VR transpose ----------------
// bx<32: qkvb[MEXT][2304] rows 0..2047 cols 1536.. -> vT[b][h][64][512]
// bx>=32: qkvb rows 2048+j cols 1536..              -> vrT[h][64][256] (j>=255 -> 0)

__global__ __launch_bounds__(256) void transpose_vvr_kernel(
    const __hip_bfloat16* __restrict__ qkvb,
    __hip_bfloat16* __restrict__ vT, __hip_bfloat16* __restrict__ vrT)
{
    __shared__ unsigned short tile[64][72];
    const int bx = blockIdx.x;
    const int h  = blockIdx.y;
    const int t = threadIdx.x;
    const int r = t >> 2, c0 = (t & 3) * 16;
    if (bx < 32) {
        const int kb = bx * 64;
        const unsigned short* src = (const unsigned short*)qkvb + (size_t)(kb + r) * 2304 + 1536 + h * 64 + c0;
        *(uint4*)&tile[r][c0]     = *(const uint4*)src;
        *(uint4*)&tile[r][c0 + 8] = *(const uint4*)(src + 8);
        __syncthreads();
        unsigned short outv[16];
#pragma unroll
        for (int i = 0; i < 16; i++) outv[i] = tile[c0 + i][r];
        unsigned short* dst = (unsigned short*)vT +
            ((size_t)((kb >> 9) * NH_ + h) * 64 + r) * 512 + (kb & 511) + c0;
        *(uint4*)dst       = *(uint4*)&outv[0];
        *(uint4*)(dst + 8) = *(uint4*)&outv[8];
    } else {
        const int jb = (bx - 32) * 64;
        const int j = jb + r;
        if (j < NR_) {
            const unsigned short* src = (const unsigned short*)qkvb + (size_t)(2048 + j) * 2304 + 1536 + h * 64 + c0;
            *(uint4*)&tile[r][c0]     = *(const uint4*)src;
            *(uint4*)&tile[r][c0 + 8] = *(const uint4*)(src + 8);
        } else {
#pragma unroll
            for (int i = 0; i < 16; i++) tile[r][c0 + i] = 0;
        }
        __syncthreads();
        unsigned short outv[16];
#pragma unroll
        for (int i = 0; i < 16; i++) outv[i] = tile[c0 + i][r];
        unsigned short* dst = (unsigned short*)vrT + ((size_t)(h * 64) + r) * 256 + jb + c0;
        *(uint4*)dst       = *(uint4*)&outv[0];
        *(uint4*)(dst + 8) = *(uint4*)&outv[8];
    }
}

// ---------------- bf16 MFMA GEMM: 128x64 tile, 8 waves, 3 blocks/CU (24 waves/CU) ----------------
// C[M,N] = A[M,K] @ Bt[N,K]^T (+bias,+gelu). grid.z = K-splits.
// Wave (wid&3)*32 rows x (wid>>2)*32 cols. 48 KB LDS double-buffered.
// global_load_lds width-16, linear LDS dest + pre-swizzled global src, XOR ds_read.

#define TK 64

__global__ __launch_bounds__(512, 6) void gemm_bf16_kernel(
    const __hip_bfloat16* __restrict__ A, const __hip_bfloat16* __restrict__ Bt,
    const float* __restrict__ bias, float* __restrict__ Cf, __hip_bfloat16* __restrict__ Cb,
    float* __restrict__ CfX, size_t xstride,
    int M, int N, int K, int act, int ksplit)
{
    __shared__ __hip_bfloat16 As[2][128 * TK];
    __shared__ __hip_bfloat16 Bs[2][64 * TK];
    const int t = threadIdx.x;
    const int lane = t & 63;
    const int wid = t >> 6;                 // 0..7
    const int lq = lane & 15, lg = lane >> 4;
    const int wm = (wid & 3) * 32, wn = (wid >> 2) * 32;

    const int nbx = gridDim.x;
    const int nwg = nbx * gridDim.y;
    int wgid = blockIdx.y * nbx + blockIdx.x;
    if ((nwg & 7) == 0) { int qq = nwg >> 3; wgid = (wgid & 7) * qq + (wgid >> 3); }
    const int bm = (wgid / nbx) * 128, bn = (wgid % nbx) * 64;
    const int kbase = blockIdx.z * ksplit;

    f32x4 acc[2][2];
#pragma unroll
    for (int i = 0; i < 2; i++)
#pragma unroll
        for (int j = 0; j < 2; j++) acc[i][j] = (f32x4){0.f, 0.f, 0.f, 0.f};

    // staging: A rows c*64 + (t>>3) (c=0,1), B rows (t>>3); 16B at pre-swizzled col
    const int rl = t >> 3;                              // 0..63
    const int cswz = (((t & 7) * 16) ^ ((rl & 7) << 4)) >> 1;   // elements
    const __hip_bfloat16* ga[2];
    const __hip_bfloat16* gb;
    int lofsA[2], lofsB;
#pragma unroll
    for (int c = 0; c < 2; c++) {
        int rowa = bm + c * 64 + rl; if (rowa >= M) rowa = M - 1;
        ga[c] = A + (size_t)rowa * K + kbase + cswz;
        lofsA[c] = (c * 64 + wid * 8) * TK;             // wave-uniform LDS base
    }
    gb = Bt + (size_t)(bn + rl) * K + kbase + cswz;
    lofsB = (wid * 8) * TK;

    const int nt = ksplit / TK;
    gload16(ga[0], &As[0][lofsA[0]]);
    gload16(ga[1], &As[0][lofsA[1]]);
    gload16(gb,    &Bs[0][lofsB]);
    __syncthreads();

    int cur = 0;
    for (int kt = 0; kt < nt; kt++) {
        if (kt + 1 < nt) {
            const int koff = (kt + 1) * TK;
            gload16(ga[0] + koff, &As[cur ^ 1][lofsA[0]]);
            gload16(ga[1] + koff, &As[cur ^ 1][lofsA[1]]);
            gload16(gb + koff,    &Bs[cur ^ 1][lofsB]);
        }
#pragma unroll
        for (int kh = 0; kh < 2; kh++) {
            const int kb = kh * 64 + lg * 16;
            bf16x8 af[2], bfr[2];
#pragma unroll
            for (int i = 0; i < 2; i++) {
                int ra = wm + i * 16 + lq;
                af[i] = *(const bf16x8*)((const char*)&As[cur][0] + ra * 128 + (kb ^ ((ra & 7) << 4)));
            }
#pragma unroll
            for (int j = 0; j < 2; j++) {
                int rb = wn + j * 16 + lq;
                bfr[j] = *(const bf16x8*)((const char*)&Bs[cur][0] + rb * 128 + (kb ^ ((rb & 7) << 4)));
            }
#pragma unroll
            for (int i = 0; i < 2; i++)
#pragma unroll
                for (int j = 0; j < 2; j++)
                    acc[i][j] = __builtin_amdgcn_mfma_f32_16x16x32_bf16(af[i], bfr[j], acc[i][j], 0, 0, 0);
        }
        __syncthreads();
        cur ^= 1;
    }

    float* outf = (blockIdx.z == 0) ? Cf : (CfX + (size_t)(blockIdx.z - 1) * xstride);
#pragma unroll
    for (int i = 0; i < 2; i++) {
#pragma unroll
        for (int j = 0; j < 2; j++) {
            int col = bn + wn + j * 16 + lq;
            float bsv = bias ? bias[col] : 0.f;
            int row0 = bm + wm + i * 16 + lg * 4;
#pragma unroll
            for (int rr = 0; rr < 4; rr++) {
                int row = row0 + rr;
                if (row >= M) continue;
                float v = acc[i][j][rr] + bsv;
                if (act) v = gelu_f(v);
                if (Cb && blockIdx.z == 0) Cb[(size_t)row * N + col] = __float2bfloat16(v);
                else                       outf[(size_t)row * N + col] = v;
            }
        }
    }
}

// ---------------- MFMA rel-pos attention ----------------
// 1D grid of 768, XCD-aware decode. 256 threads (4 waves). 32 q-rows per block.
// qkvb [MEXT][2304]: rows 0..2047 = Q|K|V of tokens; rows 2048..2302 = *|KR|VR of rel emb.

#define PS_LD 520   // bf16 elems per Ps row (512 + 8 pad)
#define PR_LD 264   // bf16 elems per Rq/prel row (256 + 8 pad)

__global__ __launch_bounds__(256, 3) void attn_kernel(
    const __hip_bfloat16* __restrict__ qkvb,  // [MEXT][2304]
    const __hip_bfloat16* __restrict__ vT,    // [B][NH][64][512]
    const __hip_bfloat16* __restrict__ vrT,   // [NH][64][256] (col 255 zero)
    const int* __restrict__ mask,
    __hip_bfloat16* __restrict__ ctxb)        // [2048][768]
{
    __shared__ unsigned short RqPrel[32 * PR_LD];
    __shared__ unsigned short Ps[32 * PS_LD];
    __shared__ float mstat[32 * 4];
    __shared__ float sstat[32 * 4];
    __shared__ float maskb[512];

    const int i_ = blockIdx.x;
    const int c_ = i_ & 7, s_ = i_ >> 3;
    const int p_ = c_ + 8 * (s_ >> 4);
    const int qt = s_ & 15;
    const int b = p_ / 12, h = p_ % 12;

    const int t = threadIdx.x;
    const int lane = t & 63, w = t >> 6;
    const int lq = lane & 15, lg = lane >> 4;

    maskb[t]       = mask[b * L_ + t]       ? 0.f : -1e30f;
    maskb[t + 256] = mask[b * L_ + t + 256] ? 0.f : -1e30f;

    const char* Qbase  = (const char*)qkvb + ((size_t)(b * L_ + qt * 32) * 2304 + h * 64) * 2;
    const char* Kbase  = (const char*)qkvb + ((size_t)(b * L_) * 2304 + 768 + h * 64) * 2;
    const char* KRbase = (const char*)qkvb + ((size_t)2048 * 2304 + 768 + h * 64) * 2;

    // hoist Q fragments once (reused by R and S phases)
    bf16x8 afq[2][2];
#pragma unroll
    for (int ks = 0; ks < 2; ks++) {
        const int kofs = ks * 64 + lg * 16;
        afq[ks][0] = *(const bf16x8*)(Qbase + (size_t)lq * 4608 + kofs);
        afq[ks][1] = *(const bf16x8*)(Qbase + (size_t)(16 + lq) * 4608 + kofs);
    }

    // ---- R phase: Rq[32][256] = Q @ KR^T ----
    {
        f32x4 accr[2][4];
#pragma unroll
        for (int i = 0; i < 2; i++)
#pragma unroll
            for (int j = 0; j < 4; j++) accr[i][j] = (f32x4){0.f, 0.f, 0.f, 0.f};
#pragma unroll
        for (int ks = 0; ks < 2; ks++) {
            const int kofs = ks * 64 + lg * 16;
            bf16x8 bkr_[4];
#pragma unroll
            for (int jt = 0; jt < 4; jt++) {
                int j = w * 64 + jt * 16 + lq;
                int jr = j > 254 ? 254 : j;
                bkr_[jt] = *(const bf16x8*)(KRbase + (size_t)jr * 4608 + kofs);
            }
#pragma unroll
            for (int jt = 0; jt < 4; jt++) {
                accr[0][jt] = __builtin_amdgcn_mfma_f32_16x16x32_bf16(afq[ks][0], bkr_[jt], accr[0][jt], 0, 0, 0);
                accr[1][jt] = __builtin_amdgcn_mfma_f32_16x16x32_bf16(afq[ks][1], bkr_[jt], accr[1][jt], 0, 0, 0);
            }
        }
#pragma unroll
        for (int it = 0; it < 2; it++)
#pragma unroll
            for (int jt = 0; jt < 4; jt++)
#pragma unroll
                for (int r = 0; r < 4; r++)
                    RqPrel[(it * 16 + lg * 4 + r) * PR_LD + w * 64 + jt * 16 + lq] = f2bfu(accr[it][jt][r]);
    }
    __syncthreads();

    // ---- S phase: Q @ K^T (wave w owns key strip w*128..+128), batched loads ----
    f32x4 accs[2][8];
#pragma unroll
    for (int i = 0; i < 2; i++)
#pragma unroll
        for (int j = 0; j < 8; j++) accs[i][j] = (f32x4){0.f, 0.f, 0.f, 0.f};
#pragma unroll
    for (int ks = 0; ks < 2; ks++) {
        const int kofs = ks * 64 + lg * 16;
        bf16x8 bk_[8];
#pragma unroll
        for (int jt = 0; jt < 8; jt++) {
            int key = w * 128 + jt * 16 + lq;
            bk_[jt] = *(const bf16x8*)(Kbase + (size_t)key * 4608 + kofs);
        }
#pragma unroll
        for (int jt = 0; jt < 8; jt++) {
            accs[0][jt] = __builtin_amdgcn_mfma_f32_16x16x32_bf16(afq[ks][0], bk_[jt], accs[0][jt], 0, 0, 0);
            accs[1][jt] = __builtin_amdgcn_mfma_f32_16x16x32_bf16(afq[ks][1], bk_[jt], accs[1][jt], 0, 0, 0);
        }
    }

    // ---- S epilogue: add rel score + mask ----
#pragma unroll
    for (int it = 0; it < 2; it++) {
#pragma unroll
        for (int r = 0; r < 4; r++) {
            int q = it * 16 + lg * 4 + r;
            int qg = qt * 32 + q;
            float mx = -INFINITY;
#pragma unroll
            for (int jt = 0; jt < 8; jt++) {
                int k = w * 128 + jt * 16 + lq;
                int jc = k - qg + 127;
                jc = jc < 0 ? 0 : (jc > 254 ? 254 : jc);
                float s = (accs[it][jt][r] + bfu2f(RqPrel[q * PR_LD + jc])) * COEF_ + maskb[k];
                accs[it][jt][r] = s;
                mx = fmaxf(mx, s);
            }
#pragma unroll
            for (int off = 1; off < 16; off <<= 1) mx = fmaxf(mx, __shfl_xor(mx, off, 64));
            if (lq == 0) mstat[q * 4 + w] = mx;
        }
    }
    __syncthreads();

    // ---- exp + row sums + write P ----
#pragma unroll
    for (int it = 0; it < 2; it++) {
#pragma unroll
        for (int r = 0; r < 4; r++) {
            int q = it * 16 + lg * 4 + r;
            float4 mv = *(const float4*)&mstat[q * 4];
            float gm = fmaxf(fmaxf(mv.x, mv.y), fmaxf(mv.z, mv.w));
            float ssum = 0.f;
#pragma unroll
            for (int jt = 0; jt < 8; jt++) {
                int k = w * 128 + jt * 16 + lq;
                float p = __expf(accs[it][jt][r] - gm);
                ssum += p;
                Ps[q * PS_LD + k] = f2bfu(p);
            }
#pragma unroll
            for (int off = 1; off < 16; off <<= 1) ssum += __shfl_xor(ssum, off, 64);
            if (lq == 0) sstat[q * 4 + w] = ssum;
        }
    }
    __syncthreads();

    // ---- prel construction + PV operand prefetch ----
    const __hip_bfloat16* vTb  = vT  + (((size_t)(b * NH_ + h) * 64) + w * 16 + lq) * 512 + lg * 8;
    const __hip_bfloat16* vrTb = vrT + ((size_t)(h * 64) + w * 16 + lq) * 256 + lg * 8;
    bf16x8 bvpre[8], vrpre[8];
#pragma unroll
    for (int ks = 0; ks < 8; ks++) {
        bvpre[ks] = *(const bf16x8*)(vTb + ks * 32);
        vrpre[ks] = *(const bf16x8*)(vrTb + ks * 32);
    }
    {
        int q = t >> 3, sub = t & 7;
        int qg = qt * 32 + q;
#pragma unroll
        for (int jj = 0; jj < 32; jj++) {
            int j = sub + 8 * jj;
            if (j == 0 || j == 254) continue;
            if (j == 255) { RqPrel[q * PR_LD + 255] = 0; continue; }
            int k = qg + j - 127;
            unsigned short val = ((unsigned)k < 512u) ? Ps[q * PS_LD + k] : (unsigned short)0;
            RqPrel[q * PR_LD + j] = val;
        }
    }
    {
        int task = t >> 2, ts = t & 3;
        int q = task >> 1, side = task & 1;
        int qg = qt * 32 + q;
        float sum = 0.f;
        if (side == 0) {
            int hi = qg - 127;
            for (int k = ts; k <= hi; k += 4) sum += bfu2f(Ps[q * PS_LD + k]);
        } else {
            for (int k = qg + 127 + ts; k < 512; k += 4) sum += bfu2f(Ps[q * PS_LD + k]);
        }
        sum += __shfl_xor(sum, 1, 64);
        sum += __shfl_xor(sum, 2, 64);
        if (ts == 0) RqPrel[q * PR_LD + (side == 0 ? 0 : 254)] = f2bfu(sum);
    }
    __syncthreads();

    // ---- PV phase: out strip d in [w*16, w*16+16) ----
    f32x4 accv[2];
    accv[0] = (f32x4){0.f, 0.f, 0.f, 0.f};
    accv[1] = (f32x4){0.f, 0.f, 0.f, 0.f};

#pragma unroll
    for (int ks = 0; ks < 8; ks++) {
        bf16x8 pa0 = *(const bf16x8*)((const char*)Ps + (size_t)lq * (PS_LD * 2) + ks * 64 + lg * 16);
        bf16x8 pa1 = *(const bf16x8*)((const char*)Ps + (size_t)(16 + lq) * (PS_LD * 2) + ks * 64 + lg * 16);
        accv[0] = __builtin_amdgcn_mfma_f32_16x16x32_bf16(pa0, bvpre[ks], accv[0], 0, 0, 0);
        accv[1] = __builtin_amdgcn_mfma_f32_16x16x32_bf16(pa1, bvpre[ks], accv[1], 0, 0, 0);
    }
#pragma unroll
    for (int ks = 8; ks < 16; ks++) {
        bf16x8 bv = *(const bf16x8*)(vTb + ks * 32);
        bf16x8 pa0 = *(const bf16x8*)((const char*)Ps + (size_t)lq * (PS_LD * 2) + ks * 64 + lg * 16);
        bf16x8 pa1 = *(const bf16x8*)((const char*)Ps + (size_t)(16 + lq) * (PS_LD * 2) + ks * 64 + lg * 16);
        accv[0] = __builtin_amdgcn_mfma_f32_16x16x32_bf16(pa0, bv, accv[0], 0, 0, 0);
        accv[1] = __builtin_amdgcn_mfma_f32_16x16x32_bf16(pa1, bv, accv[1], 0, 0, 0);
    }
#pragma unroll
    for (int ks = 0; ks < 8; ks++) {
        bf16x8 pa0 = *(const bf16x8*)((const char*)RqPrel + (size_t)lq * (PR_LD * 2) + ks * 64 + lg * 16);
        bf16x8 pa1 = *(const bf16x8*)((const char*)RqPrel + (size_t)(16 + lq) * (PR_LD * 2) + ks * 64 + lg * 16);
        accv[0] = __builtin_amdgcn_mfma_f32_16x16x32_bf16(pa0, vrpre[ks], accv[0], 0, 0, 0);
        accv[1] = __builtin_amdgcn_mfma_f32_16x16x32_bf16(pa1, vrpre[ks], accv[1], 0, 0, 0);
    }

#pragma unroll
    for (int it = 0; it < 2; it++) {
#pragma unroll
        for (int r = 0; r < 4; r++) {
            int q = it * 16 + lg * 4 + r;
            float4 sv = *(const float4*)&sstat[q * 4];
            float inv = 1.f / (sv.x + sv.y + sv.z + sv.w);
            ctxb[(size_t)(b * L_ + qt * 32 + q) * 768 + h * 64 + w * 16 + lq] =
                __float2bfloat16(accv[it][r] * inv);
        }
    }
}

// ---------------- host ----------------

extern "C" void kernel_launch(void* const* d_in, const int* in_sizes, int n_in,
                              void* d_out, int out_size, void* d_ws, size_t ws_size,
                              hipStream_t stream)
{
    const int*   tok    = (const int*)d_in[0];
    const int*   seg    = (const int*)d_in[1];
    const int*   maskp  = (const int*)d_in[2];
    const float* temb   = (const float*)d_in[3];
    const float* semb   = (const float*)d_in[4];
    const float* esc    = (const float*)d_in[5];
    const float* ebi    = (const float*)d_in[6];
    const float* Wq     = (const float*)d_in[7];
    const float* bq     = (const float*)d_in[8];
    const float* Wk     = (const float*)d_in[9];
    const float* bk     = (const float*)d_in[10];
    const float* Wv     = (const float*)d_in[11];
    const float* bv     = (const float*)d_in[12];
    const float* relpos = (const float*)d_in[13];
    const float* Wo     = (const float*)d_in[14];
    const float* bo     = (const float*)d_in[15];
    const float* ln1s   = (const float*)d_in[16];
    const float* ln1b   = (const float*)d_in[17];
    const float* W1     = (const float*)d_in[18];
    const float* b1     = (const float*)d_in[19];
    const float* W2     = (const float*)d_in[20];
    const float* b2     = (const float*)d_in[21];
    const float* ln2s   = (const float*)d_in[22];
    const float* ln2b   = (const float*)d_in[23];

    const size_t NX = (size_t)ROWS * H_;
    float* x       = (float*)d_ws;
    float* x2      = x + NX;
    float* y       = x2 + NX;
    float* qkvbias = y + NX;                                   // 2304 f32
    __hip_bfloat16* xb    = (__hip_bfloat16*)(qkvbias + 2304); // [MEXT][768] (rows 2048.. = rel emb)
    __hip_bfloat16* x2b   = xb    + (size_t)MEXT * H_;
    __hip_bfloat16* ctxb  = x2b   + NX;
    __hip_bfloat16* qkvb  = ctxb  + NX;                        // [MEXT][2304]
    __hip_bfloat16* vT    = qkvb  + (size_t)MEXT * 2304;       // 4*12*64*512
    __hip_bfloat16* vrT   = vT    + (size_t)B_ * NH_ * 64 * 512; // 12*64*256
    __hip_bfloat16* WtQ   = vrT   + (size_t)NH_ * 64 * 256;    // 2304*768
    __hip_bfloat16* WtO   = WtQ   + (size_t)2304 * H_;         // 768*768
    __hip_bfloat16* WtW1  = WtO   + (size_t)H_ * H_;           // 3072*768
    __hip_bfloat16* WtW2  = WtW1  + (size_t)M_ * H_;           // 768*3072
    __hip_bfloat16* h1b   = WtW2  + (size_t)H_ * M_;           // 2048*3072

    float* spill = (float*)qkvb;   // split-K partials alias qkvb/vT (dead after attn)

    dim3 blk(256);
    dim3 blk512(512);

    embed_ln_kernel<<<ROWS, blk, 0, stream>>>(tok, seg, temb, semb, esc, ebi, x, xb);

    for (int l = 0; l < NL_; l++) {
        const float* wq = Wq + (size_t)l * H_ * H_;
        const float* wk = Wk + (size_t)l * H_ * H_;
        const float* wv = Wv + (size_t)l * H_ * H_;
        const float* wo = Wo + (size_t)l * H_ * H_;
        const float* w1 = W1 + (size_t)l * H_ * M_;
        const float* w2 = W2 + (size_t)l * M_ * H_;

        pack_layer_kernel<<<dim3(96, 24, 7), blk, 0, stream>>>(
            wq, wk, wv, wo, w1, w2,
            bq + (size_t)l * H_, bk + (size_t)l * H_, bv + (size_t)l * H_,
            relpos + (size_t)l * NR_ * H_,
            WtQ, WtO, WtW1, WtW2, qkvbias, xb + (size_t)ROWS * H_);

        // merged QKV + rel projection: [MEXT][768] @ [2304][768]^T -> qkvb [MEXT][2304]
        gemm_bf16_kernel<<<dim3(36, 18), blk512, 0, stream>>>(xb, WtQ, qkvbias, nullptr, qkvb, nullptr, 0,
                                                              MEXT, 2304, H_, 0, H_);
        transpose_vvr_kernel<<<dim3(36, 12), blk, 0, stream>>>(qkvb, vT, vrT);

        attn_kernel<<<dim3(768), blk, 0, stream>>>(qkvb, vT, vrT, maskp, ctxb);

        // O projection: split-K x2 (768 -> 2x384); bias added in add_ln
        gemm_bf16_kernel<<<dim3(12, 16, 2), blk512, 0, stream>>>(ctxb, WtO, nullptr, y, nullptr, spill, NX,
                                                                 ROWS, H_, H_, 0, 384);
        add_ln_kernel<<<ROWS, blk, 0, stream>>>(x, y, spill, nullptr, bo + (size_t)l * H_,
                                                ln1s + (size_t)l * H_, ln1b + (size_t)l * H_, x2, x2b);

        // MLP
        gemm_bf16_kernel<<<dim3(48, 16), blk512, 0, stream>>>(x2b, WtW1, b1 + (size_t)l * M_, nullptr, h1b, nullptr, 0,
                                                              ROWS, M_, H_, 1, H_);
        gemm_bf16_kernel<<<dim3(12, 16, 3), blk512, 0, stream>>>(h1b, WtW2, nullptr, y, nullptr, spill, NX,
                                                                 ROWS, H_, M_, 0, 1024);

        float* outp = (l == NL_ - 1) ? (float*)d_out : x;
        __hip_bfloat16* outbp = (l == NL_ - 1) ? nullptr : xb;
        add_ln_kernel<<<ROWS, blk, 0, stream>>>(x2, y, spill, spill + NX, b2 + (size_t)l * H_,
                                                ln2s + (size_t)l * H_, ln2b + (size_t)l * H_, outp, outbp);
    }
}